// Round 1
// baseline (449.440 us; speedup 1.0000x reference)
//
#include <hip/hip_runtime.h>
#include <math.h>

#define CCH 256
#define NPOOL 7
#define NCLS 81
#define DCLS 80
#define NHEAD 512            /* padded head width: 81 logits + 324 reg + pad */
#define FLOG_MAX 4.1351666f  /* log(1000/16) */

typedef _Float16 half8 __attribute__((ext_vector_type(8)));
typedef _Float16 half4 __attribute__((ext_vector_type(4)));
typedef float floatx4 __attribute__((ext_vector_type(4)));

// ---------------------------------------------------------------------------
// zero a region (float4 stores)
// ---------------------------------------------------------------------------
__global__ void zero_k(float4* __restrict__ p, int count4)
{
    int i = blockIdx.x * blockDim.x + threadIdx.x;
    if (i < count4) p[i] = make_float4(0.f, 0.f, 0.f, 0.f);
}

// ---------------------------------------------------------------------------
// RoI-align box math (per-cell scalar part)
// ---------------------------------------------------------------------------
__device__ __forceinline__ void roi_setup(
    const float* __restrict__ prop, const int* __restrict__ imidx,
    const float* __restrict__ f0, const float* __restrict__ f1,
    const float* __restrict__ f2, const float* __restrict__ f3,
    int h0, int h1, int h2, int h3, int b,
    const float*& base, int& W, size_t& o00, size_t& o01, size_t& o10, size_t& o11,
    float& w00, float& w01, float& w10, float& w11)
{
    int roi = b / 49, p = b % 49;
    int py = p / 7, px = p % 7;

    const float* pr = prop + (size_t)roi * 4;
    float x1 = pr[0], y1 = pr[1], x2 = pr[2], y2 = pr[3];
    float pw = x2 - x1, ph = y2 - y1;

    float lv = floorf(4.0f + log2f(sqrtf(pw * ph) / 224.0f + 1e-6f));
    lv = fminf(fmaxf(lv, 2.0f), 5.0f);
    int lvl = (int)lv - 2;

    const float* fm; int H; float s;
    if (lvl == 0)      { fm = f0; H = h0; s = 0.25f;    }
    else if (lvl == 1) { fm = f1; H = h1; s = 0.125f;   }
    else if (lvl == 2) { fm = f2; H = h2; s = 0.0625f;  }
    else               { fm = f3; H = h3; s = 0.03125f; }
    W = H;

    float xs1 = x1 * s, ys1 = y1 * s, xs2 = x2 * s, ys2 = y2 * s;
    float gx = (px + 0.5f) / 7.0f, gy = (py + 0.5f) / 7.0f;
    float xx = xs1 + gx * (xs2 - xs1) - 0.5f;
    float yy = ys1 + gy * (ys2 - ys1) - 0.5f;
    float x0f = floorf(xx), y0f = floorf(yy);
    float wx = xx - x0f, wy = yy - y0f;
    int x0i = min(max((int)x0f, 0), W - 1);
    int x1i = min(max((int)x0f + 1, 0), W - 1);
    int y0i = min(max((int)y0f, 0), H - 1);
    int y1i = min(max((int)y0f + 1, 0), H - 1);

    int ii = imidx[roi];
    base = fm + (size_t)ii * H * W * CCH;
    o00 = ((size_t)y0i * W + x0i) * CCH;
    o01 = ((size_t)y0i * W + x1i) * CCH;
    o10 = ((size_t)y1i * W + x0i) * CCH;
    o11 = ((size_t)y1i * W + x1i) * CCH;
    w00 = (1.0f - wx) * (1.0f - wy);
    w01 = wx * (1.0f - wy);
    w10 = (1.0f - wx) * wy;
    w11 = wx * wy;
}

// fp32 fallback variant: grid R*49 x 256 threads
__global__ void roi_align_k(const float* __restrict__ prop,
                            const int* __restrict__ imidx,
                            const float* __restrict__ f0,
                            const float* __restrict__ f1,
                            const float* __restrict__ f2,
                            const float* __restrict__ f3,
                            int h0, int h1, int h2, int h3,
                            float* __restrict__ pooled)
{
    int b = blockIdx.x, c = threadIdx.x;
    const float* base; int W; size_t o00, o01, o10, o11;
    float w00, w01, w10, w11;
    roi_setup(prop, imidx, f0, f1, f2, f3, h0, h1, h2, h3, b,
              base, W, o00, o01, o10, o11, w00, w01, w10, w11);
    float v = base[o00 + c] * w00 + base[o01 + c] * w01
            + base[o10 + c] * w10 + base[o11 + c] * w11;
    pooled[(size_t)b * CCH + c] = v;
}

// f16 hi/lo split: grid R*49/4 blocks x 256 threads; wave w -> cell 4b+w
__global__ __launch_bounds__(256) void roi_align_f16v4_k(
    const float* __restrict__ prop, const int* __restrict__ imidx,
    const float* __restrict__ f0, const float* __restrict__ f1,
    const float* __restrict__ f2, const float* __restrict__ f3,
    int h0, int h1, int h2, int h3,
    _Float16* __restrict__ poolH, _Float16* __restrict__ poolL)
{
    int b = blockIdx.x * 4 + (threadIdx.x >> 6);
    int lane = threadIdx.x & 63;
    const float* base; int W; size_t o00, o01, o10, o11;
    float w00, w01, w10, w11;
    roi_setup(prop, imidx, f0, f1, f2, f3, h0, h1, h2, h3, b,
              base, W, o00, o01, o10, o11, w00, w01, w10, w11);

    int c4 = lane * 4;
    float4 v00 = *(const float4*)(base + o00 + c4);
    float4 v01 = *(const float4*)(base + o01 + c4);
    float4 v10 = *(const float4*)(base + o10 + c4);
    float4 v11 = *(const float4*)(base + o11 + c4);
    const float* p00 = (const float*)&v00;
    const float* p01 = (const float*)&v01;
    const float* p10 = (const float*)&v10;
    const float* p11 = (const float*)&v11;

    half4 h, l;
#pragma unroll
    for (int e = 0; e < 4; ++e) {
        float v = p00[e] * w00 + p01[e] * w01 + p10[e] * w10 + p11[e] * w11;
        _Float16 hh = (_Float16)v;
        h[e] = hh;
        l[e] = (_Float16)(v - (float)hh);
    }
    size_t idx = (size_t)b * CCH + c4;
    *(half4*)(poolH + idx) = h;
    *(half4*)(poolL + idx) = l;
}

// ---------------------------------------------------------------------------
// Transpose-convert: W [K][N] fp32 -> WtH/WtL [N][K] f16 hi/lo.
// ---------------------------------------------------------------------------
__global__ __launch_bounds__(256) void convert_w_t_k(const float* __restrict__ W,
                                                     _Float16* __restrict__ WtH,
                                                     _Float16* __restrict__ WtL,
                                                     int K, int N)
{
    __shared__ float sh[64][65];
    int k0 = blockIdx.x * 64, n0 = blockIdx.y * 64;
    int t = threadIdx.x;
#pragma unroll
    for (int p = 0; p < 4; ++p) {
        int idx = p * 256 + t;
        int kr = idx >> 4, nc = (idx & 15) * 4;
        float4 v = *(const float4*)(W + (size_t)(k0 + kr) * N + n0 + nc);
        sh[kr][nc + 0] = v.x; sh[kr][nc + 1] = v.y;
        sh[kr][nc + 2] = v.z; sh[kr][nc + 3] = v.w;
    }
    __syncthreads();
#pragma unroll
    for (int p = 0; p < 4; ++p) {
        int idx = p * 256 + t;
        int nr = idx >> 4, kc = (idx & 15) * 4;
        half4 h, l;
#pragma unroll
        for (int i = 0; i < 4; ++i) {
            float v = sh[kc + i][nr];
            _Float16 hh = (_Float16)v;
            h[i] = hh;
            l[i] = (_Float16)(v - (float)hh);
        }
        *(half4*)(WtH + (size_t)(n0 + nr) * K + k0 + kc) = h;
        *(half4*)(WtL + (size_t)(n0 + nr) * K + k0 + kc) = l;
    }
}

// Guarded variant for N not multiple of 64; writes rows rowofs+n with stride Kt.
__global__ __launch_bounds__(256) void convert_w_t_guard_k(const float* __restrict__ W,
                                                           _Float16* __restrict__ WtH,
                                                           _Float16* __restrict__ WtL,
                                                           int K, int N, int Kt, int rowofs)
{
    __shared__ float sh[64][65];
    int k0 = blockIdx.x * 64, n0 = blockIdx.y * 64;
    int t = threadIdx.x;
#pragma unroll
    for (int p = 0; p < 4; ++p) {
        int idx = p * 256 + t;
        int kr = idx >> 4, nc = (idx & 15) * 4;
#pragma unroll
        for (int e = 0; e < 4; ++e) {
            int nn = n0 + nc + e;
            sh[kr][nc + e] = (nn < N) ? W[(size_t)(k0 + kr) * N + nn] : 0.0f;
        }
    }
    __syncthreads();
#pragma unroll
    for (int p = 0; p < 4; ++p) {
        int idx = p * 256 + t;
        int nr = idx >> 4, kc = (idx & 15) * 4;
        if (n0 + nr < N) {
            half4 h, l;
#pragma unroll
            for (int i = 0; i < 4; ++i) {
                float v = sh[kc + i][nr];
                _Float16 hh = (_Float16)v;
                h[i] = hh;
                l[i] = (_Float16)(v - (float)hh);
            }
            *(half4*)(WtH + (size_t)(rowofs + n0 + nr) * Kt + k0 + kc) = h;
            *(half4*)(WtL + (size_t)(rowofs + n0 + nr) * Kt + k0 + kc) = l;
        }
    }
}

// ---------------------------------------------------------------------------
// act-split: out = relu(acc + bias) -> f16 hi/lo. 4 elems/thread.
// ---------------------------------------------------------------------------
__global__ void act_split_k(const float* __restrict__ acc,
                            const float* __restrict__ bias,
                            _Float16* __restrict__ outH,
                            _Float16* __restrict__ outL,
                            int total, int CL)
{
    int i = (blockIdx.x * blockDim.x + threadIdx.x) * 4;
    if (i >= total) return;
    int b = i % CL;
    float4 v = *(const float4*)(acc + i);
    float4 bb = *(const float4*)(bias + b);
    const float* pv = (const float*)&v;
    const float* pb = (const float*)&bb;
    half4 h, l;
#pragma unroll
    for (int e = 0; e < 4; ++e) {
        float f = fmaxf(pv[e] + pb[e], 0.0f);
        _Float16 hh = (_Float16)f;
        h[e] = hh;
        l[e] = (_Float16)(f - (float)hh);
    }
    *(half4*)(outH + i) = h;
    *(half4*)(outL + i) = l;
}

// ---------------------------------------------------------------------------
// global->LDS DMA, width 16 (wave-uniform LDS base + lane*16)
// ---------------------------------------------------------------------------
__device__ __forceinline__ void dma16(const _Float16* g, _Float16* l)
{
    __builtin_amdgcn_global_load_lds(
        (const __attribute__((address_space(1))) unsigned int*)g,
        (__attribute__((address_space(3))) unsigned int*)l, 16, 0, 0);
}

#define LDKE 32   /* halves per LDS row (64 B), unpadded for DMA */

// ---------------------------------------------------------------------------
// Split-f16 MFMA GEMM, 256x256 tile, 4-phase raw-barrier pipeline:
//   Cacc[M,N] += (Ah+Al)[M][K] @ (Bh+Bl)^T,  Bt given as [N][K].
// 512 thr = 8 waves (2Mx4N), wave tile 128x64 (acc[8][4] f32x4 = 128 VGPR).
// BK=32; LDS = 2 buf x 4 arrays x 256x32 halves = 128 KiB (1 block/CU).
// Per K-tile: 4 phases x {ds_read subtile ; stage next-tile dma ; s_barrier ;
// lgkmcnt(0) ; setprio(1) ; 24 MFMA ; setprio(0) ; s_barrier}.
// Staging for tile t+1 is issued in phases 0-1 of tile t (8 dma16/thread);
// drained with a single vmcnt(0) at the END of phase 3 (aged >= 2 phases),
// never a per-phase __syncthreads drain.  B-fragments are read once per
// K-tile (phase 0) and reused in all 4 phases -> 96 MFMA / 24 ds_read_b128.
// fp32 atomicAdd epilogue.  Requires M%256==0, N%256==0, Kc%32==0.
// ---------------------------------------------------------------------------
__global__ __launch_bounds__(512, 2) void gemm_mfma_split256_k(
    const _Float16* __restrict__ Ah, const _Float16* __restrict__ Al,
    const _Float16* __restrict__ Bh, const _Float16* __restrict__ Bl,
    float* __restrict__ Cacc, int M, int N, int K, int Kc, int SP)
{
    // [buf][arr: Ah,Al,Bh,Bl][256 rows x 32 halves]
    __shared__ _Float16 lds[2][4][256 * LDKE];

    int bid = blockIdx.x;
    int MT = M >> 8, NT = N >> 8;
    int tiles = MT * NT;
    int z = bid / tiles;              // K-slice (slow -> tile-sharing bids adjacent)
    int q = bid - z * tiles;
    int nn = q % NT, mm = q / NT;
    int m0 = mm << 8, n0 = nn << 8;
    int kb = z * Kc;                  // half offset into K
    int nt = Kc >> 5;                 // K-tiles of 32

    int t = threadIdx.x;
    int lane = t & 63, w = t >> 6;
    int wr = w >> 2, wc = w & 3;      // 2x4 wave grid over 256x256
    int fr = lane & 15;
    int fk = (lane >> 4) * 8;

    // staging map: round r in {0,1}: row = r*128 + (t>>2), chunk = (t&3)*8 halves
    int srow = t >> 2;
    int sch = (t & 3) * 8;
    const _Float16* gAh0 = Ah + (size_t)(m0 + srow) * K + sch;
    const _Float16* gAl0 = Al + (size_t)(m0 + srow) * K + sch;
    const _Float16* gBh0 = Bh + (size_t)(n0 + srow) * K + sch;
    const _Float16* gBl0 = Bl + (size_t)(n0 + srow) * K + sch;
    size_t rskip = (size_t)128 * K;
    int d0 = t * 8;                   // LDS half offset, round 0 (16 B/lane linear)
    int d1 = 4096 + t * 8;            // round 1

    floatx4 acc[8][4] = {};

#define STAGE_A(b, kh) do { \
    dma16(gAh0 + (kh), &lds[b][0][d0]); \
    dma16(gAh0 + rskip + (kh), &lds[b][0][d1]); \
    dma16(gAl0 + (kh), &lds[b][1][d0]); \
    dma16(gAl0 + rskip + (kh), &lds[b][1][d1]); } while (0)
#define STAGE_B(b, kh) do { \
    dma16(gBh0 + (kh), &lds[b][2][d0]); \
    dma16(gBh0 + rskip + (kh), &lds[b][2][d1]); \
    dma16(gBl0 + (kh), &lds[b][3][d0]); \
    dma16(gBl0 + rskip + (kh), &lds[b][3][d1]); } while (0)

    // prologue: stage tile 0 into buf 0, full drain once
    STAGE_A(0, kb);
    STAGE_B(0, kb);
    asm volatile("s_waitcnt vmcnt(0)" ::: "memory");
    __builtin_amdgcn_s_barrier();

    int abase = wr * 128 + fr;        // + i*16
    int bbase = wc * 64 + fr;         // + j*16

#pragma unroll 1
    for (int tt = 0; tt < nt; ++tt) {
        int c = tt & 1, nb = c ^ 1;
        bool hasnext = (tt + 1) < nt;
        int kh = kb + (tt + 1) * 32;

        const _Float16* sAh = lds[c][0];
        const _Float16* sAl = lds[c][1];
        const _Float16* sBh = lds[c][2];
        const _Float16* sBl = lds[c][3];

        half8 bhf[4], blf[4];
        half8 a0h, a0l, a1h, a1l;

        // ------------- phase 0: B frags + A rowtiles 0,1; stage A(next) ----
#pragma unroll
        for (int j = 0; j < 4; ++j) {
            int bo = (bbase + j * 16) * LDKE + fk;
            bhf[j] = *(const half8*)&sBh[bo];
            blf[j] = *(const half8*)&sBl[bo];
        }
        {
            int a0 = (abase + 0 * 16) * LDKE + fk;
            int a1 = (abase + 1 * 16) * LDKE + fk;
            a0h = *(const half8*)&sAh[a0]; a0l = *(const half8*)&sAl[a0];
            a1h = *(const half8*)&sAh[a1]; a1l = *(const half8*)&sAl[a1];
        }
        if (hasnext) STAGE_A(nb, kh);
        __builtin_amdgcn_s_barrier();
        asm volatile("s_waitcnt lgkmcnt(0)" ::: "memory");
        __builtin_amdgcn_sched_barrier(0);
        __builtin_amdgcn_s_setprio(1);
#pragma unroll
        for (int j = 0; j < 4; ++j) {
            acc[0][j] = __builtin_amdgcn_mfma_f32_16x16x32_f16(a0h, bhf[j], acc[0][j], 0, 0, 0);
            acc[0][j] = __builtin_amdgcn_mfma_f32_16x16x32_f16(a0h, blf[j], acc[0][j], 0, 0, 0);
            acc[0][j] = __builtin_amdgcn_mfma_f32_16x16x32_f16(a0l, bhf[j], acc[0][j], 0, 0, 0);
            acc[1][j] = __builtin_amdgcn_mfma_f32_16x16x32_f16(a1h, bhf[j], acc[1][j], 0, 0, 0);
            acc[1][j] = __builtin_amdgcn_mfma_f32_16x16x32_f16(a1h, blf[j], acc[1][j], 0, 0, 0);
            acc[1][j] = __builtin_amdgcn_mfma_f32_16x16x32_f16(a1l, bhf[j], acc[1][j], 0, 0, 0);
        }
        __builtin_amdgcn_s_setprio(0);
        __builtin_amdgcn_s_barrier();

        // ------------- phase 1: A rowtiles 2,3; stage B(next) --------------
        {
            int a0 = (abase + 2 * 16) * LDKE + fk;
            int a1 = (abase + 3 * 16) * LDKE + fk;
            a0h = *(const half8*)&sAh[a0]; a0l = *(const half8*)&sAl[a0];
            a1h = *(const half8*)&sAh[a1]; a1l = *(const half8*)&sAl[a1];
        }
        if (hasnext) STAGE_B(nb, kh);
        __builtin_amdgcn_s_barrier();
        asm volatile("s_waitcnt lgkmcnt(0)" ::: "memory");
        __builtin_amdgcn_sched_barrier(0);
        __builtin_amdgcn_s_setprio(1);
#pragma unroll
        for (int j = 0; j < 4; ++j) {
            acc[2][j] = __builtin_amdgcn_mfma_f32_16x16x32_f16(a0h, bhf[j], acc[2][j], 0, 0, 0);
            acc[2][j] = __builtin_amdgcn_mfma_f32_16x16x32_f16(a0h, blf[j], acc[2][j], 0, 0, 0);
            acc[2][j] = __builtin_amdgcn_mfma_f32_16x16x32_f16(a0l, bhf[j], acc[2][j], 0, 0, 0);
            acc[3][j] = __builtin_amdgcn_mfma_f32_16x16x32_f16(a1h, bhf[j], acc[3][j], 0, 0, 0);
            acc[3][j] = __builtin_amdgcn_mfma_f32_16x16x32_f16(a1h, blf[j], acc[3][j], 0, 0, 0);
            acc[3][j] = __builtin_amdgcn_mfma_f32_16x16x32_f16(a1l, bhf[j], acc[3][j], 0, 0, 0);
        }
        __builtin_amdgcn_s_setprio(0);
        __builtin_amdgcn_s_barrier();

        // ------------- phase 2: A rowtiles 4,5 -----------------------------
        {
            int a0 = (abase + 4 * 16) * LDKE + fk;
            int a1 = (abase + 5 * 16) * LDKE + fk;
            a0h = *(const half8*)&sAh[a0]; a0l = *(const half8*)&sAl[a0];
            a1h = *(const half8*)&sAh[a1]; a1l = *(const half8*)&sAl[a1];
        }
        __builtin_amdgcn_s_barrier();
        asm volatile("s_waitcnt lgkmcnt(0)" ::: "memory");
        __builtin_amdgcn_sched_barrier(0);
        __builtin_amdgcn_s_setprio(1);
#pragma unroll
        for (int j = 0; j < 4; ++j) {
            acc[4][j] = __builtin_amdgcn_mfma_f32_16x16x32_f16(a0h, bhf[j], acc[4][j], 0, 0, 0);
            acc[4][j] = __builtin_amdgcn_mfma_f32_16x16x32_f16(a0h, blf[j], acc[4][j], 0, 0, 0);
            acc[4][j] = __builtin_amdgcn_mfma_f32_16x16x32_f16(a0l, bhf[j], acc[4][j], 0, 0, 0);
            acc[5][j] = __builtin_amdgcn_mfma_f32_16x16x32_f16(a1h, bhf[j], acc[5][j], 0, 0, 0);
            acc[5][j] = __builtin_amdgcn_mfma_f32_16x16x32_f16(a1h, blf[j], acc[5][j], 0, 0, 0);
            acc[5][j] = __builtin_amdgcn_mfma_f32_16x16x32_f16(a1l, bhf[j], acc[5][j], 0, 0, 0);
        }
        __builtin_amdgcn_s_setprio(0);
        __builtin_amdgcn_s_barrier();

        // ------------- phase 3: A rowtiles 6,7; vmcnt drain at end ---------
        {
            int a0 = (abase + 6 * 16) * LDKE + fk;
            int a1 = (abase + 7 * 16) * LDKE + fk;
            a0h = *(const half8*)&sAh[a0]; a0l = *(const half8*)&sAl[a0];
            a1h = *(const half8*)&sAh[a1]; a1l = *(const half8*)&sAl[a1];
        }
        __builtin_amdgcn_s_barrier();
        asm volatile("s_waitcnt lgkmcnt(0)" ::: "memory");
        __builtin_amdgcn_sched_barrier(0);
        __builtin_amdgcn_s_setprio(1);
#pragma unroll
        for (int j = 0; j < 4; ++j) {
            acc[6][j] = __builtin_amdgcn_mfma_f32_16x16x32_f16(a0h, bhf[j], acc[6][j], 0, 0, 0);
            acc[6][j] = __builtin_amdgcn_mfma_f32_16x16x32_f16(a0h, blf[j], acc[6][j], 0, 0, 0);
            acc[6][j] = __builtin_amdgcn_mfma_f32_16x16x32_f16(a0l, bhf[j], acc[6][j], 0, 0, 0);
            acc[7][j] = __builtin_amdgcn_mfma_f32_16x16x32_f16(a1h, bhf[j], acc[7][j], 0, 0, 0);
            acc[7][j] = __builtin_amdgcn_mfma_f32_16x16x32_f16(a1h, blf[j], acc[7][j], 0, 0, 0);
            acc[7][j] = __builtin_amdgcn_mfma_f32_16x16x32_f16(a1l, bhf[j], acc[7][j], 0, 0, 0);
        }
        __builtin_amdgcn_s_setprio(0);
        // next tile's 8 dma (issued phases 0-1) must be resident before any
        // wave reads buf nb: drain, then phase-lock.
        asm volatile("s_waitcnt vmcnt(0)" ::: "memory");
        __builtin_amdgcn_s_barrier();
    }
#undef STAGE_A
#undef STAGE_B

    // epilogue: C/D layout col=lane&15, row=(lane>>4)*4+reg
    int rbase = (lane >> 4) * 4;
#pragma unroll
    for (int i = 0; i < 8; ++i)
#pragma unroll
        for (int j = 0; j < 4; ++j) {
            int col = n0 + wc * 64 + j * 16 + fr;
#pragma unroll
            for (int r = 0; r < 4; ++r) {
                int row = m0 + wr * 128 + i * 16 + rbase + r;
                atomicAdd(&Cacc[(size_t)row * N + col], acc[i][j][r]);
            }
        }
}

// ---------------------------------------------------------------------------
// Non-split fused MFMA GEMM, 64x64 tile, full-K accumulation in registers:
//   C = (Ah+Al) @ (Bh+Bl)^T   (3 products)
// mode 0: Cout[row*N+col] = C (raw fp32)
// mode 1: relu(C + bias[col]) -> outH/outL f16 hi/lo
// 256 thr (2x2 waves of 32x32 = 2x2 of 16x16x32). DMA staging (16 KB LDS).
// Requires M%64==0, N%64==0, K%32==0.
// ---------------------------------------------------------------------------
__global__ __launch_bounds__(256) void gemm_mfma_fused64_k(
    const _Float16* __restrict__ Ah, const _Float16* __restrict__ Al,
    const _Float16* __restrict__ Bh, const _Float16* __restrict__ Bl,
    const float* __restrict__ bias,
    float* __restrict__ Cout,
    _Float16* __restrict__ outH, _Float16* __restrict__ outL,
    int M, int N, int K, int mode)
{
    __shared__ _Float16 sAh[64 * LDKE], sAl[64 * LDKE];
    __shared__ _Float16 sBh[64 * LDKE], sBl[64 * LDKE];

    int m0 = blockIdx.y * 64, n0 = blockIdx.x * 64;
    int t = threadIdx.x;
    int lane = t & 63, w = t >> 6;
    int wr = w >> 1, wc = w & 1;          // 2x2 wave grid over 64x64
    int fr = lane & 15;
    int fk = (lane >> 4) * 8;

    // DMA: wave w stages rows [w*16, w*16+16) of all four arrays
    int drow = w * 16 + (lane >> 2);
    int dkq = (lane & 3) * 8;
    const _Float16* gAh = Ah + (size_t)(m0 + drow) * K + dkq;
    const _Float16* gAl = Al + (size_t)(m0 + drow) * K + dkq;
    const _Float16* gBh = Bh + (size_t)(n0 + drow) * K + dkq;
    const _Float16* gBl = Bl + (size_t)(n0 + drow) * K + dkq;
    _Float16* lAh = &sAh[w * 512];
    _Float16* lAl = &sAl[w * 512];
    _Float16* lBh = &sBh[w * 512];
    _Float16* lBl = &sBl[w * 512];

    floatx4 acc[2][2] = {};

    for (int k0 = 0; k0 < K; k0 += 32) {
        dma16(gAh + k0, lAh);
        dma16(gAl + k0, lAl);
        dma16(gBh + k0, lBh);
        dma16(gBl + k0, lBl);
        __syncthreads();

        half8 ah[2], av[2], bh[2], bv[2];
#pragma unroll
        for (int i = 0; i < 2; ++i) {
            int ar = wr * 32 + i * 16 + fr;
            ah[i] = *(const half8*)&sAh[ar * LDKE + fk];
            av[i] = *(const half8*)&sAl[ar * LDKE + fk];
            int bc = wc * 32 + i * 16 + fr;
            bh[i] = *(const half8*)&sBh[bc * LDKE + fk];
            bv[i] = *(const half8*)&sBl[bc * LDKE + fk];
        }
#pragma unroll
        for (int i = 0; i < 2; ++i)
#pragma unroll
            for (int j = 0; j < 2; ++j) {
                acc[i][j] = __builtin_amdgcn_mfma_f32_16x16x32_f16(ah[i], bh[j], acc[i][j], 0, 0, 0);
                acc[i][j] = __builtin_amdgcn_mfma_f32_16x16x32_f16(ah[i], bv[j], acc[i][j], 0, 0, 0);
                acc[i][j] = __builtin_amdgcn_mfma_f32_16x16x32_f16(av[i], bh[j], acc[i][j], 0, 0, 0);
            }
        __syncthreads();
    }

    int rbase = (lane >> 4) * 4;
#pragma unroll
    for (int i = 0; i < 2; ++i)
#pragma unroll
        for (int j = 0; j < 2; ++j) {
            int col = n0 + wc * 32 + j * 16 + fr;
#pragma unroll
            for (int r = 0; r < 4; ++r) {
                int row = m0 + wr * 32 + i * 16 + rbase + r;
                float v = acc[i][j][r];
                if (mode == 0) {
                    Cout[(size_t)row * N + col] = v;
                } else {
                    float f = fmaxf(v + bias[col], 0.0f);
                    _Float16 hh = (_Float16)f;
                    outH[(size_t)row * N + col] = hh;
                    outL[(size_t)row * N + col] = (_Float16)(f - (float)hh);
                }
            }
        }
}

// ---------------------------------------------------------------------------
// fp32 split-K GEMM (fallback path only)
// ---------------------------------------------------------------------------
__global__ __launch_bounds__(256) void gemm_splitk_k(const float* __restrict__ A,
                                                     const float* __restrict__ B,
                                                     const float* __restrict__ abias,
                                                     float* __restrict__ Cacc,
                                                     int M, int N, int K, int Kc)
{
    __shared__ float Ast[16][68];
    __shared__ float Bs[16][68];

    int m0 = blockIdx.y * 64, n0 = blockIdx.x * 64;
    int kb = blockIdx.z * Kc;
    int ke = min(K, kb + Kc);
    int tid = threadIdx.x;
    int tx = tid & 15, ty = tid >> 4;
    int arow = tid >> 2, akq = (tid & 3) << 2;
    int bcol = tid & 63, bk = tid >> 6;

    const float* Arow = A + (size_t)(m0 + arow) * K;
    bool nfull = (n0 + 64 <= N);

    float acc[4][4] = {};

    for (int k0 = kb; k0 < ke; k0 += 16) {
        float4 av = *(const float4*)(Arow + k0 + akq);
        if (abias) {
            av.x = fmaxf(av.x + abias[k0 + akq + 0], 0.0f);
            av.y = fmaxf(av.y + abias[k0 + akq + 1], 0.0f);
            av.z = fmaxf(av.z + abias[k0 + akq + 2], 0.0f);
            av.w = fmaxf(av.w + abias[k0 + akq + 3], 0.0f);
        }
        float bv[4];
        if (nfull) {
#pragma unroll
            for (int e = 0; e < 4; ++e)
                bv[e] = B[(size_t)(k0 + bk * 4 + e) * N + n0 + bcol];
        } else {
            bool ok = (n0 + bcol) < N;
#pragma unroll
            for (int e = 0; e < 4; ++e)
                bv[e] = ok ? B[(size_t)(k0 + bk * 4 + e) * N + n0 + bcol] : 0.0f;
        }
        __syncthreads();
        Ast[akq + 0][arow] = av.x;
        Ast[akq + 1][arow] = av.y;
        Ast[akq + 2][arow] = av.z;
        Ast[akq + 3][arow] = av.w;
#pragma unroll
        for (int e = 0; e < 4; ++e) Bs[bk * 4 + e][bcol] = bv[e];
        __syncthreads();

#pragma unroll
        for (int kk = 0; kk < 16; ++kk) {
            float4 af = *(const float4*)&Ast[kk][ty * 4];
            float4 bf = *(const float4*)&Bs[kk][tx * 4];
            float a_[4] = {af.x, af.y, af.z, af.w};
            float b_[4] = {bf.x, bf.y, bf.z, bf.w};
#pragma unroll
            for (int i = 0; i < 4; ++i)
#pragma unroll
                for (int j = 0; j < 4; ++j)
                    acc[i][j] = fmaf(a_[i], b_[j], acc[i][j]);
        }
    }

#pragma unroll
    for (int i = 0; i < 4; ++i) {
        int row = m0 + ty * 4 + i;
#pragma unroll
        for (int j = 0; j < 4; ++j) {
            int col = n0 + tx * 4 + j;
            if (col < N) atomicAdd(&Cacc[(size_t)row * N + col], acc[i][j]);
        }
    }
}

// ---------------------------------------------------------------------------
// softmax over (logits + bc), classes 1..80. grid = R, block = 64.
// ---------------------------------------------------------------------------
__global__ void softmax_k(const float* __restrict__ logits, int ldl,
                          const float* __restrict__ bc,
                          float* __restrict__ scr)
{
    int r = blockIdx.x;
    int t = threadIdx.x;
    const float* row = logits + (size_t)r * ldl;

    float v0 = row[t] + bc[t];
    float v1 = (t + 64 < NCLS) ? (row[t + 64] + bc[t + 64]) : -INFINITY;
    float m = fmaxf(v0, v1);
#pragma unroll
    for (int o = 32; o > 0; o >>= 1) m = fmaxf(m, __shfl_down(m, o));
    m = __shfl(m, 0);

    float e0 = expf(v0 - m);
    float e1 = (t + 64 < NCLS) ? expf(v1 - m) : 0.0f;
    float sum = e0 + e1;
#pragma unroll
    for (int o = 32; o > 0; o >>= 1) sum += __shfl_down(sum, o);
    sum = __shfl(sum, 0);
    float inv = 1.0f / sum;

    if (t >= 1)        scr[(size_t)r * DCLS + (t - 1)]  = e0 * inv;
    if (t + 64 < NCLS) scr[(size_t)r * DCLS + (t + 63)] = e1 * inv;
}

// ---------------------------------------------------------------------------
// per-image NMS with fused box decode. grid = n, block = 1024.
// Argmax per pick: per-thread strided scan -> 64-lane shuffle reduce ->
// 16 wave leaders in LDS -> wave-0 shuffle reduce. 3 syncthreads/iteration
// (was ~13 with the LDS tree).
// ---------------------------------------------------------------------------
#define NMS_T 1024
__global__ __launch_bounds__(NMS_T) void nms_k(
    const float* __restrict__ scr,
    const float* __restrict__ prop,
    const int* __restrict__ imidx,
    const float* __restrict__ head, int ldh, int regofs,
    const float* __restrict__ br,
    const float* __restrict__ imsz,
    const float* __restrict__ score_thr_p,
    const float* __restrict__ min_size_p,
    const float* __restrict__ iou_thr_p,
    int* __restrict__ cidx,
    float* __restrict__ cscore,
    float* __restrict__ cbo,
    float* __restrict__ cbox,
    float* __restrict__ carea,
    float* __restrict__ out,
    int M, int n, int imtop)
{
    int img = blockIdx.x;
    int t = threadIdx.x;
    const int T = NMS_T;
    const int NW = NMS_T / 64;
    int lane = t & 63, wid = t >> 6;

    __shared__ int cnt;
    __shared__ float wbs[NW];
    __shared__ int wbg[NW];
    __shared__ int wbl[NW];
    __shared__ float fS;
    __shared__ float wb0, wb1, wb2, wb3, wa;

    if (t == 0) cnt = 0;
    __syncthreads();

    float score_thr = score_thr_p[0];
    float min_size  = min_size_p[0];
    float iou_thr   = iou_thr_p[0];
    float immax = imsz[0];
    for (int q = 1; q < 2 * n; ++q) immax = fmaxf(immax, imsz[q]);

    int base = img * M;
    for (int j = t; j < M; j += T) {
        int r = j / DCLS;
        if (imidx[r] != img) continue;
        float s = scr[j];
        if (s <= score_thr) continue;

        int cls = j - r * DCLS + 1;
        const float* pr = prop + (size_t)r * 4;
        float pw = pr[2] - pr[0], ph = pr[3] - pr[1];
        float cx = (pr[0] + pr[2]) * 0.5f, cy = (pr[1] + pr[3]) * 0.5f;
        const float* rg_ = head + (size_t)r * ldh + regofs + cls * 4;
        const float* bb = br + cls * 4;
        float dx = (rg_[0] + bb[0]) * 0.1f;
        float dy = (rg_[1] + bb[1]) * 0.1f;
        float dw = fminf((rg_[2] + bb[2]) * 0.2f, FLOG_MAX);
        float dh = fminf((rg_[3] + bb[3]) * 0.2f, FLOG_MAX);
        float ncx = dx * pw + cx;
        float ncy = dy * ph + cy;
        float nw = expf(dw) * pw;
        float nh = expf(dh) * ph;
        float hbound = imsz[img * 2 + 0];
        float wbound = imsz[img * 2 + 1];
        float bx1 = fminf(fmaxf(ncx - nw * 0.5f, 0.0f), wbound);
        float bx2 = fminf(fmaxf(ncx + nw * 0.5f, 0.0f), wbound);
        float by1 = fminf(fmaxf(ncy - nh * 0.5f, 0.0f), hbound);
        float by2 = fminf(fmaxf(ncy + nh * 0.5f, 0.0f), hbound);
        if (bx2 - bx1 < min_size || by2 - by1 < min_size) continue;

        float off = (float)cls * (immax + 2.0f);
        int p = atomicAdd(&cnt, 1);
        cidx[base + p] = j;
        cscore[base + p] = s;
        cbox[(size_t)(base + p) * 4 + 0] = bx1;
        cbox[(size_t)(base + p) * 4 + 1] = by1;
        cbox[(size_t)(base + p) * 4 + 2] = bx2;
        cbox[(size_t)(base + p) * 4 + 3] = by2;
        cbo[(size_t)(base + p) * 4 + 0] = bx1 + off;
        cbo[(size_t)(base + p) * 4 + 1] = by1 + off;
        cbo[(size_t)(base + p) * 4 + 2] = bx2 + off;
        cbo[(size_t)(base + p) * 4 + 3] = by2 + off;
        carea[base + p] = (bx2 - bx1) * (by2 - by1);
    }
    __syncthreads();
    int K = cnt;

    float* ob  = out;
    float* osc = out + (size_t)n * imtop * 4;
    float* ocl = out + (size_t)n * imtop * 5;

    int it = 0;
    for (; it < imtop; ++it) {
        // per-thread scan (tie-break: higher score, then lower global idx)
        float best = -1e30f; int bg = 0x7fffffff; int bl = -1;
        for (int p = t; p < K; p += T) {
            float sv = cscore[base + p];
            int g = cidx[base + p];
            if (sv > best || (sv == best && g < bg)) { best = sv; bg = g; bl = p; }
        }
        // 64-lane shuffle reduce
#pragma unroll
        for (int o = 32; o > 0; o >>= 1) {
            float os = __shfl_down(best, o);
            int   og = __shfl_down(bg, o);
            int   ol = __shfl_down(bl, o);
            if (os > best || (os == best && og < bg)) { best = os; bg = og; bl = ol; }
        }
        if (lane == 0) { wbs[wid] = best; wbg[wid] = bg; wbl[wid] = bl; }
        __syncthreads();
        if (wid == 0) {
            float b2 = (lane < NW) ? wbs[lane] : -1e30f;
            int   g2 = (lane < NW) ? wbg[lane] : 0x7fffffff;
            int   l2 = (lane < NW) ? wbl[lane] : -1;
#pragma unroll
            for (int o = NW / 2; o > 0; o >>= 1) {
                float os = __shfl_down(b2, o);
                int   og = __shfl_down(g2, o);
                int   ol = __shfl_down(l2, o);
                if (os > b2 || (os == b2 && og < g2)) { b2 = os; g2 = og; l2 = ol; }
            }
            if (lane == 0) {
                fS = b2;
                if (b2 > 0.0f) {
                    int lp = l2;
                    size_t oslot = (size_t)img * imtop + it;
                    ob[oslot * 4 + 0] = cbox[(size_t)(base + lp) * 4 + 0];
                    ob[oslot * 4 + 1] = cbox[(size_t)(base + lp) * 4 + 1];
                    ob[oslot * 4 + 2] = cbox[(size_t)(base + lp) * 4 + 2];
                    ob[oslot * 4 + 3] = cbox[(size_t)(base + lp) * 4 + 3];
                    osc[oslot] = b2;
                    ocl[oslot] = (float)(g2 % DCLS + 1);
                    wb0 = cbo[(size_t)(base + lp) * 4 + 0];
                    wb1 = cbo[(size_t)(base + lp) * 4 + 1];
                    wb2 = cbo[(size_t)(base + lp) * 4 + 2];
                    wb3 = cbo[(size_t)(base + lp) * 4 + 3];
                    wa  = carea[base + lp];
                    cscore[base + lp] = -1.0f;
                }
            }
        }
        __syncthreads();
        if (fS <= 0.0f) break;

        float b0 = wb0, b1 = wb1, b2_ = wb2, b3 = wb3, ai = wa;
        for (int p = t; p < K; p += T) {
            float c0 = cbo[(size_t)(base + p) * 4 + 0];
            float c1 = cbo[(size_t)(base + p) * 4 + 1];
            float c2 = cbo[(size_t)(base + p) * 4 + 2];
            float c3 = cbo[(size_t)(base + p) * 4 + 3];
            float iw = fmaxf(fminf(b2_, c2) - fmaxf(b0, c0), 0.0f);
            float ih = fmaxf(fminf(b3, c3) - fmaxf(b1, c1), 0.0f);
            float inter = iw * ih;
            float iou = inter / (ai + carea[base + p] - inter + 1e-6f);
            if (iou > iou_thr) cscore[base + p] = -1.0f;
        }
        __syncthreads();
    }

    for (int q = it + t; q < imtop; q += T) {
        size_t oslot = (size_t)img * imtop + q;
        ob[oslot * 4 + 0] = 0.0f;
        ob[oslot * 4 + 1] = 0.0f;
        ob[oslot * 4 + 2] = 0.0f;
        ob[oslot * 4 + 3] = 0.0f;
        osc[oslot] = 0.0f;
        ocl[oslot] = -1.0f;
    }
}

// ---------------------------------------------------------------------------
extern "C" void kernel_launch(void* const* d_in, const int* in_sizes, int n_in,
                              void* d_out, int out_size, void* d_ws, size_t ws_size,
                              hipStream_t stream)
{
    const float* prop   = (const float*)d_in[0];
    const int*   imidx  = (const int*)d_in[1];
    const float* f0     = (const float*)d_in[2];
    const float* f1     = (const float*)d_in[3];
    const float* f2     = (const float*)d_in[4];
    const float* f3     = (const float*)d_in[5];
    const float* W0     = (const float*)d_in[6];
    const float* b0     = (const float*)d_in[7];
    const float* W1     = (const float*)d_in[8];
    const float* b1     = (const float*)d_in[9];
    const float* Wc     = (const float*)d_in[10];
    const float* bc     = (const float*)d_in[11];
    const float* Wr     = (const float*)d_in[12];
    const float* br     = (const float*)d_in[13];
    const float* imsz   = (const float*)d_in[14];
    const float* sthr   = (const float*)d_in[15];
    const float* ithr   = (const float*)d_in[16];
    const float* msz    = (const float*)d_in[18];

    int R = in_sizes[1];              // 1024
    int n = in_sizes[14] / 2;         // 2
    int imtop = out_size / (n * 6);   // 100
    int M = R * DCLS;                 // 81920
    int K0 = NPOOL * NPOOL * CCH;     // 12544
    int CL = in_sizes[7];             // 1024

    int h0 = (int)(sqrtf((float)(in_sizes[2] / (n * CCH))) + 0.5f);
    int h1 = (int)(sqrtf((float)(in_sizes[3] / (n * CCH))) + 0.5f);
    int h2 = (int)(sqrtf((float)(in_sizes[4] / (n * CCH))) + 0.5f);
    int h3 = (int)(sqrtf((float)(in_sizes[5] / (n * CCH))) + 0.5f);

    float* outf = (float*)d_out;

    // ---- MFMA-path workspace layout (bytes) ----
    size_t szPool  = (size_t)R * K0 * 2;
    size_t szX     = (size_t)R * CL * 4;
    size_t szHead  = (size_t)R * NHEAD * 4;
    size_t szWh    = (size_t)NHEAD * CL * 2;
    size_t szXh    = (size_t)R * CL * 2;
    size_t szW1t   = (size_t)CL * CL * 2;
    size_t szScr   = (size_t)R * DCLS * 4;

    size_t needed = 4 * szPool + 2 * szX + szHead + 2 * szWh
                  + 4 * szXh + 2 * szW1t + szScr;

    const int SP0 = 14;               // Kc = K0/14 = 896 = 28*32
    bool mfma_ok = (ws_size >= needed) && (R % 256 == 0) && (CL % 256 == 0)
                 && (K0 % (SP0 * 32) == 0) && ((R * 49) % 4 == 0);

    if (mfma_ok) {
        uint8_t* w = (uint8_t*)d_ws;
        size_t o = 0;
        _Float16* poolH   = (_Float16*)(w + o); o += szPool;
        _Float16* poolL   = (_Float16*)(w + o); o += szPool;
        _Float16* W0tH    = (_Float16*)(w + o); o += szPool;
        _Float16* W0tL    = (_Float16*)(w + o); o += szPool;
        float*    x0acc   = (float*)(w + o);    o += szX;
        float*    unused  = (float*)(w + o);    o += szX;   // (kept for layout stability)
        float*    headacc = (float*)(w + o);    o += szHead;
        _Float16* WheadtH = (_Float16*)(w + o); o += szWh;
        _Float16* WheadtL = (_Float16*)(w + o); o += szWh;
        _Float16* x0H     = (_Float16*)(w + o); o += szXh;
        _Float16* x0L     = (_Float16*)(w + o); o += szXh;
        _Float16* x1H     = (_Float16*)(w + o); o += szXh;
        _Float16* x1L     = (_Float16*)(w + o); o += szXh;
        _Float16* W1tH    = (_Float16*)(w + o); o += szW1t;
        _Float16* W1tL    = (_Float16*)(w + o); o += szW1t;
        float*    scr     = (float*)(w + o);
        (void)unused;

        // NMS compaction arrays alias the pool region (dead after FC0)
        int*   cidx   = (int*)d_ws;
        float* cscore = (float*)(cidx + (size_t)n * M);
        float* cbo    = cscore + (size_t)n * M;
        float* cbox   = cbo + (size_t)n * M * 4;
        float* carea  = cbox + (size_t)n * M * 4;

        // 0. zero only the split-K accumulator (x0acc, 4 MB)
        {
            int c4 = (int)(szX / 16);
            zero_k<<<dim3((c4 + 255) / 256), dim3(256), 0, stream>>>((float4*)x0acc, c4);
        }
        // 1. weight converts
        convert_w_t_k<<<dim3(K0 / 64, CL / 64), dim3(256), 0, stream>>>(W0, W0tH, W0tL, K0, CL);
        convert_w_t_k<<<dim3(CL / 64, CL / 64), dim3(256), 0, stream>>>(W1, W1tH, W1tL, CL, CL);
        convert_w_t_guard_k<<<dim3(CL / 64, (NCLS + 63) / 64), dim3(256), 0, stream>>>(
            Wc, WheadtH, WheadtL, CL, NCLS, CL, 0);
        convert_w_t_guard_k<<<dim3(CL / 64, (NCLS * 4 + 63) / 64), dim3(256), 0, stream>>>(
            Wr, WheadtH, WheadtL, CL, NCLS * 4, CL, NCLS);
        // 2. RoI align -> f16 hi/lo pooled (4 cells per 256-thr block)
        roi_align_f16v4_k<<<dim3(R * 49 / 4), dim3(256), 0, stream>>>(
            prop, imidx, f0, f1, f2, f3, h0, h1, h2, h3, poolH, poolL);
        // 3. FC0: x0acc = pooled @ W0  (256x256 tile, 4-phase pipeline, split-K 14)
        gemm_mfma_split256_k<<<dim3(SP0 * (R / 256) * (CL / 256)), dim3(512), 0, stream>>>(
            poolH, poolL, W0tH, W0tL, x0acc, R, CL, K0, K0 / SP0, SP0);
        // 4. x0 = relu(x0acc + b0) -> hi/lo
        act_split_k<<<dim3((R * CL / 4 + 255) / 256), dim3(256), 0, stream>>>(
            x0acc, b0, x0H, x0L, R * CL, CL);
        // 5. FC1 fused: x1 = relu(x0 @ W1 + b1) -> hi/lo directly (no atomics)
        gemm_mfma_fused64_k<<<dim3(CL / 64, R / 64), dim3(256), 0, stream>>>(
            x0H, x0L, W1tH, W1tL, b1, nullptr, x1H, x1L, R, CL, CL, 1);
        // 6. combined heads fused: headacc = x1 @ [Wc|Wr] raw fp32 (N=512)
        gemm_mfma_fused64_k<<<dim3(NHEAD / 64, R / 64), dim3(256), 0, stream>>>(
            x1H, x1L, WheadtH, WheadtL, nullptr, headacc, nullptr, nullptr, R, NHEAD, CL, 0);
        // 7. softmax (+bc)
        softmax_k<<<dim3(R), dim3(64), 0, stream>>>(headacc, NHEAD, bc, scr);
        // 8. NMS with fused decode (+br)
        nms_k<<<dim3(n), dim3(NMS_T), 0, stream>>>(
            scr, prop, imidx, headacc, NHEAD, NCLS, br, imsz, sthr, msz, ithr,
            cidx, cscore, cbo, cbox, carea, outf, M, n, imtop);
    } else {
        // -------- fallback: all-fp32 pipeline --------
        float* ws = (float*)d_ws;
        size_t off = 0;
        float* pooled  = ws + off; off += (size_t)R * K0;
        float* x0acc   = ws + off; off += (size_t)R * CL;
        float* x1acc   = ws + off; off += (size_t)R * CL;
        float* logits  = ws + off; off += (size_t)R * NCLS;
        off = (off + 3) & ~(size_t)3;
        float* reg     = ws + off; off += (size_t)R * NCLS * 4;
        float* scr     = ws + off; off += (size_t)R * DCLS;

        int*   cidx   = (int*)ws;
        float* cscore = (float*)(cidx + (size_t)n * M);
        float* cbo    = cscore + (size_t)n * M;
        float* cbox   = cbo + (size_t)n * M * 4;
        float* carea  = cbox + (size_t)n * M * 4;

        {
            size_t zcount = (size_t)(reg + (size_t)R * NCLS * 4 - x0acc);
            int c4 = (int)(zcount / 4);
            zero_k<<<dim3((c4 + 255) / 256), dim3(256), 0, stream>>>((float4*)x0acc, c4);
        }
        roi_align_k<<<dim3(R * 49), dim3(256), 0, stream>>>(
            prop, imidx, f0, f1, f2, f3, h0, h1, h2, h3, pooled);
        gemm_splitk_k<<<dim3(CL / 64, R / 64, 8), dim3(256), 0, stream>>>(
            pooled, W0, nullptr, x0acc, R, CL, K0, 1568);
        gemm_splitk_k<<<dim3(CL / 64, R / 64, 4), dim3(256), 0, stream>>>(
            x0acc, W1, b0, x1acc, R, CL, CL, 256);
        gemm_splitk_k<<<dim3((NCLS + 63) / 64, R / 64, 8), dim3(256), 0, stream>>>(
            x1acc, Wc, b1, logits, R, NCLS, CL, 128);
        gemm_splitk_k<<<dim3((NCLS * 4 + 63) / 64, R / 64, 4), dim3(256), 0, stream>>>(
            x1acc, Wr, b1, reg, R, NCLS * 4, CL, 256);
        softmax_k<<<dim3(R), dim3(64), 0, stream>>>(logits, NCLS, bc, scr);
        nms_k<<<dim3(n), dim3(NMS_T), 0, stream>>>(
            scr, prop, imidx, reg, NCLS * 4, 0, br, imsz, sthr, msz, ithr,
            cidx, cscore, cbo, cbox, carea, outf, M, n, imtop);
    }
}

// Round 2
// 421.870 us; speedup vs baseline: 1.0654x; 1.0654x over previous
//
#include <hip/hip_runtime.h>
#include <math.h>

#define CCH 256
#define NPOOL 7
#define NCLS 81
#define DCLS 80
#define NHEAD 512            /* padded head width: 81 logits + 324 reg + pad */
#define FLOG_MAX 4.1351666f  /* log(1000/16) */

typedef _Float16 half8 __attribute__((ext_vector_type(8)));
typedef _Float16 half4 __attribute__((ext_vector_type(4)));
typedef float floatx4 __attribute__((ext_vector_type(4)));

// ---------------------------------------------------------------------------
// zero a region (float4 stores)
// ---------------------------------------------------------------------------
__global__ void zero_k(float4* __restrict__ p, int count4)
{
    int i = blockIdx.x * blockDim.x + threadIdx.x;
    if (i < count4) p[i] = make_float4(0.f, 0.f, 0.f, 0.f);
}

// ---------------------------------------------------------------------------
// RoI-align box math (per-cell scalar part)
// ---------------------------------------------------------------------------
__device__ __forceinline__ void roi_setup(
    const float* __restrict__ prop, const int* __restrict__ imidx,
    const float* __restrict__ f0, const float* __restrict__ f1,
    const float* __restrict__ f2, const float* __restrict__ f3,
    int h0, int h1, int h2, int h3, int b,
    const float*& base, int& W, size_t& o00, size_t& o01, size_t& o10, size_t& o11,
    float& w00, float& w01, float& w10, float& w11)
{
    int roi = b / 49, p = b % 49;
    int py = p / 7, px = p % 7;

    const float* pr = prop + (size_t)roi * 4;
    float x1 = pr[0], y1 = pr[1], x2 = pr[2], y2 = pr[3];
    float pw = x2 - x1, ph = y2 - y1;

    float lv = floorf(4.0f + log2f(sqrtf(pw * ph) / 224.0f + 1e-6f));
    lv = fminf(fmaxf(lv, 2.0f), 5.0f);
    int lvl = (int)lv - 2;

    const float* fm; int H; float s;
    if (lvl == 0)      { fm = f0; H = h0; s = 0.25f;    }
    else if (lvl == 1) { fm = f1; H = h1; s = 0.125f;   }
    else if (lvl == 2) { fm = f2; H = h2; s = 0.0625f;  }
    else               { fm = f3; H = h3; s = 0.03125f; }
    W = H;

    float xs1 = x1 * s, ys1 = y1 * s, xs2 = x2 * s, ys2 = y2 * s;
    float gx = (px + 0.5f) / 7.0f, gy = (py + 0.5f) / 7.0f;
    float xx = xs1 + gx * (xs2 - xs1) - 0.5f;
    float yy = ys1 + gy * (ys2 - ys1) - 0.5f;
    float x0f = floorf(xx), y0f = floorf(yy);
    float wx = xx - x0f, wy = yy - y0f;
    int x0i = min(max((int)x0f, 0), W - 1);
    int x1i = min(max((int)x0f + 1, 0), W - 1);
    int y0i = min(max((int)y0f, 0), H - 1);
    int y1i = min(max((int)y0f + 1, 0), H - 1);

    int ii = imidx[roi];
    base = fm + (size_t)ii * H * W * CCH;
    o00 = ((size_t)y0i * W + x0i) * CCH;
    o01 = ((size_t)y0i * W + x1i) * CCH;
    o10 = ((size_t)y1i * W + x0i) * CCH;
    o11 = ((size_t)y1i * W + x1i) * CCH;
    w00 = (1.0f - wx) * (1.0f - wy);
    w01 = wx * (1.0f - wy);
    w10 = (1.0f - wx) * wy;
    w11 = wx * wy;
}

// fp32 fallback variant: grid R*49 x 256 threads
__global__ void roi_align_k(const float* __restrict__ prop,
                            const int* __restrict__ imidx,
                            const float* __restrict__ f0,
                            const float* __restrict__ f1,
                            const float* __restrict__ f2,
                            const float* __restrict__ f3,
                            int h0, int h1, int h2, int h3,
                            float* __restrict__ pooled)
{
    int b = blockIdx.x, c = threadIdx.x;
    const float* base; int W; size_t o00, o01, o10, o11;
    float w00, w01, w10, w11;
    roi_setup(prop, imidx, f0, f1, f2, f3, h0, h1, h2, h3, b,
              base, W, o00, o01, o10, o11, w00, w01, w10, w11);
    float v = base[o00 + c] * w00 + base[o01 + c] * w01
            + base[o10 + c] * w10 + base[o11 + c] * w11;
    pooled[(size_t)b * CCH + c] = v;
}

// f16 hi/lo split: grid R*49/4 blocks x 256 threads; wave w -> cell 4b+w
__global__ __launch_bounds__(256) void roi_align_f16v4_k(
    const float* __restrict__ prop, const int* __restrict__ imidx,
    const float* __restrict__ f0, const float* __restrict__ f1,
    const float* __restrict__ f2, const float* __restrict__ f3,
    int h0, int h1, int h2, int h3,
    _Float16* __restrict__ poolH, _Float16* __restrict__ poolL)
{
    int b = blockIdx.x * 4 + (threadIdx.x >> 6);
    int lane = threadIdx.x & 63;
    const float* base; int W; size_t o00, o01, o10, o11;
    float w00, w01, w10, w11;
    roi_setup(prop, imidx, f0, f1, f2, f3, h0, h1, h2, h3, b,
              base, W, o00, o01, o10, o11, w00, w01, w10, w11);

    int c4 = lane * 4;
    float4 v00 = *(const float4*)(base + o00 + c4);
    float4 v01 = *(const float4*)(base + o01 + c4);
    float4 v10 = *(const float4*)(base + o10 + c4);
    float4 v11 = *(const float4*)(base + o11 + c4);
    const float* p00 = (const float*)&v00;
    const float* p01 = (const float*)&v01;
    const float* p10 = (const float*)&v10;
    const float* p11 = (const float*)&v11;

    half4 h, l;
#pragma unroll
    for (int e = 0; e < 4; ++e) {
        float v = p00[e] * w00 + p01[e] * w01 + p10[e] * w10 + p11[e] * w11;
        _Float16 hh = (_Float16)v;
        h[e] = hh;
        l[e] = (_Float16)(v - (float)hh);
    }
    size_t idx = (size_t)b * CCH + c4;
    *(half4*)(poolH + idx) = h;
    *(half4*)(poolL + idx) = l;
}

// ---------------------------------------------------------------------------
// Transpose-convert: W [K][N] fp32 -> WtH/WtL [N][K] f16 hi/lo.
// ---------------------------------------------------------------------------
__global__ __launch_bounds__(256) void convert_w_t_k(const float* __restrict__ W,
                                                     _Float16* __restrict__ WtH,
                                                     _Float16* __restrict__ WtL,
                                                     int K, int N)
{
    __shared__ float sh[64][65];
    int k0 = blockIdx.x * 64, n0 = blockIdx.y * 64;
    int t = threadIdx.x;
#pragma unroll
    for (int p = 0; p < 4; ++p) {
        int idx = p * 256 + t;
        int kr = idx >> 4, nc = (idx & 15) * 4;
        float4 v = *(const float4*)(W + (size_t)(k0 + kr) * N + n0 + nc);
        sh[kr][nc + 0] = v.x; sh[kr][nc + 1] = v.y;
        sh[kr][nc + 2] = v.z; sh[kr][nc + 3] = v.w;
    }
    __syncthreads();
#pragma unroll
    for (int p = 0; p < 4; ++p) {
        int idx = p * 256 + t;
        int nr = idx >> 4, kc = (idx & 15) * 4;
        half4 h, l;
#pragma unroll
        for (int i = 0; i < 4; ++i) {
            float v = sh[kc + i][nr];
            _Float16 hh = (_Float16)v;
            h[i] = hh;
            l[i] = (_Float16)(v - (float)hh);
        }
        *(half4*)(WtH + (size_t)(n0 + nr) * K + k0 + kc) = h;
        *(half4*)(WtL + (size_t)(n0 + nr) * K + k0 + kc) = l;
    }
}

// Guarded variant for N not multiple of 64; writes rows rowofs+n with stride Kt.
__global__ __launch_bounds__(256) void convert_w_t_guard_k(const float* __restrict__ W,
                                                           _Float16* __restrict__ WtH,
                                                           _Float16* __restrict__ WtL,
                                                           int K, int N, int Kt, int rowofs)
{
    __shared__ float sh[64][65];
    int k0 = blockIdx.x * 64, n0 = blockIdx.y * 64;
    int t = threadIdx.x;
#pragma unroll
    for (int p = 0; p < 4; ++p) {
        int idx = p * 256 + t;
        int kr = idx >> 4, nc = (idx & 15) * 4;
#pragma unroll
        for (int e = 0; e < 4; ++e) {
            int nn = n0 + nc + e;
            sh[kr][nc + e] = (nn < N) ? W[(size_t)(k0 + kr) * N + nn] : 0.0f;
        }
    }
    __syncthreads();
#pragma unroll
    for (int p = 0; p < 4; ++p) {
        int idx = p * 256 + t;
        int nr = idx >> 4, kc = (idx & 15) * 4;
        if (n0 + nr < N) {
            half4 h, l;
#pragma unroll
            for (int i = 0; i < 4; ++i) {
                float v = sh[kc + i][nr];
                _Float16 hh = (_Float16)v;
                h[i] = hh;
                l[i] = (_Float16)(v - (float)hh);
            }
            *(half4*)(WtH + (size_t)(rowofs + n0 + nr) * Kt + k0 + kc) = h;
            *(half4*)(WtL + (size_t)(rowofs + n0 + nr) * Kt + k0 + kc) = l;
        }
    }
}

// ---------------------------------------------------------------------------
// act-split: out = relu(acc + bias) -> f16 hi/lo. 4 elems/thread.
// ---------------------------------------------------------------------------
__global__ void act_split_k(const float* __restrict__ acc,
                            const float* __restrict__ bias,
                            _Float16* __restrict__ outH,
                            _Float16* __restrict__ outL,
                            int total, int CL)
{
    int i = (blockIdx.x * blockDim.x + threadIdx.x) * 4;
    if (i >= total) return;
    int b = i % CL;
    float4 v = *(const float4*)(acc + i);
    float4 bb = *(const float4*)(bias + b);
    const float* pv = (const float*)&v;
    const float* pb = (const float*)&bb;
    half4 h, l;
#pragma unroll
    for (int e = 0; e < 4; ++e) {
        float f = fmaxf(pv[e] + pb[e], 0.0f);
        _Float16 hh = (_Float16)f;
        h[e] = hh;
        l[e] = (_Float16)(f - (float)hh);
    }
    *(half4*)(outH + i) = h;
    *(half4*)(outL + i) = l;
}

// ---------------------------------------------------------------------------
// global->LDS DMA, width 16 (wave-uniform LDS base + lane*16)
// ---------------------------------------------------------------------------
__device__ __forceinline__ void dma16(const _Float16* g, _Float16* l)
{
    __builtin_amdgcn_global_load_lds(
        (const __attribute__((address_space(1))) unsigned int*)g,
        (__attribute__((address_space(3))) unsigned int*)l, 16, 0, 0);
}

// ---------------------------------------------------------------------------
// Split-f16 MFMA GEMM, DMA staging, XCD-pinned 1-D grid:
//   Cacc[M,N] += (Ah+Al)[M][K] @ (Bh+Bl)^T,  Bt given as [N][K].
// 128x128 block tile, BK=32, 256 thr (4 waves, 64x64 each).
// 1-D grid of SP*(M/128)*(N/128); decode z = bid%SP (-> XCD via the
// bid%8 round-robin heuristic: all blocks of one K-slice share an XCD's
// L2), n fastest (A-panel reuse), m slowest. fp32 atomicAdd epilogue.
// Requires M%128==0, N%128==0, Kc%32==0.
// ---------------------------------------------------------------------------
#define LDKE 32   /* halves per LDS row (64 B), unpadded for DMA */

__global__ __launch_bounds__(256) void gemm_mfma_split_k(
    const _Float16* __restrict__ Ah, const _Float16* __restrict__ Al,
    const _Float16* __restrict__ Bh, const _Float16* __restrict__ Bl,
    float* __restrict__ Cacc, int M, int N, int K, int Kc, int SP)
{
    __shared__ _Float16 sAh[128 * LDKE], sAl[128 * LDKE];
    __shared__ _Float16 sBh[128 * LDKE], sBl[128 * LDKE];

    int bid = blockIdx.x;
    int z = bid % SP;
    int q = bid / SP;
    int NT = N >> 7;
    int nn = q % NT;
    int m = q / NT;
    int m0 = m * 128, n0 = nn * 128;
    int kb = z * Kc;
    int ke = min(K, kb + Kc);

    int t = threadIdx.x;
    int lane = t & 63, w = t >> 6;
    int wr = w >> 1, wc = w & 1;          // 2x2 wave grid over 128x128
    int fr = lane & 15;                   // fragment row/col within 16
    int fk = (lane >> 4) * 8;             // fragment k offset (quad*8)

    // DMA mapping: wave w stages row-chunks {2w, 2w+1} (16 rows x 32 halves
    // = 1 KB each) of every array. Lane L -> row_local = L>>2, kq = (L&3)*8.
    int drow = w * 32 + (lane >> 2);
    int dkq = (lane & 3) * 8;
    const _Float16* gAh = Ah + (size_t)(m0 + drow) * K + dkq;
    const _Float16* gAl = Al + (size_t)(m0 + drow) * K + dkq;
    const _Float16* gBh = Bh + (size_t)(n0 + drow) * K + dkq;
    const _Float16* gBl = Bl + (size_t)(n0 + drow) * K + dkq;
    size_t rowskip = (size_t)16 * K;

    _Float16* lAh0 = &sAh[(w * 2 + 0) * 512];
    _Float16* lAh1 = &sAh[(w * 2 + 1) * 512];
    _Float16* lAl0 = &sAl[(w * 2 + 0) * 512];
    _Float16* lAl1 = &sAl[(w * 2 + 1) * 512];
    _Float16* lBh0 = &sBh[(w * 2 + 0) * 512];
    _Float16* lBh1 = &sBh[(w * 2 + 1) * 512];
    _Float16* lBl0 = &sBl[(w * 2 + 0) * 512];
    _Float16* lBl1 = &sBl[(w * 2 + 1) * 512];

    floatx4 acc[4][4] = {};

    for (int k0 = kb; k0 < ke; k0 += 32) {
        dma16(gAh + k0, lAh0);
        dma16(gAh + rowskip + k0, lAh1);
        dma16(gAl + k0, lAl0);
        dma16(gAl + rowskip + k0, lAl1);
        dma16(gBh + k0, lBh0);
        dma16(gBh + rowskip + k0, lBh1);
        dma16(gBl + k0, lBl0);
        dma16(gBl + rowskip + k0, lBl1);
        __syncthreads();   // drains vmcnt -> DMA data visible

        half8 ah[4], al[4], bh[4], bl[4];
#pragma unroll
        for (int i = 0; i < 4; ++i) {
            int ar = wr * 64 + i * 16 + fr;
            ah[i] = *(const half8*)&sAh[ar * LDKE + fk];
            al[i] = *(const half8*)&sAl[ar * LDKE + fk];
            int bc = wc * 64 + i * 16 + fr;
            bh[i] = *(const half8*)&sBh[bc * LDKE + fk];
            bl[i] = *(const half8*)&sBl[bc * LDKE + fk];
        }
#pragma unroll
        for (int i = 0; i < 4; ++i)
#pragma unroll
            for (int j = 0; j < 4; ++j) {
                acc[i][j] = __builtin_amdgcn_mfma_f32_16x16x32_f16(ah[i], bh[j], acc[i][j], 0, 0, 0);
                acc[i][j] = __builtin_amdgcn_mfma_f32_16x16x32_f16(ah[i], bl[j], acc[i][j], 0, 0, 0);
                acc[i][j] = __builtin_amdgcn_mfma_f32_16x16x32_f16(al[i], bh[j], acc[i][j], 0, 0, 0);
            }
        __syncthreads();   // LDS reads complete before next DMA overwrite
    }

    // epilogue: C/D layout col=lane&15, row=(lane>>4)*4+reg
    int rbase = (lane >> 4) * 4;
#pragma unroll
    for (int i = 0; i < 4; ++i)
#pragma unroll
        for (int j = 0; j < 4; ++j) {
            int col = n0 + wc * 64 + j * 16 + fr;
#pragma unroll
            for (int r = 0; r < 4; ++r) {
                int row = m0 + wr * 64 + i * 16 + rbase + r;
                atomicAdd(&Cacc[(size_t)row * N + col], acc[i][j][r]);
            }
        }
}

// ---------------------------------------------------------------------------
// Non-split fused MFMA GEMM, 64x64 tile, full-K accumulation in registers,
// double-buffered LDS 2-phase prefetch (stage next tile while computing
// current; ONE barrier per K-tile — the implicit vmcnt(0)+lgkmcnt(0) in
// __syncthreads makes the staged data visible, and the register dependency
// of MFMA on the ds_reads orders reads before the next overwrite):
//   C = (Ah+Al) @ (Bh+Bl)^T   (3 products)
// mode 0: Cout[row*N+col] = C (raw fp32)
// mode 1: relu(C + bias[col]) -> outH/outL f16 hi/lo
// 256 thr (2x2 waves of 32x32 = 2x2 of 16x16x32). 32 KB LDS.
// Requires M%64==0, N%64==0, K%32==0.
// ---------------------------------------------------------------------------
__global__ __launch_bounds__(256) void gemm_mfma_fused64_k(
    const _Float16* __restrict__ Ah, const _Float16* __restrict__ Al,
    const _Float16* __restrict__ Bh, const _Float16* __restrict__ Bl,
    const float* __restrict__ bias,
    float* __restrict__ Cout,
    _Float16* __restrict__ outH, _Float16* __restrict__ outL,
    int M, int N, int K, int mode)
{
    __shared__ _Float16 sAh[2][64 * LDKE], sAl[2][64 * LDKE];
    __shared__ _Float16 sBh[2][64 * LDKE], sBl[2][64 * LDKE];

    int m0 = blockIdx.y * 64, n0 = blockIdx.x * 64;
    int t = threadIdx.x;
    int lane = t & 63, w = t >> 6;
    int wr = w >> 1, wc = w & 1;          // 2x2 wave grid over 64x64
    int fr = lane & 15;
    int fk = (lane >> 4) * 8;

    // DMA: wave w stages rows [w*16, w*16+16) of all four arrays
    int drow = w * 16 + (lane >> 2);
    int dkq = (lane & 3) * 8;
    const _Float16* gAh = Ah + (size_t)(m0 + drow) * K + dkq;
    const _Float16* gAl = Al + (size_t)(m0 + drow) * K + dkq;
    const _Float16* gBh = Bh + (size_t)(n0 + drow) * K + dkq;
    const _Float16* gBl = Bl + (size_t)(n0 + drow) * K + dkq;
    int lofs = w * 512;

    int nt = K >> 5;

    // prologue: stage tile 0 into buf 0
    dma16(gAh + 0, &sAh[0][lofs]);
    dma16(gAl + 0, &sAl[0][lofs]);
    dma16(gBh + 0, &sBh[0][lofs]);
    dma16(gBl + 0, &sBl[0][lofs]);
    __syncthreads();

    floatx4 acc[2][2] = {};

    for (int tt = 0; tt < nt; ++tt) {
        int c = tt & 1, nb = c ^ 1;
        if (tt + 1 < nt) {
            int k1 = (tt + 1) << 5;
            dma16(gAh + k1, &sAh[nb][lofs]);
            dma16(gAl + k1, &sAl[nb][lofs]);
            dma16(gBh + k1, &sBh[nb][lofs]);
            dma16(gBl + k1, &sBl[nb][lofs]);
        }

        half8 ah[2], av[2], bh[2], bv[2];
#pragma unroll
        for (int i = 0; i < 2; ++i) {
            int ar = wr * 32 + i * 16 + fr;
            ah[i] = *(const half8*)&sAh[c][ar * LDKE + fk];
            av[i] = *(const half8*)&sAl[c][ar * LDKE + fk];
            int bc = wc * 32 + i * 16 + fr;
            bh[i] = *(const half8*)&sBh[c][bc * LDKE + fk];
            bv[i] = *(const half8*)&sBl[c][bc * LDKE + fk];
        }
#pragma unroll
        for (int i = 0; i < 2; ++i)
#pragma unroll
            for (int j = 0; j < 2; ++j) {
                acc[i][j] = __builtin_amdgcn_mfma_f32_16x16x32_f16(ah[i], bh[j], acc[i][j], 0, 0, 0);
                acc[i][j] = __builtin_amdgcn_mfma_f32_16x16x32_f16(ah[i], bv[j], acc[i][j], 0, 0, 0);
                acc[i][j] = __builtin_amdgcn_mfma_f32_16x16x32_f16(av[i], bh[j], acc[i][j], 0, 0, 0);
            }
        __syncthreads();   // staged data visible; all reads of buf c done
    }

    int rbase = (lane >> 4) * 4;
#pragma unroll
    for (int i = 0; i < 2; ++i)
#pragma unroll
        for (int j = 0; j < 2; ++j) {
            int col = n0 + wc * 32 + j * 16 + fr;
#pragma unroll
            for (int r = 0; r < 4; ++r) {
                int row = m0 + wr * 32 + i * 16 + rbase + r;
                float v = acc[i][j][r];
                if (mode == 0) {
                    Cout[(size_t)row * N + col] = v;
                } else {
                    float f = fmaxf(v + bias[col], 0.0f);
                    _Float16 hh = (_Float16)f;
                    outH[(size_t)row * N + col] = hh;
                    outL[(size_t)row * N + col] = (_Float16)(f - (float)hh);
                }
            }
        }
}

// ---------------------------------------------------------------------------
// fp32 split-K GEMM (fallback path only)
// ---------------------------------------------------------------------------
__global__ __launch_bounds__(256) void gemm_splitk_k(const float* __restrict__ A,
                                                     const float* __restrict__ B,
                                                     const float* __restrict__ abias,
                                                     float* __restrict__ Cacc,
                                                     int M, int N, int K, int Kc)
{
    __shared__ float Ast[16][68];
    __shared__ float Bs[16][68];

    int m0 = blockIdx.y * 64, n0 = blockIdx.x * 64;
    int kb = blockIdx.z * Kc;
    int ke = min(K, kb + Kc);
    int tid = threadIdx.x;
    int tx = tid & 15, ty = tid >> 4;
    int arow = tid >> 2, akq = (tid & 3) << 2;
    int bcol = tid & 63, bk = tid >> 6;

    const float* Arow = A + (size_t)(m0 + arow) * K;
    bool nfull = (n0 + 64 <= N);

    float acc[4][4] = {};

    for (int k0 = kb; k0 < ke; k0 += 16) {
        float4 av = *(const float4*)(Arow + k0 + akq);
        if (abias) {
            av.x = fmaxf(av.x + abias[k0 + akq + 0], 0.0f);
            av.y = fmaxf(av.y + abias[k0 + akq + 1], 0.0f);
            av.z = fmaxf(av.z + abias[k0 + akq + 2], 0.0f);
            av.w = fmaxf(av.w + abias[k0 + akq + 3], 0.0f);
        }
        float bv[4];
        if (nfull) {
#pragma unroll
            for (int e = 0; e < 4; ++e)
                bv[e] = B[(size_t)(k0 + bk * 4 + e) * N + n0 + bcol];
        } else {
            bool ok = (n0 + bcol) < N;
#pragma unroll
            for (int e = 0; e < 4; ++e)
                bv[e] = ok ? B[(size_t)(k0 + bk * 4 + e) * N + n0 + bcol] : 0.0f;
        }
        __syncthreads();
        Ast[akq + 0][arow] = av.x;
        Ast[akq + 1][arow] = av.y;
        Ast[akq + 2][arow] = av.z;
        Ast[akq + 3][arow] = av.w;
#pragma unroll
        for (int e = 0; e < 4; ++e) Bs[bk * 4 + e][bcol] = bv[e];
        __syncthreads();

#pragma unroll
        for (int kk = 0; kk < 16; ++kk) {
            float4 af = *(const float4*)&Ast[kk][ty * 4];
            float4 bf = *(const float4*)&Bs[kk][tx * 4];
            float a_[4] = {af.x, af.y, af.z, af.w};
            float b_[4] = {bf.x, bf.y, bf.z, bf.w};
#pragma unroll
            for (int i = 0; i < 4; ++i)
#pragma unroll
                for (int j = 0; j < 4; ++j)
                    acc[i][j] = fmaf(a_[i], b_[j], acc[i][j]);
        }
    }

#pragma unroll
    for (int i = 0; i < 4; ++i) {
        int row = m0 + ty * 4 + i;
#pragma unroll
        for (int j = 0; j < 4; ++j) {
            int col = n0 + tx * 4 + j;
            if (col < N) atomicAdd(&Cacc[(size_t)row * N + col], acc[i][j]);
        }
    }
}

// ---------------------------------------------------------------------------
// softmax over (logits + bc), classes 1..80. grid = R, block = 64.
// ---------------------------------------------------------------------------
__global__ void softmax_k(const float* __restrict__ logits, int ldl,
                          const float* __restrict__ bc,
                          float* __restrict__ scr)
{
    int r = blockIdx.x;
    int t = threadIdx.x;
    const float* row = logits + (size_t)r * ldl;

    float v0 = row[t] + bc[t];
    float v1 = (t + 64 < NCLS) ? (row[t + 64] + bc[t + 64]) : -INFINITY;
    float m = fmaxf(v0, v1);
#pragma unroll
    for (int o = 32; o > 0; o >>= 1) m = fmaxf(m, __shfl_down(m, o));
    m = __shfl(m, 0);

    float e0 = expf(v0 - m);
    float e1 = (t + 64 < NCLS) ? expf(v1 - m) : 0.0f;
    float sum = e0 + e1;
#pragma unroll
    for (int o = 32; o > 0; o >>= 1) sum += __shfl_down(sum, o);
    sum = __shfl(sum, 0);
    float inv = 1.0f / sum;

    if (t >= 1)        scr[(size_t)r * DCLS + (t - 1)]  = e0 * inv;
    if (t + 64 < NCLS) scr[(size_t)r * DCLS + (t + 63)] = e1 * inv;
}

// ---------------------------------------------------------------------------
// per-image NMS with fused box decode. grid = n, block = 1024.
// Pick loop is REGISTER-RESIDENT: after compaction each thread owns up to
// NMS_CPT candidates in registers (score, offset-box, area, global idx).
// Per pick: static-unrolled local argmax -> 64-lane shuffle reduce carrying
// (score,g,p,box,area) -> 16 wave leaders in LDS -> wave-0 shuffle reduce ->
// LDS broadcast -> in-register IoU suppression. NO global memory on the
// critical path; 2 syncthreads/pick. Winner's owner thread writes the
// output slot (cbox reload, L2-hot, off critical path).
// Fallback to global-memory loop if K > NMS_T*NMS_CPT.
// ---------------------------------------------------------------------------
#define NMS_T 1024
#define NMS_CPT 8
__global__ __launch_bounds__(NMS_T) void nms_k(
    const float* __restrict__ scr,
    const float* __restrict__ prop,
    const int* __restrict__ imidx,
    const float* __restrict__ head, int ldh, int regofs,
    const float* __restrict__ br,
    const float* __restrict__ imsz,
    const float* __restrict__ score_thr_p,
    const float* __restrict__ min_size_p,
    const float* __restrict__ iou_thr_p,
    int* __restrict__ cidx,
    float* __restrict__ cscore,
    float* __restrict__ cbo,
    float* __restrict__ cbox,
    float* __restrict__ carea,
    float* __restrict__ out,
    int M, int n, int imtop)
{
    int img = blockIdx.x;
    int t = threadIdx.x;
    const int T = NMS_T;
    const int NW = NMS_T / 64;
    int lane = t & 63, wid = t >> 6;

    __shared__ int cnt;
    __shared__ float ws_sc[NW], ws_o0[NW], ws_o1[NW], ws_o2[NW], ws_o3[NW], ws_ar[NW];
    __shared__ int ws_g[NW], ws_p[NW];
    __shared__ float f_sc, f_o0, f_o1, f_o2, f_o3, f_ar;
    __shared__ int f_g, f_p;

    if (t == 0) cnt = 0;
    __syncthreads();

    float score_thr = score_thr_p[0];
    float min_size  = min_size_p[0];
    float iou_thr   = iou_thr_p[0];
    float immax = imsz[0];
    for (int q = 1; q < 2 * n; ++q) immax = fmaxf(immax, imsz[q]);

    int base = img * M;
    for (int j = t; j < M; j += T) {
        int r = j / DCLS;
        if (imidx[r] != img) continue;
        float s = scr[j];
        if (s <= score_thr) continue;

        int cls = j - r * DCLS + 1;
        const float* pr = prop + (size_t)r * 4;
        float pw = pr[2] - pr[0], ph = pr[3] - pr[1];
        float cx = (pr[0] + pr[2]) * 0.5f, cy = (pr[1] + pr[3]) * 0.5f;
        const float* rg_ = head + (size_t)r * ldh + regofs + cls * 4;
        const float* bb = br + cls * 4;
        float dx = (rg_[0] + bb[0]) * 0.1f;
        float dy = (rg_[1] + bb[1]) * 0.1f;
        float dw = fminf((rg_[2] + bb[2]) * 0.2f, FLOG_MAX);
        float dh = fminf((rg_[3] + bb[3]) * 0.2f, FLOG_MAX);
        float ncx = dx * pw + cx;
        float ncy = dy * ph + cy;
        float nw = expf(dw) * pw;
        float nh = expf(dh) * ph;
        float hbound = imsz[img * 2 + 0];
        float wbound = imsz[img * 2 + 1];
        float bx1 = fminf(fmaxf(ncx - nw * 0.5f, 0.0f), wbound);
        float bx2 = fminf(fmaxf(ncx + nw * 0.5f, 0.0f), wbound);
        float by1 = fminf(fmaxf(ncy - nh * 0.5f, 0.0f), hbound);
        float by2 = fminf(fmaxf(ncy + nh * 0.5f, 0.0f), hbound);
        if (bx2 - bx1 < min_size || by2 - by1 < min_size) continue;

        float off = (float)cls * (immax + 2.0f);
        int p = atomicAdd(&cnt, 1);
        cidx[base + p] = j;
        cscore[base + p] = s;
        cbox[(size_t)(base + p) * 4 + 0] = bx1;
        cbox[(size_t)(base + p) * 4 + 1] = by1;
        cbox[(size_t)(base + p) * 4 + 2] = bx2;
        cbox[(size_t)(base + p) * 4 + 3] = by2;
        cbo[(size_t)(base + p) * 4 + 0] = bx1 + off;
        cbo[(size_t)(base + p) * 4 + 1] = by1 + off;
        cbo[(size_t)(base + p) * 4 + 2] = bx2 + off;
        cbo[(size_t)(base + p) * 4 + 3] = by2 + off;
        carea[base + p] = (bx2 - bx1) * (by2 - by1);
    }
    __syncthreads();
    int K = cnt;

    float* ob  = out;
    float* osc = out + (size_t)n * imtop * 4;
    float* ocl = out + (size_t)n * imtop * 5;

    int it = 0;
    if (K <= T * NMS_CPT) {
        // ---------------- register-resident pick loop ----------------
        float rsc[NMS_CPT], ro0[NMS_CPT], ro1[NMS_CPT], ro2[NMS_CPT], ro3[NMS_CPT], rar[NMS_CPT];
        int rgi[NMS_CPT];
#pragma unroll
        for (int s = 0; s < NMS_CPT; ++s) {
            int p = t + s * T;
            bool ok = p < K;
            rsc[s] = ok ? cscore[base + p] : -1e30f;
            rgi[s] = ok ? cidx[base + p] : 0x7fffffff;
            ro0[s] = ok ? cbo[(size_t)(base + p) * 4 + 0] : 0.0f;
            ro1[s] = ok ? cbo[(size_t)(base + p) * 4 + 1] : 0.0f;
            ro2[s] = ok ? cbo[(size_t)(base + p) * 4 + 2] : 0.0f;
            ro3[s] = ok ? cbo[(size_t)(base + p) * 4 + 3] : 0.0f;
            rar[s] = ok ? carea[base + p] : 0.0f;
        }

        for (; it < imtop; ++it) {
            // local argmax (static indices only)
            float bsc = -1e30f; int bg = 0x7fffffff, bp = -1;
            float b0 = 0.f, b1 = 0.f, b2 = 0.f, b3 = 0.f, ba = 0.f;
#pragma unroll
            for (int s = 0; s < NMS_CPT; ++s) {
                if (rsc[s] > bsc || (rsc[s] == bsc && rgi[s] < bg)) {
                    bsc = rsc[s]; bg = rgi[s]; bp = t + s * T;
                    b0 = ro0[s]; b1 = ro1[s]; b2 = ro2[s]; b3 = ro3[s]; ba = rar[s];
                }
            }
            // 64-lane shuffle reduce carrying everything
#pragma unroll
            for (int o = 32; o > 0; o >>= 1) {
                float os = __shfl_down(bsc, o);
                int   og = __shfl_down(bg, o);
                int   op = __shfl_down(bp, o);
                float q0 = __shfl_down(b0, o), q1 = __shfl_down(b1, o);
                float q2 = __shfl_down(b2, o), q3 = __shfl_down(b3, o);
                float qa = __shfl_down(ba, o);
                if (os > bsc || (os == bsc && og < bg)) {
                    bsc = os; bg = og; bp = op;
                    b0 = q0; b1 = q1; b2 = q2; b3 = q3; ba = qa;
                }
            }
            if (lane == 0) {
                ws_sc[wid] = bsc; ws_g[wid] = bg; ws_p[wid] = bp;
                ws_o0[wid] = b0; ws_o1[wid] = b1; ws_o2[wid] = b2; ws_o3[wid] = b3;
                ws_ar[wid] = ba;
            }
            __syncthreads();
            if (wid == 0) {
                float s2 = (lane < NW) ? ws_sc[lane] : -1e30f;
                int   g2 = (lane < NW) ? ws_g[lane] : 0x7fffffff;
                int   p2 = (lane < NW) ? ws_p[lane] : -1;
                float c0 = (lane < NW) ? ws_o0[lane] : 0.f;
                float c1 = (lane < NW) ? ws_o1[lane] : 0.f;
                float c2 = (lane < NW) ? ws_o2[lane] : 0.f;
                float c3 = (lane < NW) ? ws_o3[lane] : 0.f;
                float ca = (lane < NW) ? ws_ar[lane] : 0.f;
#pragma unroll
                for (int o = NW / 2; o > 0; o >>= 1) {
                    float os = __shfl_down(s2, o);
                    int   og = __shfl_down(g2, o);
                    int   op = __shfl_down(p2, o);
                    float q0 = __shfl_down(c0, o), q1 = __shfl_down(c1, o);
                    float q2 = __shfl_down(c2, o), q3 = __shfl_down(c3, o);
                    float qa = __shfl_down(ca, o);
                    if (os > s2 || (os == s2 && og < g2)) {
                        s2 = os; g2 = og; p2 = op;
                        c0 = q0; c1 = q1; c2 = q2; c3 = q3; ca = qa;
                    }
                }
                if (lane == 0) {
                    f_sc = s2; f_g = g2; f_p = p2;
                    f_o0 = c0; f_o1 = c1; f_o2 = c2; f_o3 = c3; f_ar = ca;
                }
            }
            __syncthreads();
            float wsc = f_sc;
            if (wsc <= 0.0f) break;
            float w0 = f_o0, w1 = f_o1, w2 = f_o2, w3 = f_o3, wa = f_ar;
            int wp = f_p, wg = f_g;

            // winner's owner thread: write output slot + kill own candidate
#pragma unroll
            for (int s = 0; s < NMS_CPT; ++s) {
                if (t + s * T == wp) {
                    size_t oslot = (size_t)img * imtop + it;
                    ob[oslot * 4 + 0] = cbox[(size_t)(base + wp) * 4 + 0];
                    ob[oslot * 4 + 1] = cbox[(size_t)(base + wp) * 4 + 1];
                    ob[oslot * 4 + 2] = cbox[(size_t)(base + wp) * 4 + 2];
                    ob[oslot * 4 + 3] = cbox[(size_t)(base + wp) * 4 + 3];
                    osc[oslot] = wsc;
                    ocl[oslot] = (float)(wg % DCLS + 1);
                    rsc[s] = -1e30f;
                }
            }
            // in-register suppression
#pragma unroll
            for (int s = 0; s < NMS_CPT; ++s) {
                float iw = fmaxf(fminf(w2, ro2[s]) - fmaxf(w0, ro0[s]), 0.0f);
                float ih = fmaxf(fminf(w3, ro3[s]) - fmaxf(w1, ro1[s]), 0.0f);
                float inter = iw * ih;
                float iou = inter / (wa + rar[s] - inter + 1e-6f);
                if (iou > iou_thr) rsc[s] = -1e30f;
            }
        }
    } else {
        // ---------------- fallback: global-memory pick loop ----------------
        for (; it < imtop; ++it) {
            float best = -1e30f; int bg = 0x7fffffff; int bl = -1;
            for (int p = t; p < K; p += T) {
                float sv = cscore[base + p];
                int g = cidx[base + p];
                if (sv > best || (sv == best && g < bg)) { best = sv; bg = g; bl = p; }
            }
#pragma unroll
            for (int o = 32; o > 0; o >>= 1) {
                float os = __shfl_down(best, o);
                int   og = __shfl_down(bg, o);
                int   ol = __shfl_down(bl, o);
                if (os > best || (os == best && og < bg)) { best = os; bg = og; bl = ol; }
            }
            if (lane == 0) { ws_sc[wid] = best; ws_g[wid] = bg; ws_p[wid] = bl; }
            __syncthreads();
            if (wid == 0) {
                float b2 = (lane < NW) ? ws_sc[lane] : -1e30f;
                int   g2 = (lane < NW) ? ws_g[lane] : 0x7fffffff;
                int   l2 = (lane < NW) ? ws_p[lane] : -1;
#pragma unroll
                for (int o = NW / 2; o > 0; o >>= 1) {
                    float os = __shfl_down(b2, o);
                    int   og = __shfl_down(g2, o);
                    int   ol = __shfl_down(l2, o);
                    if (os > b2 || (os == b2 && og < g2)) { b2 = os; g2 = og; l2 = ol; }
                }
                if (lane == 0) {
                    f_sc = b2;
                    if (b2 > 0.0f) {
                        int lp = l2;
                        size_t oslot = (size_t)img * imtop + it;
                        ob[oslot * 4 + 0] = cbox[(size_t)(base + lp) * 4 + 0];
                        ob[oslot * 4 + 1] = cbox[(size_t)(base + lp) * 4 + 1];
                        ob[oslot * 4 + 2] = cbox[(size_t)(base + lp) * 4 + 2];
                        ob[oslot * 4 + 3] = cbox[(size_t)(base + lp) * 4 + 3];
                        osc[oslot] = b2;
                        ocl[oslot] = (float)(g2 % DCLS + 1);
                        f_o0 = cbo[(size_t)(base + lp) * 4 + 0];
                        f_o1 = cbo[(size_t)(base + lp) * 4 + 1];
                        f_o2 = cbo[(size_t)(base + lp) * 4 + 2];
                        f_o3 = cbo[(size_t)(base + lp) * 4 + 3];
                        f_ar = carea[base + lp];
                        cscore[base + lp] = -1.0f;
                    }
                }
            }
            __syncthreads();
            if (f_sc <= 0.0f) break;

            float b0 = f_o0, b1 = f_o1, b2_ = f_o2, b3 = f_o3, ai = f_ar;
            for (int p = t; p < K; p += T) {
                float c0 = cbo[(size_t)(base + p) * 4 + 0];
                float c1 = cbo[(size_t)(base + p) * 4 + 1];
                float c2 = cbo[(size_t)(base + p) * 4 + 2];
                float c3 = cbo[(size_t)(base + p) * 4 + 3];
                float iw = fmaxf(fminf(b2_, c2) - fmaxf(b0, c0), 0.0f);
                float ih = fmaxf(fminf(b3, c3) - fmaxf(b1, c1), 0.0f);
                float inter = iw * ih;
                float iou = inter / (ai + carea[base + p] - inter + 1e-6f);
                if (iou > iou_thr) cscore[base + p] = -1.0f;
            }
            __syncthreads();
        }
    }

    for (int q = it + t; q < imtop; q += T) {
        size_t oslot = (size_t)img * imtop + q;
        ob[oslot * 4 + 0] = 0.0f;
        ob[oslot * 4 + 1] = 0.0f;
        ob[oslot * 4 + 2] = 0.0f;
        ob[oslot * 4 + 3] = 0.0f;
        osc[oslot] = 0.0f;
        ocl[oslot] = -1.0f;
    }
}

// ---------------------------------------------------------------------------
extern "C" void kernel_launch(void* const* d_in, const int* in_sizes, int n_in,
                              void* d_out, int out_size, void* d_ws, size_t ws_size,
                              hipStream_t stream)
{
    const float* prop   = (const float*)d_in[0];
    const int*   imidx  = (const int*)d_in[1];
    const float* f0     = (const float*)d_in[2];
    const float* f1     = (const float*)d_in[3];
    const float* f2     = (const float*)d_in[4];
    const float* f3     = (const float*)d_in[5];
    const float* W0     = (const float*)d_in[6];
    const float* b0     = (const float*)d_in[7];
    const float* W1     = (const float*)d_in[8];
    const float* b1     = (const float*)d_in[9];
    const float* Wc     = (const float*)d_in[10];
    const float* bc     = (const float*)d_in[11];
    const float* Wr     = (const float*)d_in[12];
    const float* br     = (const float*)d_in[13];
    const float* imsz   = (const float*)d_in[14];
    const float* sthr   = (const float*)d_in[15];
    const float* ithr   = (const float*)d_in[16];
    const float* msz    = (const float*)d_in[18];

    int R = in_sizes[1];              // 1024
    int n = in_sizes[14] / 2;         // 2
    int imtop = out_size / (n * 6);   // 100
    int M = R * DCLS;                 // 81920
    int K0 = NPOOL * NPOOL * CCH;     // 12544
    int CL = in_sizes[7];             // 1024

    int h0 = (int)(sqrtf((float)(in_sizes[2] / (n * CCH))) + 0.5f);
    int h1 = (int)(sqrtf((float)(in_sizes[3] / (n * CCH))) + 0.5f);
    int h2 = (int)(sqrtf((float)(in_sizes[4] / (n * CCH))) + 0.5f);
    int h3 = (int)(sqrtf((float)(in_sizes[5] / (n * CCH))) + 0.5f);

    float* outf = (float*)d_out;

    // ---- MFMA-path workspace layout (bytes) ----
    size_t szPool  = (size_t)R * K0 * 2;
    size_t szX     = (size_t)R * CL * 4;
    size_t szHead  = (size_t)R * NHEAD * 4;
    size_t szWh    = (size_t)NHEAD * CL * 2;
    size_t szXh    = (size_t)R * CL * 2;
    size_t szW1t   = (size_t)CL * CL * 2;
    size_t szScr   = (size_t)R * DCLS * 4;

    size_t needed = 4 * szPool + 2 * szX + szHead + 2 * szWh
                  + 4 * szXh + 2 * szW1t + szScr;

    int splitK0 = 8;                  // Kc = K0/8 = 1568 = 49*32
    bool mfma_ok = (ws_size >= needed) && (R % 128 == 0) && (CL % 128 == 0)
                 && (K0 % (splitK0 * 32) == 0) && (CL % 32 == 0)
                 && ((R * 49) % 4 == 0);

    if (mfma_ok) {
        uint8_t* w = (uint8_t*)d_ws;
        size_t o = 0;
        _Float16* poolH   = (_Float16*)(w + o); o += szPool;
        _Float16* poolL   = (_Float16*)(w + o); o += szPool;
        _Float16* W0tH    = (_Float16*)(w + o); o += szPool;
        _Float16* W0tL    = (_Float16*)(w + o); o += szPool;
        float*    x0acc   = (float*)(w + o);    o += szX;
        float*    unused  = (float*)(w + o);    o += szX;   // (kept for layout stability)
        float*    headacc = (float*)(w + o);    o += szHead;
        _Float16* WheadtH = (_Float16*)(w + o); o += szWh;
        _Float16* WheadtL = (_Float16*)(w + o); o += szWh;
        _Float16* x0H     = (_Float16*)(w + o); o += szXh;
        _Float16* x0L     = (_Float16*)(w + o); o += szXh;
        _Float16* x1H     = (_Float16*)(w + o); o += szXh;
        _Float16* x1L     = (_Float16*)(w + o); o += szXh;
        _Float16* W1tH    = (_Float16*)(w + o); o += szW1t;
        _Float16* W1tL    = (_Float16*)(w + o); o += szW1t;
        float*    scr     = (float*)(w + o);
        (void)unused;

        // NMS compaction arrays alias the pool region (dead after FC0)
        int*   cidx   = (int*)d_ws;
        float* cscore = (float*)(cidx + (size_t)n * M);
        float* cbo    = cscore + (size_t)n * M;
        float* cbox   = cbo + (size_t)n * M * 4;
        float* carea  = cbox + (size_t)n * M * 4;

        // 0. zero only the split-K accumulator (x0acc, 4 MB)
        {
            int c4 = (int)(szX / 16);
            zero_k<<<dim3((c4 + 255) / 256), dim3(256), 0, stream>>>((float4*)x0acc, c4);
        }
        // 1. weight converts
        convert_w_t_k<<<dim3(K0 / 64, CL / 64), dim3(256), 0, stream>>>(W0, W0tH, W0tL, K0, CL);
        convert_w_t_k<<<dim3(CL / 64, CL / 64), dim3(256), 0, stream>>>(W1, W1tH, W1tL, CL, CL);
        convert_w_t_guard_k<<<dim3(CL / 64, (NCLS + 63) / 64), dim3(256), 0, stream>>>(
            Wc, WheadtH, WheadtL, CL, NCLS, CL, 0);
        convert_w_t_guard_k<<<dim3(CL / 64, (NCLS * 4 + 63) / 64), dim3(256), 0, stream>>>(
            Wr, WheadtH, WheadtL, CL, NCLS * 4, CL, NCLS);
        // 2. RoI align -> f16 hi/lo pooled (4 cells per 256-thr block)
        roi_align_f16v4_k<<<dim3(R * 49 / 4), dim3(256), 0, stream>>>(
            prop, imidx, f0, f1, f2, f3, h0, h1, h2, h3, poolH, poolL);
        // 3. FC0: x0acc = pooled @ W0  (split-K 8, XCD-pinned 1-D grid of 512)
        gemm_mfma_split_k<<<dim3(splitK0 * (R / 128) * (CL / 128)), dim3(256), 0, stream>>>(
            poolH, poolL, W0tH, W0tL, x0acc, R, CL, K0, K0 / splitK0, splitK0);
        // 4. x0 = relu(x0acc + b0) -> hi/lo
        act_split_k<<<dim3((R * CL / 4 + 255) / 256), dim3(256), 0, stream>>>(
            x0acc, b0, x0H, x0L, R * CL, CL);
        // 5. FC1 fused: x1 = relu(x0 @ W1 + b1) -> hi/lo directly (no atomics)
        gemm_mfma_fused64_k<<<dim3(CL / 64, R / 64), dim3(256), 0, stream>>>(
            x0H, x0L, W1tH, W1tL, b1, nullptr, x1H, x1L, R, CL, CL, 1);
        // 6. combined heads fused: headacc = x1 @ [Wc|Wr] raw fp32 (N=512)
        gemm_mfma_fused64_k<<<dim3(NHEAD / 64, R / 64), dim3(256), 0, stream>>>(
            x1H, x1L, WheadtH, WheadtL, nullptr, headacc, nullptr, nullptr, R, NHEAD, CL, 0);
        // 7. softmax (+bc)
        softmax_k<<<dim3(R), dim3(64), 0, stream>>>(headacc, NHEAD, bc, scr);
        // 8. NMS with fused decode (+br)
        nms_k<<<dim3(n), dim3(NMS_T), 0, stream>>>(
            scr, prop, imidx, headacc, NHEAD, NCLS, br, imsz, sthr, msz, ithr,
            cidx, cscore, cbo, cbox, carea, outf, M, n, imtop);
    } else {
        // -------- fallback: all-fp32 pipeline --------
        float* ws = (float*)d_ws;
        size_t off = 0;
        float* pooled  = ws + off; off += (size_t)R * K0;
        float* x0acc   = ws + off; off += (size_t)R * CL;
        float* x1acc   = ws + off; off += (size_t)R * CL;
        float* logits  = ws + off; off += (size_t)R * NCLS;
        off = (off + 3) & ~(size_t)3;
        float* reg     = ws + off; off += (size_t)R * NCLS * 4;
        float* scr     = ws + off; off += (size_t)R * DCLS;

        int*   cidx   = (int*)ws;
        float* cscore = (float*)(cidx + (size_t)n * M);
        float* cbo    = cscore + (size_t)n * M;
        float* cbox   = cbo + (size_t)n * M * 4;
        float* carea  = cbox + (size_t)n * M * 4;

        {
            size_t zcount = (size_t)(reg + (size_t)R * NCLS * 4 - x0acc);
            int c4 = (int)(zcount / 4);
            zero_k<<<dim3((c4 + 255) / 256), dim3(256), 0, stream>>>((float4*)x0acc, c4);
        }
        roi_align_k<<<dim3(R * 49), dim3(256), 0, stream>>>(
            prop, imidx, f0, f1, f2, f3, h0, h1, h2, h3, pooled);
        gemm_splitk_k<<<dim3(CL / 64, R / 64, 8), dim3(256), 0, stream>>>(
            pooled, W0, nullptr, x0acc, R, CL, K0, 1568);
        gemm_splitk_k<<<dim3(CL / 64, R / 64, 4), dim3(256), 0, stream>>>(
            x0acc, W1, b0, x1acc, R, CL, CL, 256);
        gemm_splitk_k<<<dim3((NCLS + 63) / 64, R / 64, 8), dim3(256), 0, stream>>>(
            x1acc, Wc, b1, logits, R, NCLS, CL, 128);
        gemm_splitk_k<<<dim3((NCLS * 4 + 63) / 64, R / 64, 4), dim3(256), 0, stream>>>(
            x1acc, Wr, b1, reg, R, NCLS * 4, CL, 256);
        softmax_k<<<dim3(R), dim3(64), 0, stream>>>(logits, NCLS, bc, scr);
        nms_k<<<dim3(n), dim3(NMS_T), 0, stream>>>(
            scr, prop, imidx, reg, NCLS * 4, 0, br, imsz, sthr, msz, ithr,
            cidx, cscore, cbo, cbox, carea, outf, M, n, imtop);
    }
}

// Round 3
// 419.391 us; speedup vs baseline: 1.0717x; 1.0059x over previous
//
#include <hip/hip_runtime.h>
#include <math.h>

#define CCH 256
#define NPOOL 7
#define NCLS 81
#define DCLS 80
#define NHEAD 512            /* padded head width: 81 logits + 324 reg + pad */
#define FLOG_MAX 4.1351666f  /* log(1000/16) */

typedef _Float16 half8 __attribute__((ext_vector_type(8)));
typedef _Float16 half4 __attribute__((ext_vector_type(4)));
typedef float floatx4 __attribute__((ext_vector_type(4)));

// ---------------------------------------------------------------------------
// zero a region (float4 stores)
// ---------------------------------------------------------------------------
__global__ void zero_k(float4* __restrict__ p, int count4)
{
    int i = blockIdx.x * blockDim.x + threadIdx.x;
    if (i < count4) p[i] = make_float4(0.f, 0.f, 0.f, 0.f);
}

// ---------------------------------------------------------------------------
// RoI-align box math (per-cell scalar part)
// ---------------------------------------------------------------------------
__device__ __forceinline__ void roi_setup(
    const float* __restrict__ prop, const int* __restrict__ imidx,
    const float* __restrict__ f0, const float* __restrict__ f1,
    const float* __restrict__ f2, const float* __restrict__ f3,
    int h0, int h1, int h2, int h3, int b,
    const float*& base, int& W, size_t& o00, size_t& o01, size_t& o10, size_t& o11,
    float& w00, float& w01, float& w10, float& w11)
{
    int roi = b / 49, p = b % 49;
    int py = p / 7, px = p % 7;

    const float* pr = prop + (size_t)roi * 4;
    float x1 = pr[0], y1 = pr[1], x2 = pr[2], y2 = pr[3];
    float pw = x2 - x1, ph = y2 - y1;

    float lv = floorf(4.0f + log2f(sqrtf(pw * ph) / 224.0f + 1e-6f));
    lv = fminf(fmaxf(lv, 2.0f), 5.0f);
    int lvl = (int)lv - 2;

    const float* fm; int H; float s;
    if (lvl == 0)      { fm = f0; H = h0; s = 0.25f;    }
    else if (lvl == 1) { fm = f1; H = h1; s = 0.125f;   }
    else if (lvl == 2) { fm = f2; H = h2; s = 0.0625f;  }
    else               { fm = f3; H = h3; s = 0.03125f; }
    W = H;

    float xs1 = x1 * s, ys1 = y1 * s, xs2 = x2 * s, ys2 = y2 * s;
    float gx = (px + 0.5f) / 7.0f, gy = (py + 0.5f) / 7.0f;
    float xx = xs1 + gx * (xs2 - xs1) - 0.5f;
    float yy = ys1 + gy * (ys2 - ys1) - 0.5f;
    float x0f = floorf(xx), y0f = floorf(yy);
    float wx = xx - x0f, wy = yy - y0f;
    int x0i = min(max((int)x0f, 0), W - 1);
    int x1i = min(max((int)x0f + 1, 0), W - 1);
    int y0i = min(max((int)y0f, 0), H - 1);
    int y1i = min(max((int)y0f + 1, 0), H - 1);

    int ii = imidx[roi];
    base = fm + (size_t)ii * H * W * CCH;
    o00 = ((size_t)y0i * W + x0i) * CCH;
    o01 = ((size_t)y0i * W + x1i) * CCH;
    o10 = ((size_t)y1i * W + x0i) * CCH;
    o11 = ((size_t)y1i * W + x1i) * CCH;
    w00 = (1.0f - wx) * (1.0f - wy);
    w01 = wx * (1.0f - wy);
    w10 = (1.0f - wx) * wy;
    w11 = wx * wy;
}

// fp32 fallback variant: grid R*49 x 256 threads
__global__ void roi_align_k(const float* __restrict__ prop,
                            const int* __restrict__ imidx,
                            const float* __restrict__ f0,
                            const float* __restrict__ f1,
                            const float* __restrict__ f2,
                            const float* __restrict__ f3,
                            int h0, int h1, int h2, int h3,
                            float* __restrict__ pooled)
{
    int b = blockIdx.x, c = threadIdx.x;
    const float* base; int W; size_t o00, o01, o10, o11;
    float w00, w01, w10, w11;
    roi_setup(prop, imidx, f0, f1, f2, f3, h0, h1, h2, h3, b,
              base, W, o00, o01, o10, o11, w00, w01, w10, w11);
    float v = base[o00 + c] * w00 + base[o01 + c] * w01
            + base[o10 + c] * w10 + base[o11 + c] * w11;
    pooled[(size_t)b * CCH + c] = v;
}

// f16 hi/lo split: grid R*49/4 blocks x 256 threads; wave w -> cell 4b+w
__global__ __launch_bounds__(256) void roi_align_f16v4_k(
    const float* __restrict__ prop, const int* __restrict__ imidx,
    const float* __restrict__ f0, const float* __restrict__ f1,
    const float* __restrict__ f2, const float* __restrict__ f3,
    int h0, int h1, int h2, int h3,
    _Float16* __restrict__ poolH, _Float16* __restrict__ poolL)
{
    int b = blockIdx.x * 4 + (threadIdx.x >> 6);
    int lane = threadIdx.x & 63;
    const float* base; int W; size_t o00, o01, o10, o11;
    float w00, w01, w10, w11;
    roi_setup(prop, imidx, f0, f1, f2, f3, h0, h1, h2, h3, b,
              base, W, o00, o01, o10, o11, w00, w01, w10, w11);

    int c4 = lane * 4;
    float4 v00 = *(const float4*)(base + o00 + c4);
    float4 v01 = *(const float4*)(base + o01 + c4);
    float4 v10 = *(const float4*)(base + o10 + c4);
    float4 v11 = *(const float4*)(base + o11 + c4);
    const float* p00 = (const float*)&v00;
    const float* p01 = (const float*)&v01;
    const float* p10 = (const float*)&v10;
    const float* p11 = (const float*)&v11;

    half4 h, l;
#pragma unroll
    for (int e = 0; e < 4; ++e) {
        float v = p00[e] * w00 + p01[e] * w01 + p10[e] * w10 + p11[e] * w11;
        _Float16 hh = (_Float16)v;
        h[e] = hh;
        l[e] = (_Float16)(v - (float)hh);
    }
    size_t idx = (size_t)b * CCH + c4;
    *(half4*)(poolH + idx) = h;
    *(half4*)(poolL + idx) = l;
}

// ---------------------------------------------------------------------------
// Transpose-convert: W [K][N] fp32 -> WtH/WtL [N][K] f16 hi/lo.
// ---------------------------------------------------------------------------
__global__ __launch_bounds__(256) void convert_w_t_k(const float* __restrict__ W,
                                                     _Float16* __restrict__ WtH,
                                                     _Float16* __restrict__ WtL,
                                                     int K, int N)
{
    __shared__ float sh[64][65];
    int k0 = blockIdx.x * 64, n0 = blockIdx.y * 64;
    int t = threadIdx.x;
#pragma unroll
    for (int p = 0; p < 4; ++p) {
        int idx = p * 256 + t;
        int kr = idx >> 4, nc = (idx & 15) * 4;
        float4 v = *(const float4*)(W + (size_t)(k0 + kr) * N + n0 + nc);
        sh[kr][nc + 0] = v.x; sh[kr][nc + 1] = v.y;
        sh[kr][nc + 2] = v.z; sh[kr][nc + 3] = v.w;
    }
    __syncthreads();
#pragma unroll
    for (int p = 0; p < 4; ++p) {
        int idx = p * 256 + t;
        int nr = idx >> 4, kc = (idx & 15) * 4;
        half4 h, l;
#pragma unroll
        for (int i = 0; i < 4; ++i) {
            float v = sh[kc + i][nr];
            _Float16 hh = (_Float16)v;
            h[i] = hh;
            l[i] = (_Float16)(v - (float)hh);
        }
        *(half4*)(WtH + (size_t)(n0 + nr) * K + k0 + kc) = h;
        *(half4*)(WtL + (size_t)(n0 + nr) * K + k0 + kc) = l;
    }
}

// Guarded variant for N not multiple of 64; writes rows rowofs+n with stride Kt.
__global__ __launch_bounds__(256) void convert_w_t_guard_k(const float* __restrict__ W,
                                                           _Float16* __restrict__ WtH,
                                                           _Float16* __restrict__ WtL,
                                                           int K, int N, int Kt, int rowofs)
{
    __shared__ float sh[64][65];
    int k0 = blockIdx.x * 64, n0 = blockIdx.y * 64;
    int t = threadIdx.x;
#pragma unroll
    for (int p = 0; p < 4; ++p) {
        int idx = p * 256 + t;
        int kr = idx >> 4, nc = (idx & 15) * 4;
#pragma unroll
        for (int e = 0; e < 4; ++e) {
            int nn = n0 + nc + e;
            sh[kr][nc + e] = (nn < N) ? W[(size_t)(k0 + kr) * N + nn] : 0.0f;
        }
    }
    __syncthreads();
#pragma unroll
    for (int p = 0; p < 4; ++p) {
        int idx = p * 256 + t;
        int nr = idx >> 4, kc = (idx & 15) * 4;
        if (n0 + nr < N) {
            half4 h, l;
#pragma unroll
            for (int i = 0; i < 4; ++i) {
                float v = sh[kc + i][nr];
                _Float16 hh = (_Float16)v;
                h[i] = hh;
                l[i] = (_Float16)(v - (float)hh);
            }
            *(half4*)(WtH + (size_t)(rowofs + n0 + nr) * Kt + k0 + kc) = h;
            *(half4*)(WtL + (size_t)(rowofs + n0 + nr) * Kt + k0 + kc) = l;
        }
    }
}

// ---------------------------------------------------------------------------
// act-split: out = relu(acc + bias) -> f16 hi/lo. 4 elems/thread.
// ---------------------------------------------------------------------------
__global__ void act_split_k(const float* __restrict__ acc,
                            const float* __restrict__ bias,
                            _Float16* __restrict__ outH,
                            _Float16* __restrict__ outL,
                            int total, int CL)
{
    int i = (blockIdx.x * blockDim.x + threadIdx.x) * 4;
    if (i >= total) return;
    int b = i % CL;
    float4 v = *(const float4*)(acc + i);
    float4 bb = *(const float4*)(bias + b);
    const float* pv = (const float*)&v;
    const float* pb = (const float*)&bb;
    half4 h, l;
#pragma unroll
    for (int e = 0; e < 4; ++e) {
        float f = fmaxf(pv[e] + pb[e], 0.0f);
        _Float16 hh = (_Float16)f;
        h[e] = hh;
        l[e] = (_Float16)(f - (float)hh);
    }
    *(half4*)(outH + i) = h;
    *(half4*)(outL + i) = l;
}

// ---------------------------------------------------------------------------
// global->LDS DMA, width 16 (wave-uniform LDS base + lane*16)
// ---------------------------------------------------------------------------
__device__ __forceinline__ void dma16(const _Float16* g, _Float16* l)
{
    __builtin_amdgcn_global_load_lds(
        (const __attribute__((address_space(1))) unsigned int*)g,
        (__attribute__((address_space(3))) unsigned int*)l, 16, 0, 0);
}

// ---------------------------------------------------------------------------
// LDS granule swizzle (bank-conflict fix, rule: both-sides-or-neither):
// row r's source granule c (16 B) is stored at physical position
// p = c ^ ((r>>1)&3) within the row's 64 B. Since global_load_lds writes
// linearly (lane L -> row L>>2, pos L&3), we PRE-SWIZZLE the global source:
// lane L loads granule (L&3) ^ ((L>>3)&3). Fragment reads then use
// p = (lane>>4) ^ ((lane>>1)&3) instead of lane>>4. Result: for a b128
// fragment read (16 rows x 64 B stride), bank-start set covers all 8
// 4-bank groups with 2 lanes each -> 2-way (free) instead of 8-way.
// ---------------------------------------------------------------------------
#define LDKE 32   /* halves per LDS row (64 B), unpadded for DMA */
#define DKQ_SWZ(lane)  ((((lane) & 3) ^ (((lane) >> 3) & 3)) << 3)
#define FK_SWZ(lane)   (((((lane) >> 4) ^ (((lane) >> 1) & 3))) << 3)

// ---------------------------------------------------------------------------
// Split-f16 MFMA GEMM, DMA staging, XCD-pinned 1-D grid:
//   Cacc[M,N] += (Ah+Al)[M][K] @ (Bh+Bl)^T,  Bt given as [N][K].
// 128x128 block tile, BK=32, 256 thr (4 waves, 64x64 each).
// 1-D grid of SP*(M/128)*(N/128); decode z = bid%SP (-> XCD via the
// bid%8 round-robin heuristic: all blocks of one K-slice share an XCD's
// L2), n fastest (A-panel reuse), m slowest. fp32 atomicAdd epilogue.
// Requires M%128==0, N%128==0, Kc%32==0.
// ---------------------------------------------------------------------------
__global__ __launch_bounds__(256) void gemm_mfma_split_k(
    const _Float16* __restrict__ Ah, const _Float16* __restrict__ Al,
    const _Float16* __restrict__ Bh, const _Float16* __restrict__ Bl,
    float* __restrict__ Cacc, int M, int N, int K, int Kc, int SP)
{
    __shared__ _Float16 sAh[128 * LDKE], sAl[128 * LDKE];
    __shared__ _Float16 sBh[128 * LDKE], sBl[128 * LDKE];

    int bid = blockIdx.x;
    int z = bid % SP;
    int q = bid / SP;
    int NT = N >> 7;
    int nn = q % NT;
    int m = q / NT;
    int m0 = m * 128, n0 = nn * 128;
    int kb = z * Kc;
    int ke = min(K, kb + Kc);

    int t = threadIdx.x;
    int lane = t & 63, w = t >> 6;
    int wr = w >> 1, wc = w & 1;          // 2x2 wave grid over 128x128
    int fr = lane & 15;                   // fragment row/col within 16
    int fk = FK_SWZ(lane);                // swizzled fragment granule offset

    // DMA mapping: wave w stages row-chunks {2w, 2w+1} (16 rows x 32 halves
    // = 1 KB each) of every array. Lane L -> row_local = L>>2, granule
    // pre-swizzled so the linear LDS write realizes the XOR layout.
    int drow = w * 32 + (lane >> 2);
    int dkq = DKQ_SWZ(lane);
    const _Float16* gAh = Ah + (size_t)(m0 + drow) * K + dkq;
    const _Float16* gAl = Al + (size_t)(m0 + drow) * K + dkq;
    const _Float16* gBh = Bh + (size_t)(n0 + drow) * K + dkq;
    const _Float16* gBl = Bl + (size_t)(n0 + drow) * K + dkq;
    size_t rowskip = (size_t)16 * K;

    _Float16* lAh0 = &sAh[(w * 2 + 0) * 512];
    _Float16* lAh1 = &sAh[(w * 2 + 1) * 512];
    _Float16* lAl0 = &sAl[(w * 2 + 0) * 512];
    _Float16* lAl1 = &sAl[(w * 2 + 1) * 512];
    _Float16* lBh0 = &sBh[(w * 2 + 0) * 512];
    _Float16* lBh1 = &sBh[(w * 2 + 1) * 512];
    _Float16* lBl0 = &sBl[(w * 2 + 0) * 512];
    _Float16* lBl1 = &sBl[(w * 2 + 1) * 512];

    floatx4 acc[4][4] = {};

    for (int k0 = kb; k0 < ke; k0 += 32) {
        dma16(gAh + k0, lAh0);
        dma16(gAh + rowskip + k0, lAh1);
        dma16(gAl + k0, lAl0);
        dma16(gAl + rowskip + k0, lAl1);
        dma16(gBh + k0, lBh0);
        dma16(gBh + rowskip + k0, lBh1);
        dma16(gBl + k0, lBl0);
        dma16(gBl + rowskip + k0, lBl1);
        __syncthreads();   // drains vmcnt -> DMA data visible

        half8 ah[4], al[4], bh[4], bl[4];
#pragma unroll
        for (int i = 0; i < 4; ++i) {
            int ar = wr * 64 + i * 16 + fr;
            ah[i] = *(const half8*)&sAh[ar * LDKE + fk];
            al[i] = *(const half8*)&sAl[ar * LDKE + fk];
            int bc = wc * 64 + i * 16 + fr;
            bh[i] = *(const half8*)&sBh[bc * LDKE + fk];
            bl[i] = *(const half8*)&sBl[bc * LDKE + fk];
        }
#pragma unroll
        for (int i = 0; i < 4; ++i)
#pragma unroll
            for (int j = 0; j < 4; ++j) {
                acc[i][j] = __builtin_amdgcn_mfma_f32_16x16x32_f16(ah[i], bh[j], acc[i][j], 0, 0, 0);
                acc[i][j] = __builtin_amdgcn_mfma_f32_16x16x32_f16(ah[i], bl[j], acc[i][j], 0, 0, 0);
                acc[i][j] = __builtin_amdgcn_mfma_f32_16x16x32_f16(al[i], bh[j], acc[i][j], 0, 0, 0);
            }
        __syncthreads();   // LDS reads complete before next DMA overwrite
    }

    // epilogue: C/D layout col=lane&15, row=(lane>>4)*4+reg
    int rbase = (lane >> 4) * 4;
#pragma unroll
    for (int i = 0; i < 4; ++i)
#pragma unroll
        for (int j = 0; j < 4; ++j) {
            int col = n0 + wc * 64 + j * 16 + fr;
#pragma unroll
            for (int r = 0; r < 4; ++r) {
                int row = m0 + wr * 64 + i * 16 + rbase + r;
                atomicAdd(&Cacc[(size_t)row * N + col], acc[i][j][r]);
            }
        }
}

// ---------------------------------------------------------------------------
// Non-split fused MFMA GEMM, 64x64 tile, full-K accumulation in registers,
// double-buffered LDS 2-phase prefetch (stage next tile while computing
// current; ONE barrier per K-tile). Same granule swizzle as above.
//   C = (Ah+Al) @ (Bh+Bl)^T   (3 products)
// mode 0: Cout[row*N+col] = C (raw fp32)
// mode 1: relu(C + bias[col]) -> outH/outL f16 hi/lo
// 256 thr (2x2 waves of 32x32 = 2x2 of 16x16x32). 32 KB LDS.
// Requires M%64==0, N%64==0, K%32==0.
// ---------------------------------------------------------------------------
__global__ __launch_bounds__(256) void gemm_mfma_fused64_k(
    const _Float16* __restrict__ Ah, const _Float16* __restrict__ Al,
    const _Float16* __restrict__ Bh, const _Float16* __restrict__ Bl,
    const float* __restrict__ bias,
    float* __restrict__ Cout,
    _Float16* __restrict__ outH, _Float16* __restrict__ outL,
    int M, int N, int K, int mode)
{
    __shared__ _Float16 sAh[2][64 * LDKE], sAl[2][64 * LDKE];
    __shared__ _Float16 sBh[2][64 * LDKE], sBl[2][64 * LDKE];

    int m0 = blockIdx.y * 64, n0 = blockIdx.x * 64;
    int t = threadIdx.x;
    int lane = t & 63, w = t >> 6;
    int wr = w >> 1, wc = w & 1;          // 2x2 wave grid over 64x64
    int fr = lane & 15;
    int fk = FK_SWZ(lane);

    // DMA: wave w stages rows [w*16, w*16+16) of all four arrays
    int drow = w * 16 + (lane >> 2);
    int dkq = DKQ_SWZ(lane);
    const _Float16* gAh = Ah + (size_t)(m0 + drow) * K + dkq;
    const _Float16* gAl = Al + (size_t)(m0 + drow) * K + dkq;
    const _Float16* gBh = Bh + (size_t)(n0 + drow) * K + dkq;
    const _Float16* gBl = Bl + (size_t)(n0 + drow) * K + dkq;
    int lofs = w * 512;

    int nt = K >> 5;

    // prologue: stage tile 0 into buf 0
    dma16(gAh + 0, &sAh[0][lofs]);
    dma16(gAl + 0, &sAl[0][lofs]);
    dma16(gBh + 0, &sBh[0][lofs]);
    dma16(gBl + 0, &sBl[0][lofs]);
    __syncthreads();

    floatx4 acc[2][2] = {};

    for (int tt = 0; tt < nt; ++tt) {
        int c = tt & 1, nb = c ^ 1;
        if (tt + 1 < nt) {
            int k1 = (tt + 1) << 5;
            dma16(gAh + k1, &sAh[nb][lofs]);
            dma16(gAl + k1, &sAl[nb][lofs]);
            dma16(gBh + k1, &sBh[nb][lofs]);
            dma16(gBl + k1, &sBl[nb][lofs]);
        }

        half8 ah[2], av[2], bh[2], bv[2];
#pragma unroll
        for (int i = 0; i < 2; ++i) {
            int ar = wr * 32 + i * 16 + fr;
            ah[i] = *(const half8*)&sAh[c][ar * LDKE + fk];
            av[i] = *(const half8*)&sAl[c][ar * LDKE + fk];
            int bc = wc * 32 + i * 16 + fr;
            bh[i] = *(const half8*)&sBh[c][bc * LDKE + fk];
            bv[i] = *(const half8*)&sBl[c][bc * LDKE + fk];
        }
#pragma unroll
        for (int i = 0; i < 2; ++i)
#pragma unroll
            for (int j = 0; j < 2; ++j) {
                acc[i][j] = __builtin_amdgcn_mfma_f32_16x16x32_f16(ah[i], bh[j], acc[i][j], 0, 0, 0);
                acc[i][j] = __builtin_amdgcn_mfma_f32_16x16x32_f16(ah[i], bv[j], acc[i][j], 0, 0, 0);
                acc[i][j] = __builtin_amdgcn_mfma_f32_16x16x32_f16(av[i], bh[j], acc[i][j], 0, 0, 0);
            }
        __syncthreads();   // staged data visible; all reads of buf c done
    }

    int rbase = (lane >> 4) * 4;
#pragma unroll
    for (int i = 0; i < 2; ++i)
#pragma unroll
        for (int j = 0; j < 2; ++j) {
            int col = n0 + wc * 32 + j * 16 + fr;
#pragma unroll
            for (int r = 0; r < 4; ++r) {
                int row = m0 + wr * 32 + i * 16 + rbase + r;
                float v = acc[i][j][r];
                if (mode == 0) {
                    Cout[(size_t)row * N + col] = v;
                } else {
                    float f = fmaxf(v + bias[col], 0.0f);
                    _Float16 hh = (_Float16)f;
                    outH[(size_t)row * N + col] = hh;
                    outL[(size_t)row * N + col] = (_Float16)(f - (float)hh);
                }
            }
        }
}

// ---------------------------------------------------------------------------
// fp32 split-K GEMM (fallback path only)
// ---------------------------------------------------------------------------
__global__ __launch_bounds__(256) void gemm_splitk_k(const float* __restrict__ A,
                                                     const float* __restrict__ B,
                                                     const float* __restrict__ abias,
                                                     float* __restrict__ Cacc,
                                                     int M, int N, int K, int Kc)
{
    __shared__ float Ast[16][68];
    __shared__ float Bs[16][68];

    int m0 = blockIdx.y * 64, n0 = blockIdx.x * 64;
    int kb = blockIdx.z * Kc;
    int ke = min(K, kb + Kc);
    int tid = threadIdx.x;
    int tx = tid & 15, ty = tid >> 4;
    int arow = tid >> 2, akq = (tid & 3) << 2;
    int bcol = tid & 63, bk = tid >> 6;

    const float* Arow = A + (size_t)(m0 + arow) * K;
    bool nfull = (n0 + 64 <= N);

    float acc[4][4] = {};

    for (int k0 = kb; k0 < ke; k0 += 16) {
        float4 av = *(const float4*)(Arow + k0 + akq);
        if (abias) {
            av.x = fmaxf(av.x + abias[k0 + akq + 0], 0.0f);
            av.y = fmaxf(av.y + abias[k0 + akq + 1], 0.0f);
            av.z = fmaxf(av.z + abias[k0 + akq + 2], 0.0f);
            av.w = fmaxf(av.w + abias[k0 + akq + 3], 0.0f);
        }
        float bv[4];
        if (nfull) {
#pragma unroll
            for (int e = 0; e < 4; ++e)
                bv[e] = B[(size_t)(k0 + bk * 4 + e) * N + n0 + bcol];
        } else {
            bool ok = (n0 + bcol) < N;
#pragma unroll
            for (int e = 0; e < 4; ++e)
                bv[e] = ok ? B[(size_t)(k0 + bk * 4 + e) * N + n0 + bcol] : 0.0f;
        }
        __syncthreads();
        Ast[akq + 0][arow] = av.x;
        Ast[akq + 1][arow] = av.y;
        Ast[akq + 2][arow] = av.z;
        Ast[akq + 3][arow] = av.w;
#pragma unroll
        for (int e = 0; e < 4; ++e) Bs[bk * 4 + e][bcol] = bv[e];
        __syncthreads();

#pragma unroll
        for (int kk = 0; kk < 16; ++kk) {
            float4 af = *(const float4*)&Ast[kk][ty * 4];
            float4 bf = *(const float4*)&Bs[kk][tx * 4];
            float a_[4] = {af.x, af.y, af.z, af.w};
            float b_[4] = {bf.x, bf.y, bf.z, bf.w};
#pragma unroll
            for (int i = 0; i < 4; ++i)
#pragma unroll
                for (int j = 0; j < 4; ++j)
                    acc[i][j] = fmaf(a_[i], b_[j], acc[i][j]);
        }
    }

#pragma unroll
    for (int i = 0; i < 4; ++i) {
        int row = m0 + ty * 4 + i;
#pragma unroll
        for (int j = 0; j < 4; ++j) {
            int col = n0 + tx * 4 + j;
            if (col < N) atomicAdd(&Cacc[(size_t)row * N + col], acc[i][j]);
        }
    }
}

// ---------------------------------------------------------------------------
// softmax over (logits + bc), classes 1..80. grid = R, block = 64.
// ---------------------------------------------------------------------------
__global__ void softmax_k(const float* __restrict__ logits, int ldl,
                          const float* __restrict__ bc,
                          float* __restrict__ scr)
{
    int r = blockIdx.x;
    int t = threadIdx.x;
    const float* row = logits + (size_t)r * ldl;

    float v0 = row[t] + bc[t];
    float v1 = (t + 64 < NCLS) ? (row[t + 64] + bc[t + 64]) : -INFINITY;
    float m = fmaxf(v0, v1);
#pragma unroll
    for (int o = 32; o > 0; o >>= 1) m = fmaxf(m, __shfl_down(m, o));
    m = __shfl(m, 0);

    float e0 = expf(v0 - m);
    float e1 = (t + 64 < NCLS) ? expf(v1 - m) : 0.0f;
    float sum = e0 + e1;
#pragma unroll
    for (int o = 32; o > 0; o >>= 1) sum += __shfl_down(sum, o);
    sum = __shfl(sum, 0);
    float inv = 1.0f / sum;

    if (t >= 1)        scr[(size_t)r * DCLS + (t - 1)]  = e0 * inv;
    if (t + 64 < NCLS) scr[(size_t)r * DCLS + (t + 63)] = e1 * inv;
}

// ---------------------------------------------------------------------------
// per-image NMS with fused box decode. grid = n, block = 1024.
// Greedy argmax-NMS == sort-once + sequential-scan NMS (identical outputs,
// incl. tie-break: key = (score desc, global idx asc)).
//   1) compaction (unchanged)
//   2) bitonic sort of (key, slot) in LDS, all 1024 threads
//   3) single-wave scan: chunks of 64 sorted candidates; check vs accepted
//      set (LDS broadcast); intra-chunk resolve via ballot+ffs+shuffle.
//      ZERO block barriers per pick (was 2-13).
// Fallback to the old global-memory argmax loop if K > 4096 or imtop > 512.
// ---------------------------------------------------------------------------
#define NMS_T 1024
#define NMS_SORTMAX 4096
#define NMS_AMAX 512
__global__ __launch_bounds__(NMS_T) void nms_k(
    const float* __restrict__ scr,
    const float* __restrict__ prop,
    const int* __restrict__ imidx,
    const float* __restrict__ head, int ldh, int regofs,
    const float* __restrict__ br,
    const float* __restrict__ imsz,
    const float* __restrict__ score_thr_p,
    const float* __restrict__ min_size_p,
    const float* __restrict__ iou_thr_p,
    int* __restrict__ cidx,
    float* __restrict__ cscore,
    float* __restrict__ cbo,
    float* __restrict__ cbox,
    float* __restrict__ carea,
    float* __restrict__ out,
    int M, int n, int imtop)
{
    int img = blockIdx.x;
    int t = threadIdx.x;
    const int T = NMS_T;
    const int NW = NMS_T / 64;
    int lane = t & 63, wid = t >> 6;

    __shared__ int cnt;
    __shared__ unsigned long long skey[NMS_SORTMAX];
    __shared__ int sp_[NMS_SORTMAX];
    __shared__ float aab0[NMS_AMAX], aab1[NMS_AMAX], aab2[NMS_AMAX], aab3[NMS_AMAX], aaa[NMS_AMAX];
    __shared__ int f_it;
    __shared__ float ws_sc[NW];
    __shared__ int ws_g[NW], ws_p[NW];
    __shared__ float f_sc, f_o0, f_o1, f_o2, f_o3, f_ar;

    if (t == 0) cnt = 0;
    __syncthreads();

    float score_thr = score_thr_p[0];
    float min_size  = min_size_p[0];
    float iou_thr   = iou_thr_p[0];
    float immax = imsz[0];
    for (int q = 1; q < 2 * n; ++q) immax = fmaxf(immax, imsz[q]);

    int base = img * M;
    for (int j = t; j < M; j += T) {
        int r = j / DCLS;
        if (imidx[r] != img) continue;
        float s = scr[j];
        if (s <= score_thr) continue;

        int cls = j - r * DCLS + 1;
        const float* pr = prop + (size_t)r * 4;
        float pw = pr[2] - pr[0], ph = pr[3] - pr[1];
        float cx = (pr[0] + pr[2]) * 0.5f, cy = (pr[1] + pr[3]) * 0.5f;
        const float* rg_ = head + (size_t)r * ldh + regofs + cls * 4;
        const float* bb = br + cls * 4;
        float dx = (rg_[0] + bb[0]) * 0.1f;
        float dy = (rg_[1] + bb[1]) * 0.1f;
        float dw = fminf((rg_[2] + bb[2]) * 0.2f, FLOG_MAX);
        float dh = fminf((rg_[3] + bb[3]) * 0.2f, FLOG_MAX);
        float ncx = dx * pw + cx;
        float ncy = dy * ph + cy;
        float nw = expf(dw) * pw;
        float nh = expf(dh) * ph;
        float hbound = imsz[img * 2 + 0];
        float wbound = imsz[img * 2 + 1];
        float bx1 = fminf(fmaxf(ncx - nw * 0.5f, 0.0f), wbound);
        float bx2 = fminf(fmaxf(ncx + nw * 0.5f, 0.0f), wbound);
        float by1 = fminf(fmaxf(ncy - nh * 0.5f, 0.0f), hbound);
        float by2 = fminf(fmaxf(ncy + nh * 0.5f, 0.0f), hbound);
        if (bx2 - bx1 < min_size || by2 - by1 < min_size) continue;

        float off = (float)cls * (immax + 2.0f);
        int p = atomicAdd(&cnt, 1);
        cidx[base + p] = j;
        cscore[base + p] = s;
        cbox[(size_t)(base + p) * 4 + 0] = bx1;
        cbox[(size_t)(base + p) * 4 + 1] = by1;
        cbox[(size_t)(base + p) * 4 + 2] = bx2;
        cbox[(size_t)(base + p) * 4 + 3] = by2;
        cbo[(size_t)(base + p) * 4 + 0] = bx1 + off;
        cbo[(size_t)(base + p) * 4 + 1] = by1 + off;
        cbo[(size_t)(base + p) * 4 + 2] = bx2 + off;
        cbo[(size_t)(base + p) * 4 + 3] = by2 + off;
        carea[base + p] = (bx2 - bx1) * (by2 - by1);
    }
    __syncthreads();
    int K = cnt;

    float* ob  = out;
    float* osc = out + (size_t)n * imtop * 4;
    float* ocl = out + (size_t)n * imtop * 5;

    int it = 0;
    if (K <= NMS_SORTMAX && imtop <= NMS_AMAX) {
        // ---------------- sort + sequential-scan NMS ----------------
        int SN = 64; while (SN < K) SN <<= 1;
        for (int i = t; i < SN; i += T) {
            if (i < K) {
                unsigned int sb = __float_as_uint(cscore[base + i]);
                skey[i] = ((unsigned long long)sb << 32)
                        | (unsigned int)(~cidx[base + i]);
            } else {
                skey[i] = 0ull;
            }
            sp_[i] = i;
        }
        for (int k = 2; k <= SN; k <<= 1) {
            for (int j = k >> 1; j > 0; j >>= 1) {
                __syncthreads();
                for (int i = t; i < SN; i += T) {
                    int l = i ^ j;
                    if (l > i) {
                        unsigned long long ki = skey[i], kl = skey[l];
                        bool up = ((i & k) == 0);
                        bool sw = up ? (ki < kl) : (ki > kl);
                        if (sw) {
                            skey[i] = kl; skey[l] = ki;
                            int tp = sp_[i]; sp_[i] = sp_[l]; sp_[l] = tp;
                        }
                    }
                }
            }
        }
        __syncthreads();

        if (wid == 0) {
            int na = 0;
            for (int c0 = 0; c0 < K && na < imtop; c0 += 64) {
                int ci = c0 + lane;
                bool alive = ci < K;
                float x0 = 0.f, x1 = 0.f, x2 = 0.f, x3 = 0.f, ar_ = 0.f, sc = 0.f;
                float q0 = 0.f, q1 = 0.f, q2 = 0.f, q3 = 0.f;
                int g = 0;
                if (alive) {
                    unsigned long long key = skey[ci];
                    sc = __uint_as_float((unsigned int)(key >> 32));
                    int pp = sp_[ci];
                    g = cidx[base + pp];
                    x0 = cbo[(size_t)(base + pp) * 4 + 0];
                    x1 = cbo[(size_t)(base + pp) * 4 + 1];
                    x2 = cbo[(size_t)(base + pp) * 4 + 2];
                    x3 = cbo[(size_t)(base + pp) * 4 + 3];
                    ar_ = carea[base + pp];
                    q0 = cbox[(size_t)(base + pp) * 4 + 0];
                    q1 = cbox[(size_t)(base + pp) * 4 + 1];
                    q2 = cbox[(size_t)(base + pp) * 4 + 2];
                    q3 = cbox[(size_t)(base + pp) * 4 + 3];
                    if (sc <= 0.0f) alive = false;
                }
                // check against already-accepted set (LDS broadcast reads)
                for (int a = 0; a < na; ++a) {
                    float iw = fmaxf(fminf(aab2[a], x2) - fmaxf(aab0[a], x0), 0.0f);
                    float ih = fmaxf(fminf(aab3[a], x3) - fmaxf(aab1[a], x1), 0.0f);
                    float inter = iw * ih;
                    float iou = inter / (aaa[a] + ar_ - inter + 1e-6f);
                    if (iou > iou_thr) alive = false;
                }
                // intra-chunk sequential resolve
                unsigned long long mm = __ballot(alive);
                while (mm != 0ull && na < imtop) {
                    int s = __ffsll(mm) - 1;
                    float b0 = __shfl(x0, s), b1 = __shfl(x1, s);
                    float b2v = __shfl(x2, s), b3v = __shfl(x3, s);
                    float ba = __shfl(ar_, s);
                    if (lane == s) {
                        size_t oslot = (size_t)img * imtop + na;
                        ob[oslot * 4 + 0] = q0;
                        ob[oslot * 4 + 1] = q1;
                        ob[oslot * 4 + 2] = q2;
                        ob[oslot * 4 + 3] = q3;
                        osc[oslot] = sc;
                        ocl[oslot] = (float)(g % DCLS + 1);
                        aab0[na] = x0; aab1[na] = x1; aab2[na] = x2; aab3[na] = x3;
                        aaa[na] = ar_;
                        alive = false;
                    }
                    na++;
                    if (alive && lane > s) {
                        float iw = fmaxf(fminf(b2v, x2) - fmaxf(b0, x0), 0.0f);
                        float ih = fmaxf(fminf(b3v, x3) - fmaxf(b1, x1), 0.0f);
                        float inter = iw * ih;
                        float iou = inter / (ba + ar_ - inter + 1e-6f);
                        if (iou > iou_thr) alive = false;
                    }
                    mm = __ballot(alive);
                }
            }
            if (lane == 0) f_it = na;
        }
        __syncthreads();
        it = f_it;
    } else {
        // ---------------- fallback: global-memory argmax loop ----------------
        for (; it < imtop; ++it) {
            float best = -1e30f; int bg = 0x7fffffff; int bl = -1;
            for (int p = t; p < K; p += T) {
                float sv = cscore[base + p];
                int g = cidx[base + p];
                if (sv > best || (sv == best && g < bg)) { best = sv; bg = g; bl = p; }
            }
#pragma unroll
            for (int o = 32; o > 0; o >>= 1) {
                float os = __shfl_down(best, o);
                int   og = __shfl_down(bg, o);
                int   ol = __shfl_down(bl, o);
                if (os > best || (os == best && og < bg)) { best = os; bg = og; bl = ol; }
            }
            if (lane == 0) { ws_sc[wid] = best; ws_g[wid] = bg; ws_p[wid] = bl; }
            __syncthreads();
            if (wid == 0) {
                float b2 = (lane < NW) ? ws_sc[lane] : -1e30f;
                int   g2 = (lane < NW) ? ws_g[lane] : 0x7fffffff;
                int   l2 = (lane < NW) ? ws_p[lane] : -1;
#pragma unroll
                for (int o = NW / 2; o > 0; o >>= 1) {
                    float os = __shfl_down(b2, o);
                    int   og = __shfl_down(g2, o);
                    int   ol = __shfl_down(l2, o);
                    if (os > b2 || (os == b2 && og < g2)) { b2 = os; g2 = og; l2 = ol; }
                }
                if (lane == 0) {
                    f_sc = b2;
                    if (b2 > 0.0f) {
                        int lp = l2;
                        size_t oslot = (size_t)img * imtop + it;
                        ob[oslot * 4 + 0] = cbox[(size_t)(base + lp) * 4 + 0];
                        ob[oslot * 4 + 1] = cbox[(size_t)(base + lp) * 4 + 1];
                        ob[oslot * 4 + 2] = cbox[(size_t)(base + lp) * 4 + 2];
                        ob[oslot * 4 + 3] = cbox[(size_t)(base + lp) * 4 + 3];
                        osc[oslot] = b2;
                        ocl[oslot] = (float)(g2 % DCLS + 1);
                        f_o0 = cbo[(size_t)(base + lp) * 4 + 0];
                        f_o1 = cbo[(size_t)(base + lp) * 4 + 1];
                        f_o2 = cbo[(size_t)(base + lp) * 4 + 2];
                        f_o3 = cbo[(size_t)(base + lp) * 4 + 3];
                        f_ar = carea[base + lp];
                        cscore[base + lp] = -1.0f;
                    }
                }
            }
            __syncthreads();
            if (f_sc <= 0.0f) break;

            float b0 = f_o0, b1 = f_o1, b2_ = f_o2, b3 = f_o3, ai = f_ar;
            for (int p = t; p < K; p += T) {
                float c0 = cbo[(size_t)(base + p) * 4 + 0];
                float c1 = cbo[(size_t)(base + p) * 4 + 1];
                float c2 = cbo[(size_t)(base + p) * 4 + 2];
                float c3 = cbo[(size_t)(base + p) * 4 + 3];
                float iw = fmaxf(fminf(b2_, c2) - fmaxf(b0, c0), 0.0f);
                float ih = fmaxf(fminf(b3, c3) - fmaxf(b1, c1), 0.0f);
                float inter = iw * ih;
                float iou = inter / (ai + carea[base + p] - inter + 1e-6f);
                if (iou > iou_thr) cscore[base + p] = -1.0f;
            }
            __syncthreads();
        }
    }

    for (int q = it + t; q < imtop; q += T) {
        size_t oslot = (size_t)img * imtop + q;
        ob[oslot * 4 + 0] = 0.0f;
        ob[oslot * 4 + 1] = 0.0f;
        ob[oslot * 4 + 2] = 0.0f;
        ob[oslot * 4 + 3] = 0.0f;
        osc[oslot] = 0.0f;
        ocl[oslot] = -1.0f;
    }
}

// ---------------------------------------------------------------------------
extern "C" void kernel_launch(void* const* d_in, const int* in_sizes, int n_in,
                              void* d_out, int out_size, void* d_ws, size_t ws_size,
                              hipStream_t stream)
{
    const float* prop   = (const float*)d_in[0];
    const int*   imidx  = (const int*)d_in[1];
    const float* f0     = (const float*)d_in[2];
    const float* f1     = (const float*)d_in[3];
    const float* f2     = (const float*)d_in[4];
    const float* f3     = (const float*)d_in[5];
    const float* W0     = (const float*)d_in[6];
    const float* b0     = (const float*)d_in[7];
    const float* W1     = (const float*)d_in[8];
    const float* b1     = (const float*)d_in[9];
    const float* Wc     = (const float*)d_in[10];
    const float* bc     = (const float*)d_in[11];
    const float* Wr     = (const float*)d_in[12];
    const float* br     = (const float*)d_in[13];
    const float* imsz   = (const float*)d_in[14];
    const float* sthr   = (const float*)d_in[15];
    const float* ithr   = (const float*)d_in[16];
    const float* msz    = (const float*)d_in[18];

    int R = in_sizes[1];              // 1024
    int n = in_sizes[14] / 2;         // 2
    int imtop = out_size / (n * 6);   // 100
    int M = R * DCLS;                 // 81920
    int K0 = NPOOL * NPOOL * CCH;     // 12544
    int CL = in_sizes[7];             // 1024

    int h0 = (int)(sqrtf((float)(in_sizes[2] / (n * CCH))) + 0.5f);
    int h1 = (int)(sqrtf((float)(in_sizes[3] / (n * CCH))) + 0.5f);
    int h2 = (int)(sqrtf((float)(in_sizes[4] / (n * CCH))) + 0.5f);
    int h3 = (int)(sqrtf((float)(in_sizes[5] / (n * CCH))) + 0.5f);

    float* outf = (float*)d_out;

    // ---- MFMA-path workspace layout (bytes) ----
    size_t szPool  = (size_t)R * K0 * 2;
    size_t szX     = (size_t)R * CL * 4;
    size_t szHead  = (size_t)R * NHEAD * 4;
    size_t szWh    = (size_t)NHEAD * CL * 2;
    size_t szXh    = (size_t)R * CL * 2;
    size_t szW1t   = (size_t)CL * CL * 2;
    size_t szScr   = (size_t)R * DCLS * 4;

    size_t needed = 4 * szPool + 2 * szX + szHead + 2 * szWh
                  + 4 * szXh + 2 * szW1t + szScr;

    int splitK0 = 8;                  // Kc = K0/8 = 1568 = 49*32
    bool mfma_ok = (ws_size >= needed) && (R % 128 == 0) && (CL % 128 == 0)
                 && (K0 % (splitK0 * 32) == 0) && (CL % 32 == 0)
                 && ((R * 49) % 4 == 0);

    if (mfma_ok) {
        uint8_t* w = (uint8_t*)d_ws;
        size_t o = 0;
        _Float16* poolH   = (_Float16*)(w + o); o += szPool;
        _Float16* poolL   = (_Float16*)(w + o); o += szPool;
        _Float16* W0tH    = (_Float16*)(w + o); o += szPool;
        _Float16* W0tL    = (_Float16*)(w + o); o += szPool;
        float*    x0acc   = (float*)(w + o);    o += szX;
        float*    unused  = (float*)(w + o);    o += szX;   // (kept for layout stability)
        float*    headacc = (float*)(w + o);    o += szHead;
        _Float16* WheadtH = (_Float16*)(w + o); o += szWh;
        _Float16* WheadtL = (_Float16*)(w + o); o += szWh;
        _Float16* x0H     = (_Float16*)(w + o); o += szXh;
        _Float16* x0L     = (_Float16*)(w + o); o += szXh;
        _Float16* x1H     = (_Float16*)(w + o); o += szXh;
        _Float16* x1L     = (_Float16*)(w + o); o += szXh;
        _Float16* W1tH    = (_Float16*)(w + o); o += szW1t;
        _Float16* W1tL    = (_Float16*)(w + o); o += szW1t;
        float*    scr     = (float*)(w + o);
        (void)unused;

        // NMS compaction arrays alias the pool region (dead after FC0)
        int*   cidx   = (int*)d_ws;
        float* cscore = (float*)(cidx + (size_t)n * M);
        float* cbo    = cscore + (size_t)n * M;
        float* cbox   = cbo + (size_t)n * M * 4;
        float* carea  = cbox + (size_t)n * M * 4;

        // 0. zero only the split-K accumulator (x0acc, 4 MB)
        {
            int c4 = (int)(szX / 16);
            zero_k<<<dim3((c4 + 255) / 256), dim3(256), 0, stream>>>((float4*)x0acc, c4);
        }
        // 1. weight converts
        convert_w_t_k<<<dim3(K0 / 64, CL / 64), dim3(256), 0, stream>>>(W0, W0tH, W0tL, K0, CL);
        convert_w_t_k<<<dim3(CL / 64, CL / 64), dim3(256), 0, stream>>>(W1, W1tH, W1tL, CL, CL);
        convert_w_t_guard_k<<<dim3(CL / 64, (NCLS + 63) / 64), dim3(256), 0, stream>>>(
            Wc, WheadtH, WheadtL, CL, NCLS, CL, 0);
        convert_w_t_guard_k<<<dim3(CL / 64, (NCLS * 4 + 63) / 64), dim3(256), 0, stream>>>(
            Wr, WheadtH, WheadtL, CL, NCLS * 4, CL, NCLS);
        // 2. RoI align -> f16 hi/lo pooled (4 cells per 256-thr block)
        roi_align_f16v4_k<<<dim3(R * 49 / 4), dim3(256), 0, stream>>>(
            prop, imidx, f0, f1, f2, f3, h0, h1, h2, h3, poolH, poolL);
        // 3. FC0: x0acc = pooled @ W0  (split-K 8, XCD-pinned 1-D grid of 512)
        gemm_mfma_split_k<<<dim3(splitK0 * (R / 128) * (CL / 128)), dim3(256), 0, stream>>>(
            poolH, poolL, W0tH, W0tL, x0acc, R, CL, K0, K0 / splitK0, splitK0);
        // 4. x0 = relu(x0acc + b0) -> hi/lo
        act_split_k<<<dim3((R * CL / 4 + 255) / 256), dim3(256), 0, stream>>>(
            x0acc, b0, x0H, x0L, R * CL, CL);
        // 5. FC1 fused: x1 = relu(x0 @ W1 + b1) -> hi/lo directly (no atomics)
        gemm_mfma_fused64_k<<<dim3(CL / 64, R / 64), dim3(256), 0, stream>>>(
            x0H, x0L, W1tH, W1tL, b1, nullptr, x1H, x1L, R, CL, CL, 1);
        // 6. combined heads fused: headacc = x1 @ [Wc|Wr] raw fp32 (N=512)
        gemm_mfma_fused64_k<<<dim3(NHEAD / 64, R / 64), dim3(256), 0, stream>>>(
            x1H, x1L, WheadtH, WheadtL, nullptr, headacc, nullptr, nullptr, R, NHEAD, CL, 0);
        // 7. softmax (+bc)
        softmax_k<<<dim3(R), dim3(64), 0, stream>>>(headacc, NHEAD, bc, scr);
        // 8. NMS with fused decode (+br)
        nms_k<<<dim3(n), dim3(NMS_T), 0, stream>>>(
            scr, prop, imidx, headacc, NHEAD, NCLS, br, imsz, sthr, msz, ithr,
            cidx, cscore, cbo, cbox, carea, outf, M, n, imtop);
    } else {
        // -------- fallback: all-fp32 pipeline --------
        float* ws = (float*)d_ws;
        size_t off = 0;
        float* pooled  = ws + off; off += (size_t)R * K0;
        float* x0acc   = ws + off; off += (size_t)R * CL;
        float* x1acc   = ws + off; off += (size_t)R * CL;
        float* logits  = ws + off; off += (size_t)R * NCLS;
        off = (off + 3) & ~(size_t)3;
        float* reg     = ws + off; off += (size_t)R * NCLS * 4;
        float* scr     = ws + off; off += (size_t)R * DCLS;

        int*   cidx   = (int*)ws;
        float* cscore = (float*)(cidx + (size_t)n * M);
        float* cbo    = cscore + (size_t)n * M;
        float* cbox   = cbo + (size_t)n * M * 4;
        float* carea  = cbox + (size_t)n * M * 4;

        {
            size_t zcount = (size_t)(reg + (size_t)R * NCLS * 4 - x0acc);
            int c4 = (int)(zcount / 4);
            zero_k<<<dim3((c4 + 255) / 256), dim3(256), 0, stream>>>((float4*)x0acc, c4);
        }
        roi_align_k<<<dim3(R * 49), dim3(256), 0, stream>>>(
            prop, imidx, f0, f1, f2, f3, h0, h1, h2, h3, pooled);
        gemm_splitk_k<<<dim3(CL / 64, R / 64, 8), dim3(256), 0, stream>>>(
            pooled, W0, nullptr, x0acc, R, CL, K0, 1568);
        gemm_splitk_k<<<dim3(CL / 64, R / 64, 4), dim3(256), 0, stream>>>(
            x0acc, W1, b0, x1acc, R, CL, CL, 256);
        gemm_splitk_k<<<dim3((NCLS + 63) / 64, R / 64, 8), dim3(256), 0, stream>>>(
            x1acc, Wc, b1, logits, R, NCLS, CL, 128);
        gemm_splitk_k<<<dim3((NCLS * 4 + 63) / 64, R / 64, 4), dim3(256), 0, stream>>>(
            x1acc, Wr, b1, reg, R, NCLS * 4, CL, 256);
        softmax_k<<<dim3(R), dim3(64), 0, stream>>>(logits, NCLS, bc, scr);
        nms_k<<<dim3(n), dim3(NMS_T), 0, stream>>>(
            scr, prop, imidx, reg, NCLS * 4, 0, br, imsz, sthr, msz, ithr,
            cidx, cscore, cbo, cbox, carea, outf, M, n, imtop);
    }
}

// Round 4
// 401.923 us; speedup vs baseline: 1.1182x; 1.0435x over previous
//
#include <hip/hip_runtime.h>
#include <math.h>

#define CCH 256
#define NPOOL 7
#define NCLS 81
#define DCLS 80
#define NHEAD 512            /* padded head width: 81 logits + 324 reg + pad */
#define FLOG_MAX 4.1351666f  /* log(1000/16) */

typedef _Float16 half8 __attribute__((ext_vector_type(8)));
typedef _Float16 half4 __attribute__((ext_vector_type(4)));
typedef float floatx4 __attribute__((ext_vector_type(4)));

// ---------------------------------------------------------------------------
// zero a region (float4 stores)  (fallback path only; MFMA path folds this
// into pre_uber_k)
// ---------------------------------------------------------------------------
__global__ void zero_k(float4* __restrict__ p, int count4)
{
    int i = blockIdx.x * blockDim.x + threadIdx.x;
    if (i < count4) p[i] = make_float4(0.f, 0.f, 0.f, 0.f);
}

// ---------------------------------------------------------------------------
// RoI-align box math (per-cell scalar part)
// ---------------------------------------------------------------------------
__device__ __forceinline__ void roi_setup(
    const float* __restrict__ prop, const int* __restrict__ imidx,
    const float* __restrict__ f0, const float* __restrict__ f1,
    const float* __restrict__ f2, const float* __restrict__ f3,
    int h0, int h1, int h2, int h3, int b,
    const float*& base, int& W, size_t& o00, size_t& o01, size_t& o10, size_t& o11,
    float& w00, float& w01, float& w10, float& w11)
{
    int roi = b / 49, p = b % 49;
    int py = p / 7, px = p % 7;

    const float* pr = prop + (size_t)roi * 4;
    float x1 = pr[0], y1 = pr[1], x2 = pr[2], y2 = pr[3];
    float pw = x2 - x1, ph = y2 - y1;

    float lv = floorf(4.0f + log2f(sqrtf(pw * ph) / 224.0f + 1e-6f));
    lv = fminf(fmaxf(lv, 2.0f), 5.0f);
    int lvl = (int)lv - 2;

    const float* fm; int H; float s;
    if (lvl == 0)      { fm = f0; H = h0; s = 0.25f;    }
    else if (lvl == 1) { fm = f1; H = h1; s = 0.125f;   }
    else if (lvl == 2) { fm = f2; H = h2; s = 0.0625f;  }
    else               { fm = f3; H = h3; s = 0.03125f; }
    W = H;

    float xs1 = x1 * s, ys1 = y1 * s, xs2 = x2 * s, ys2 = y2 * s;
    float gx = (px + 0.5f) / 7.0f, gy = (py + 0.5f) / 7.0f;
    float xx = xs1 + gx * (xs2 - xs1) - 0.5f;
    float yy = ys1 + gy * (ys2 - ys1) - 0.5f;
    float x0f = floorf(xx), y0f = floorf(yy);
    float wx = xx - x0f, wy = yy - y0f;
    int x0i = min(max((int)x0f, 0), W - 1);
    int x1i = min(max((int)x0f + 1, 0), W - 1);
    int y0i = min(max((int)y0f, 0), H - 1);
    int y1i = min(max((int)y0f + 1, 0), H - 1);

    int ii = imidx[roi];
    base = fm + (size_t)ii * H * W * CCH;
    o00 = ((size_t)y0i * W + x0i) * CCH;
    o01 = ((size_t)y0i * W + x1i) * CCH;
    o10 = ((size_t)y1i * W + x0i) * CCH;
    o11 = ((size_t)y1i * W + x1i) * CCH;
    w00 = (1.0f - wx) * (1.0f - wy);
    w01 = wx * (1.0f - wy);
    w10 = (1.0f - wx) * wy;
    w11 = wx * wy;
}

// fp32 fallback variant: grid R*49 x 256 threads
__global__ void roi_align_k(const float* __restrict__ prop,
                            const int* __restrict__ imidx,
                            const float* __restrict__ f0,
                            const float* __restrict__ f1,
                            const float* __restrict__ f2,
                            const float* __restrict__ f3,
                            int h0, int h1, int h2, int h3,
                            float* __restrict__ pooled)
{
    int b = blockIdx.x, c = threadIdx.x;
    const float* base; int W; size_t o00, o01, o10, o11;
    float w00, w01, w10, w11;
    roi_setup(prop, imidx, f0, f1, f2, f3, h0, h1, h2, h3, b,
              base, W, o00, o01, o10, o11, w00, w01, w10, w11);
    float v = base[o00 + c] * w00 + base[o01 + c] * w01
            + base[o10 + c] * w10 + base[o11 + c] * w11;
    pooled[(size_t)b * CCH + c] = v;
}

// ---------------------------------------------------------------------------
// Device bodies shared by the fused pre-stage über-kernel.
// ---------------------------------------------------------------------------

// f16 hi/lo RoI-align: block bb covers cells 4*bb..4*bb+3 (one per wave)
__device__ __forceinline__ void roi_f16v4_body(
    const float* __restrict__ prop, const int* __restrict__ imidx,
    const float* __restrict__ f0, const float* __restrict__ f1,
    const float* __restrict__ f2, const float* __restrict__ f3,
    int h0, int h1, int h2, int h3, int bb, int t,
    _Float16* __restrict__ poolH, _Float16* __restrict__ poolL)
{
    int b = bb * 4 + (t >> 6);
    int lane = t & 63;
    const float* base; int W; size_t o00, o01, o10, o11;
    float w00, w01, w10, w11;
    roi_setup(prop, imidx, f0, f1, f2, f3, h0, h1, h2, h3, b,
              base, W, o00, o01, o10, o11, w00, w01, w10, w11);

    int c4 = lane * 4;
    float4 v00 = *(const float4*)(base + o00 + c4);
    float4 v01 = *(const float4*)(base + o01 + c4);
    float4 v10 = *(const float4*)(base + o10 + c4);
    float4 v11 = *(const float4*)(base + o11 + c4);
    const float* p00 = (const float*)&v00;
    const float* p01 = (const float*)&v01;
    const float* p10 = (const float*)&v10;
    const float* p11 = (const float*)&v11;

    half4 h, l;
#pragma unroll
    for (int e = 0; e < 4; ++e) {
        float v = p00[e] * w00 + p01[e] * w01 + p10[e] * w10 + p11[e] * w11;
        _Float16 hh = (_Float16)v;
        h[e] = hh;
        l[e] = (_Float16)(v - (float)hh);
    }
    size_t idx = (size_t)b * CCH + c4;
    *(half4*)(poolH + idx) = h;
    *(half4*)(poolL + idx) = l;
}

// Transpose-convert W [K][N] fp32 -> WtH/WtL [N][K] f16 hi/lo (N%64==0 fast)
__device__ __forceinline__ void conv_fast_body(
    const float* __restrict__ W, _Float16* __restrict__ WtH,
    _Float16* __restrict__ WtL, int K, int N, int k0, int n0, int t,
    float (*sh)[65])
{
#pragma unroll
    for (int p = 0; p < 4; ++p) {
        int idx = p * 256 + t;
        int kr = idx >> 4, nc = (idx & 15) * 4;
        float4 v = *(const float4*)(W + (size_t)(k0 + kr) * N + n0 + nc);
        sh[kr][nc + 0] = v.x; sh[kr][nc + 1] = v.y;
        sh[kr][nc + 2] = v.z; sh[kr][nc + 3] = v.w;
    }
    __syncthreads();
#pragma unroll
    for (int p = 0; p < 4; ++p) {
        int idx = p * 256 + t;
        int nr = idx >> 4, kc = (idx & 15) * 4;
        half4 h, l;
#pragma unroll
        for (int i = 0; i < 4; ++i) {
            float v = sh[kc + i][nr];
            _Float16 hh = (_Float16)v;
            h[i] = hh;
            l[i] = (_Float16)(v - (float)hh);
        }
        *(half4*)(WtH + (size_t)(n0 + nr) * K + k0 + kc) = h;
        *(half4*)(WtL + (size_t)(n0 + nr) * K + k0 + kc) = l;
    }
}

// Guarded variant: N arbitrary; rows written at rowofs+n with stride Kt.
__device__ __forceinline__ void conv_guard_body(
    const float* __restrict__ W, _Float16* __restrict__ WtH,
    _Float16* __restrict__ WtL, int K, int N, int Kt, int rowofs,
    int k0, int n0, int t, float (*sh)[65])
{
#pragma unroll
    for (int p = 0; p < 4; ++p) {
        int idx = p * 256 + t;
        int kr = idx >> 4, nc = (idx & 15) * 4;
#pragma unroll
        for (int e = 0; e < 4; ++e) {
            int nn = n0 + nc + e;
            sh[kr][nc + e] = (nn < N) ? W[(size_t)(k0 + kr) * N + nn] : 0.0f;
        }
    }
    __syncthreads();
#pragma unroll
    for (int p = 0; p < 4; ++p) {
        int idx = p * 256 + t;
        int nr = idx >> 4, kc = (idx & 15) * 4;
        if (n0 + nr < N) {
            half4 h, l;
#pragma unroll
            for (int i = 0; i < 4; ++i) {
                float v = sh[kc + i][nr];
                _Float16 hh = (_Float16)v;
                h[i] = hh;
                l[i] = (_Float16)(v - (float)hh);
            }
            *(half4*)(WtH + (size_t)(rowofs + n0 + nr) * Kt + k0 + kc) = h;
            *(half4*)(WtL + (size_t)(rowofs + n0 + nr) * Kt + k0 + kc) = l;
        }
    }
}

// ---------------------------------------------------------------------------
// Fused pre-FC0 stage: RoI-align + all 4 weight converts + accumulator zero
// in ONE launch (block-range dispatch). All parts are mutually independent;
// fusing removes 5 launch gaps and co-schedules gather-bound (roi),
// LDS-transpose-bound (converts) and store-bound (zero) work across CUs.
// Bodies identical to the verified standalone kernels (bit-exact outputs).
// ---------------------------------------------------------------------------
__global__ __launch_bounds__(256) void pre_uber_k(
    const float* __restrict__ prop, const int* __restrict__ imidx,
    const float* __restrict__ f0, const float* __restrict__ f1,
    const float* __restrict__ f2, const float* __restrict__ f3,
    int h0, int h1, int h2, int h3,
    _Float16* __restrict__ poolH, _Float16* __restrict__ poolL,
    const float* __restrict__ W0, _Float16* __restrict__ W0tH, _Float16* __restrict__ W0tL,
    const float* __restrict__ W1, _Float16* __restrict__ W1tH, _Float16* __restrict__ W1tL,
    const float* __restrict__ Wc, const float* __restrict__ Wr,
    _Float16* __restrict__ WheadtH, _Float16* __restrict__ WheadtL,
    float4* __restrict__ zp, int zc4,
    int R, int K0, int CL)
{
    __shared__ float sh[64][65];
    int b = blockIdx.x, t = threadIdx.x;

    int NB_ROI = (R * 49) / 4;
    int KT0 = K0 / 64, NT0 = CL / 64;
    int NB_CW0 = KT0 * NT0;
    int KT1 = CL / 64;
    int NB_CW1 = KT1 * KT1;
    int NTc = (NCLS + 63) / 64;
    int NB_CWc = KT1 * NTc;
    int NTr = (NCLS * 4 + 63) / 64;
    int NB_CWr = KT1 * NTr;

    if (b < NB_ROI) {
        roi_f16v4_body(prop, imidx, f0, f1, f2, f3, h0, h1, h2, h3, b, t,
                       poolH, poolL);
        return;
    }
    b -= NB_ROI;
    if (b < NB_CW0) {
        int k0 = (b % KT0) * 64, n0 = (b / KT0) * 64;
        conv_fast_body(W0, W0tH, W0tL, K0, CL, k0, n0, t, sh);
        return;
    }
    b -= NB_CW0;
    if (b < NB_CW1) {
        int k0 = (b % KT1) * 64, n0 = (b / KT1) * 64;
        conv_fast_body(W1, W1tH, W1tL, CL, CL, k0, n0, t, sh);
        return;
    }
    b -= NB_CW1;
    if (b < NB_CWc) {
        int k0 = (b % KT1) * 64, n0 = (b / KT1) * 64;
        conv_guard_body(Wc, WheadtH, WheadtL, CL, NCLS, CL, 0, k0, n0, t, sh);
        return;
    }
    b -= NB_CWc;
    if (b < NB_CWr) {
        int k0 = (b % KT1) * 64, n0 = (b / KT1) * 64;
        conv_guard_body(Wr, WheadtH, WheadtL, CL, NCLS * 4, CL, NCLS, k0, n0, t, sh);
        return;
    }
    b -= NB_CWr;
    {
        int i = b * 256 + t;
        if (i < zc4) zp[i] = make_float4(0.f, 0.f, 0.f, 0.f);
    }
}

// ---------------------------------------------------------------------------
// Transpose-convert standalone kernels (kept for fallback-path parity; the
// MFMA path now uses pre_uber_k).
// ---------------------------------------------------------------------------
__global__ __launch_bounds__(256) void convert_w_t_k(const float* __restrict__ W,
                                                     _Float16* __restrict__ WtH,
                                                     _Float16* __restrict__ WtL,
                                                     int K, int N)
{
    __shared__ float sh[64][65];
    conv_fast_body(W, WtH, WtL, K, N, blockIdx.x * 64, blockIdx.y * 64,
                   threadIdx.x, sh);
}

__global__ __launch_bounds__(256) void convert_w_t_guard_k(const float* __restrict__ W,
                                                           _Float16* __restrict__ WtH,
                                                           _Float16* __restrict__ WtL,
                                                           int K, int N, int Kt, int rowofs)
{
    __shared__ float sh[64][65];
    conv_guard_body(W, WtH, WtL, K, N, Kt, rowofs, blockIdx.x * 64,
                    blockIdx.y * 64, threadIdx.x, sh);
}

// ---------------------------------------------------------------------------
// act-split: out = relu(acc + bias) -> f16 hi/lo. 4 elems/thread.
// ---------------------------------------------------------------------------
__global__ void act_split_k(const float* __restrict__ acc,
                            const float* __restrict__ bias,
                            _Float16* __restrict__ outH,
                            _Float16* __restrict__ outL,
                            int total, int CL)
{
    int i = (blockIdx.x * blockDim.x + threadIdx.x) * 4;
    if (i >= total) return;
    int b = i % CL;
    float4 v = *(const float4*)(acc + i);
    float4 bb = *(const float4*)(bias + b);
    const float* pv = (const float*)&v;
    const float* pb = (const float*)&bb;
    half4 h, l;
#pragma unroll
    for (int e = 0; e < 4; ++e) {
        float f = fmaxf(pv[e] + pb[e], 0.0f);
        _Float16 hh = (_Float16)f;
        h[e] = hh;
        l[e] = (_Float16)(f - (float)hh);
    }
    *(half4*)(outH + i) = h;
    *(half4*)(outL + i) = l;
}

// ---------------------------------------------------------------------------
// global->LDS DMA, width 16 (wave-uniform LDS base + lane*16)
// ---------------------------------------------------------------------------
__device__ __forceinline__ void dma16(const _Float16* g, _Float16* l)
{
    __builtin_amdgcn_global_load_lds(
        (const __attribute__((address_space(1))) unsigned int*)g,
        (__attribute__((address_space(3))) unsigned int*)l, 16, 0, 0);
}

// ---------------------------------------------------------------------------
// LDS granule swizzle (bank-conflict fix, both-sides-or-neither):
// verified round 3: SQ_LDS_BANK_CONFLICT 6.4M -> 0.
// ---------------------------------------------------------------------------
#define LDKE 32   /* halves per LDS row (64 B), unpadded for DMA */
#define DKQ_SWZ(lane)  ((((lane) & 3) ^ (((lane) >> 3) & 3)) << 3)
#define FK_SWZ(lane)   (((((lane) >> 4) ^ (((lane) >> 1) & 3))) << 3)

// ---------------------------------------------------------------------------
// Split-f16 MFMA GEMM, DMA staging, XCD-pinned 1-D grid (verified 103 us):
//   Cacc[M,N] += (Ah+Al)[M][K] @ (Bh+Bl)^T,  Bt given as [N][K].
// 128x128 block tile, BK=32, 256 thr (4 waves, 64x64 each).
// ---------------------------------------------------------------------------
__global__ __launch_bounds__(256) void gemm_mfma_split_k(
    const _Float16* __restrict__ Ah, const _Float16* __restrict__ Al,
    const _Float16* __restrict__ Bh, const _Float16* __restrict__ Bl,
    float* __restrict__ Cacc, int M, int N, int K, int Kc, int SP)
{
    __shared__ _Float16 sAh[128 * LDKE], sAl[128 * LDKE];
    __shared__ _Float16 sBh[128 * LDKE], sBl[128 * LDKE];

    int bid = blockIdx.x;
    int z = bid % SP;
    int q = bid / SP;
    int NT = N >> 7;
    int nn = q % NT;
    int m = q / NT;
    int m0 = m * 128, n0 = nn * 128;
    int kb = z * Kc;
    int ke = min(K, kb + Kc);

    int t = threadIdx.x;
    int lane = t & 63, w = t >> 6;
    int wr = w >> 1, wc = w & 1;          // 2x2 wave grid over 128x128
    int fr = lane & 15;                   // fragment row/col within 16
    int fk = FK_SWZ(lane);                // swizzled fragment granule offset

    int drow = w * 32 + (lane >> 2);
    int dkq = DKQ_SWZ(lane);
    const _Float16* gAh = Ah + (size_t)(m0 + drow) * K + dkq;
    const _Float16* gAl = Al + (size_t)(m0 + drow) * K + dkq;
    const _Float16* gBh = Bh + (size_t)(n0 + drow) * K + dkq;
    const _Float16* gBl = Bl + (size_t)(n0 + drow) * K + dkq;
    size_t rowskip = (size_t)16 * K;

    _Float16* lAh0 = &sAh[(w * 2 + 0) * 512];
    _Float16* lAh1 = &sAh[(w * 2 + 1) * 512];
    _Float16* lAl0 = &sAl[(w * 2 + 0) * 512];
    _Float16* lAl1 = &sAl[(w * 2 + 1) * 512];
    _Float16* lBh0 = &sBh[(w * 2 + 0) * 512];
    _Float16* lBh1 = &sBh[(w * 2 + 1) * 512];
    _Float16* lBl0 = &sBl[(w * 2 + 0) * 512];
    _Float16* lBl1 = &sBl[(w * 2 + 1) * 512];

    floatx4 acc[4][4] = {};

    for (int k0 = kb; k0 < ke; k0 += 32) {
        dma16(gAh + k0, lAh0);
        dma16(gAh + rowskip + k0, lAh1);
        dma16(gAl + k0, lAl0);
        dma16(gAl + rowskip + k0, lAl1);
        dma16(gBh + k0, lBh0);
        dma16(gBh + rowskip + k0, lBh1);
        dma16(gBl + k0, lBl0);
        dma16(gBl + rowskip + k0, lBl1);
        __syncthreads();   // drains vmcnt -> DMA data visible

        half8 ah[4], al[4], bh[4], bl[4];
#pragma unroll
        for (int i = 0; i < 4; ++i) {
            int ar = wr * 64 + i * 16 + fr;
            ah[i] = *(const half8*)&sAh[ar * LDKE + fk];
            al[i] = *(const half8*)&sAl[ar * LDKE + fk];
            int bc = wc * 64 + i * 16 + fr;
            bh[i] = *(const half8*)&sBh[bc * LDKE + fk];
            bl[i] = *(const half8*)&sBl[bc * LDKE + fk];
        }
#pragma unroll
        for (int i = 0; i < 4; ++i)
#pragma unroll
            for (int j = 0; j < 4; ++j) {
                acc[i][j] = __builtin_amdgcn_mfma_f32_16x16x32_f16(ah[i], bh[j], acc[i][j], 0, 0, 0);
                acc[i][j] = __builtin_amdgcn_mfma_f32_16x16x32_f16(ah[i], bl[j], acc[i][j], 0, 0, 0);
                acc[i][j] = __builtin_amdgcn_mfma_f32_16x16x32_f16(al[i], bh[j], acc[i][j], 0, 0, 0);
            }
        __syncthreads();   // LDS reads complete before next DMA overwrite
    }

    // epilogue: C/D layout col=lane&15, row=(lane>>4)*4+reg
    int rbase = (lane >> 4) * 4;
#pragma unroll
    for (int i = 0; i < 4; ++i)
#pragma unroll
        for (int j = 0; j < 4; ++j) {
            int col = n0 + wc * 64 + j * 16 + fr;
#pragma unroll
            for (int r = 0; r < 4; ++r) {
                int row = m0 + wr * 64 + i * 16 + rbase + r;
                atomicAdd(&Cacc[(size_t)row * N + col], acc[i][j][r]);
            }
        }
}

// ---------------------------------------------------------------------------
// Non-split fused MFMA GEMM, 64x64 tile, full-K accumulation in registers,
// double-buffered LDS 2-phase prefetch. Same granule swizzle.
// ---------------------------------------------------------------------------
__global__ __launch_bounds__(256) void gemm_mfma_fused64_k(
    const _Float16* __restrict__ Ah, const _Float16* __restrict__ Al,
    const _Float16* __restrict__ Bh, const _Float16* __restrict__ Bl,
    const float* __restrict__ bias,
    float* __restrict__ Cout,
    _Float16* __restrict__ outH, _Float16* __restrict__ outL,
    int M, int N, int K, int mode)
{
    __shared__ _Float16 sAh[2][64 * LDKE], sAl[2][64 * LDKE];
    __shared__ _Float16 sBh[2][64 * LDKE], sBl[2][64 * LDKE];

    int m0 = blockIdx.y * 64, n0 = blockIdx.x * 64;
    int t = threadIdx.x;
    int lane = t & 63, w = t >> 6;
    int wr = w >> 1, wc = w & 1;          // 2x2 wave grid over 64x64
    int fr = lane & 15;
    int fk = FK_SWZ(lane);

    int drow = w * 16 + (lane >> 2);
    int dkq = DKQ_SWZ(lane);
    const _Float16* gAh = Ah + (size_t)(m0 + drow) * K + dkq;
    const _Float16* gAl = Al + (size_t)(m0 + drow) * K + dkq;
    const _Float16* gBh = Bh + (size_t)(n0 + drow) * K + dkq;
    const _Float16* gBl = Bl + (size_t)(n0 + drow) * K + dkq;
    int lofs = w * 512;

    int nt = K >> 5;

    dma16(gAh + 0, &sAh[0][lofs]);
    dma16(gAl + 0, &sAl[0][lofs]);
    dma16(gBh + 0, &sBh[0][lofs]);
    dma16(gBl + 0, &sBl[0][lofs]);
    __syncthreads();

    floatx4 acc[2][2] = {};

    for (int tt = 0; tt < nt; ++tt) {
        int c = tt & 1, nb = c ^ 1;
        if (tt + 1 < nt) {
            int k1 = (tt + 1) << 5;
            dma16(gAh + k1, &sAh[nb][lofs]);
            dma16(gAl + k1, &sAl[nb][lofs]);
            dma16(gBh + k1, &sBh[nb][lofs]);
            dma16(gBl + k1, &sBl[nb][lofs]);
        }

        half8 ah[2], av[2], bh[2], bv[2];
#pragma unroll
        for (int i = 0; i < 2; ++i) {
            int ar = wr * 32 + i * 16 + fr;
            ah[i] = *(const half8*)&sAh[c][ar * LDKE + fk];
            av[i] = *(const half8*)&sAl[c][ar * LDKE + fk];
            int bc = wc * 32 + i * 16 + fr;
            bh[i] = *(const half8*)&sBh[c][bc * LDKE + fk];
            bv[i] = *(const half8*)&sBl[c][bc * LDKE + fk];
        }
#pragma unroll
        for (int i = 0; i < 2; ++i)
#pragma unroll
            for (int j = 0; j < 2; ++j) {
                acc[i][j] = __builtin_amdgcn_mfma_f32_16x16x32_f16(ah[i], bh[j], acc[i][j], 0, 0, 0);
                acc[i][j] = __builtin_amdgcn_mfma_f32_16x16x32_f16(ah[i], bv[j], acc[i][j], 0, 0, 0);
                acc[i][j] = __builtin_amdgcn_mfma_f32_16x16x32_f16(av[i], bh[j], acc[i][j], 0, 0, 0);
            }
        __syncthreads();   // staged data visible; all reads of buf c done
    }

    int rbase = (lane >> 4) * 4;
#pragma unroll
    for (int i = 0; i < 2; ++i)
#pragma unroll
        for (int j = 0; j < 2; ++j) {
            int col = n0 + wc * 32 + j * 16 + fr;
#pragma unroll
            for (int r = 0; r < 4; ++r) {
                int row = m0 + wr * 32 + i * 16 + rbase + r;
                float v = acc[i][j][r];
                if (mode == 0) {
                    Cout[(size_t)row * N + col] = v;
                } else {
                    float f = fmaxf(v + bias[col], 0.0f);
                    _Float16 hh = (_Float16)f;
                    outH[(size_t)row * N + col] = hh;
                    outL[(size_t)row * N + col] = (_Float16)(f - (float)hh);
                }
            }
        }
}

// ---------------------------------------------------------------------------
// fp32 split-K GEMM (fallback path only)
// ---------------------------------------------------------------------------
__global__ __launch_bounds__(256) void gemm_splitk_k(const float* __restrict__ A,
                                                     const float* __restrict__ B,
                                                     const float* __restrict__ abias,
                                                     float* __restrict__ Cacc,
                                                     int M, int N, int K, int Kc)
{
    __shared__ float Ast[16][68];
    __shared__ float Bs[16][68];

    int m0 = blockIdx.y * 64, n0 = blockIdx.x * 64;
    int kb = blockIdx.z * Kc;
    int ke = min(K, kb + Kc);
    int tid = threadIdx.x;
    int tx = tid & 15, ty = tid >> 4;
    int arow = tid >> 2, akq = (tid & 3) << 2;
    int bcol = tid & 63, bk = tid >> 6;

    const float* Arow = A + (size_t)(m0 + arow) * K;
    bool nfull = (n0 + 64 <= N);

    float acc[4][4] = {};

    for (int k0 = kb; k0 < ke; k0 += 16) {
        float4 av = *(const float4*)(Arow + k0 + akq);
        if (abias) {
            av.x = fmaxf(av.x + abias[k0 + akq + 0], 0.0f);
            av.y = fmaxf(av.y + abias[k0 + akq + 1], 0.0f);
            av.z = fmaxf(av.z + abias[k0 + akq + 2], 0.0f);
            av.w = fmaxf(av.w + abias[k0 + akq + 3], 0.0f);
        }
        float bv[4];
        if (nfull) {
#pragma unroll
            for (int e = 0; e < 4; ++e)
                bv[e] = B[(size_t)(k0 + bk * 4 + e) * N + n0 + bcol];
        } else {
            bool ok = (n0 + bcol) < N;
#pragma unroll
            for (int e = 0; e < 4; ++e)
                bv[e] = ok ? B[(size_t)(k0 + bk * 4 + e) * N + n0 + bcol] : 0.0f;
        }
        __syncthreads();
        Ast[akq + 0][arow] = av.x;
        Ast[akq + 1][arow] = av.y;
        Ast[akq + 2][arow] = av.z;
        Ast[akq + 3][arow] = av.w;
#pragma unroll
        for (int e = 0; e < 4; ++e) Bs[bk * 4 + e][bcol] = bv[e];
        __syncthreads();

#pragma unroll
        for (int kk = 0; kk < 16; ++kk) {
            float4 af = *(const float4*)&Ast[kk][ty * 4];
            float4 bf = *(const float4*)&Bs[kk][tx * 4];
            float a_[4] = {af.x, af.y, af.z, af.w};
            float b_[4] = {bf.x, bf.y, bf.z, bf.w};
#pragma unroll
            for (int i = 0; i < 4; ++i)
#pragma unroll
                for (int j = 0; j < 4; ++j)
                    acc[i][j] = fmaf(a_[i], b_[j], acc[i][j]);
        }
    }

#pragma unroll
    for (int i = 0; i < 4; ++i) {
        int row = m0 + ty * 4 + i;
#pragma unroll
        for (int j = 0; j < 4; ++j) {
            int col = n0 + tx * 4 + j;
            if (col < N) atomicAdd(&Cacc[(size_t)row * N + col], acc[i][j]);
        }
    }
}

// ---------------------------------------------------------------------------
// softmax over (logits + bc), classes 1..80. grid = R, block = 64.
// ---------------------------------------------------------------------------
__global__ void softmax_k(const float* __restrict__ logits, int ldl,
                          const float* __restrict__ bc,
                          float* __restrict__ scr)
{
    int r = blockIdx.x;
    int t = threadIdx.x;
    const float* row = logits + (size_t)r * ldl;

    float v0 = row[t] + bc[t];
    float v1 = (t + 64 < NCLS) ? (row[t + 64] + bc[t + 64]) : -INFINITY;
    float m = fmaxf(v0, v1);
#pragma unroll
    for (int o = 32; o > 0; o >>= 1) m = fmaxf(m, __shfl_down(m, o));
    m = __shfl(m, 0);

    float e0 = expf(v0 - m);
    float e1 = (t + 64 < NCLS) ? expf(v1 - m) : 0.0f;
    float sum = e0 + e1;
#pragma unroll
    for (int o = 32; o > 0; o >>= 1) sum += __shfl_down(sum, o);
    sum = __shfl(sum, 0);
    float inv = 1.0f / sum;

    if (t >= 1)        scr[(size_t)r * DCLS + (t - 1)]  = e0 * inv;
    if (t + 64 < NCLS) scr[(size_t)r * DCLS + (t + 63)] = e1 * inv;
}

// ---------------------------------------------------------------------------
// per-image NMS with fused box decode. grid = n, block = 1024.
// sort-once + sequential-scan (verified round 3, identical outputs).
// ---------------------------------------------------------------------------
#define NMS_T 1024
#define NMS_SORTMAX 4096
#define NMS_AMAX 512
__global__ __launch_bounds__(NMS_T) void nms_k(
    const float* __restrict__ scr,
    const float* __restrict__ prop,
    const int* __restrict__ imidx,
    const float* __restrict__ head, int ldh, int regofs,
    const float* __restrict__ br,
    const float* __restrict__ imsz,
    const float* __restrict__ score_thr_p,
    const float* __restrict__ min_size_p,
    const float* __restrict__ iou_thr_p,
    int* __restrict__ cidx,
    float* __restrict__ cscore,
    float* __restrict__ cbo,
    float* __restrict__ cbox,
    float* __restrict__ carea,
    float* __restrict__ out,
    int M, int n, int imtop)
{
    int img = blockIdx.x;
    int t = threadIdx.x;
    const int T = NMS_T;
    const int NW = NMS_T / 64;
    int lane = t & 63, wid = t >> 6;

    __shared__ int cnt;
    __shared__ unsigned long long skey[NMS_SORTMAX];
    __shared__ int sp_[NMS_SORTMAX];
    __shared__ float aab0[NMS_AMAX], aab1[NMS_AMAX], aab2[NMS_AMAX], aab3[NMS_AMAX], aaa[NMS_AMAX];
    __shared__ int f_it;
    __shared__ float ws_sc[NW];
    __shared__ int ws_g[NW], ws_p[NW];
    __shared__ float f_sc, f_o0, f_o1, f_o2, f_o3, f_ar;

    if (t == 0) cnt = 0;
    __syncthreads();

    float score_thr = score_thr_p[0];
    float min_size  = min_size_p[0];
    float iou_thr   = iou_thr_p[0];
    float immax = imsz[0];
    for (int q = 1; q < 2 * n; ++q) immax = fmaxf(immax, imsz[q]);

    int base = img * M;
    for (int j = t; j < M; j += T) {
        int r = j / DCLS;
        if (imidx[r] != img) continue;
        float s = scr[j];
        if (s <= score_thr) continue;

        int cls = j - r * DCLS + 1;
        const float* pr = prop + (size_t)r * 4;
        float pw = pr[2] - pr[0], ph = pr[3] - pr[1];
        float cx = (pr[0] + pr[2]) * 0.5f, cy = (pr[1] + pr[3]) * 0.5f;
        const float* rg_ = head + (size_t)r * ldh + regofs + cls * 4;
        const float* bb = br + cls * 4;
        float dx = (rg_[0] + bb[0]) * 0.1f;
        float dy = (rg_[1] + bb[1]) * 0.1f;
        float dw = fminf((rg_[2] + bb[2]) * 0.2f, FLOG_MAX);
        float dh = fminf((rg_[3] + bb[3]) * 0.2f, FLOG_MAX);
        float ncx = dx * pw + cx;
        float ncy = dy * ph + cy;
        float nw = expf(dw) * pw;
        float nh = expf(dh) * ph;
        float hbound = imsz[img * 2 + 0];
        float wbound = imsz[img * 2 + 1];
        float bx1 = fminf(fmaxf(ncx - nw * 0.5f, 0.0f), wbound);
        float bx2 = fminf(fmaxf(ncx + nw * 0.5f, 0.0f), wbound);
        float by1 = fminf(fmaxf(ncy - nh * 0.5f, 0.0f), hbound);
        float by2 = fminf(fmaxf(ncy + nh * 0.5f, 0.0f), hbound);
        if (bx2 - bx1 < min_size || by2 - by1 < min_size) continue;

        float off = (float)cls * (immax + 2.0f);
        int p = atomicAdd(&cnt, 1);
        cidx[base + p] = j;
        cscore[base + p] = s;
        cbox[(size_t)(base + p) * 4 + 0] = bx1;
        cbox[(size_t)(base + p) * 4 + 1] = by1;
        cbox[(size_t)(base + p) * 4 + 2] = bx2;
        cbox[(size_t)(base + p) * 4 + 3] = by2;
        cbo[(size_t)(base + p) * 4 + 0] = bx1 + off;
        cbo[(size_t)(base + p) * 4 + 1] = by1 + off;
        cbo[(size_t)(base + p) * 4 + 2] = bx2 + off;
        cbo[(size_t)(base + p) * 4 + 3] = by2 + off;
        carea[base + p] = (bx2 - bx1) * (by2 - by1);
    }
    __syncthreads();
    int K = cnt;

    float* ob  = out;
    float* osc = out + (size_t)n * imtop * 4;
    float* ocl = out + (size_t)n * imtop * 5;

    int it = 0;
    if (K <= NMS_SORTMAX && imtop <= NMS_AMAX) {
        // ---------------- sort + sequential-scan NMS ----------------
        int SN = 64; while (SN < K) SN <<= 1;
        for (int i = t; i < SN; i += T) {
            if (i < K) {
                unsigned int sb = __float_as_uint(cscore[base + i]);
                skey[i] = ((unsigned long long)sb << 32)
                        | (unsigned int)(~cidx[base + i]);
            } else {
                skey[i] = 0ull;
            }
            sp_[i] = i;
        }
        for (int k = 2; k <= SN; k <<= 1) {
            for (int j = k >> 1; j > 0; j >>= 1) {
                __syncthreads();
                for (int i = t; i < SN; i += T) {
                    int l = i ^ j;
                    if (l > i) {
                        unsigned long long ki = skey[i], kl = skey[l];
                        bool up = ((i & k) == 0);
                        bool sw = up ? (ki < kl) : (ki > kl);
                        if (sw) {
                            skey[i] = kl; skey[l] = ki;
                            int tp = sp_[i]; sp_[i] = sp_[l]; sp_[l] = tp;
                        }
                    }
                }
            }
        }
        __syncthreads();

        if (wid == 0) {
            int na = 0;
            for (int c0 = 0; c0 < K && na < imtop; c0 += 64) {
                int ci = c0 + lane;
                bool alive = ci < K;
                float x0 = 0.f, x1 = 0.f, x2 = 0.f, x3 = 0.f, ar_ = 0.f, sc = 0.f;
                float q0 = 0.f, q1 = 0.f, q2 = 0.f, q3 = 0.f;
                int g = 0;
                if (alive) {
                    unsigned long long key = skey[ci];
                    sc = __uint_as_float((unsigned int)(key >> 32));
                    int pp = sp_[ci];
                    g = cidx[base + pp];
                    x0 = cbo[(size_t)(base + pp) * 4 + 0];
                    x1 = cbo[(size_t)(base + pp) * 4 + 1];
                    x2 = cbo[(size_t)(base + pp) * 4 + 2];
                    x3 = cbo[(size_t)(base + pp) * 4 + 3];
                    ar_ = carea[base + pp];
                    q0 = cbox[(size_t)(base + pp) * 4 + 0];
                    q1 = cbox[(size_t)(base + pp) * 4 + 1];
                    q2 = cbox[(size_t)(base + pp) * 4 + 2];
                    q3 = cbox[(size_t)(base + pp) * 4 + 3];
                    if (sc <= 0.0f) alive = false;
                }
                for (int a = 0; a < na; ++a) {
                    float iw = fmaxf(fminf(aab2[a], x2) - fmaxf(aab0[a], x0), 0.0f);
                    float ih = fmaxf(fminf(aab3[a], x3) - fmaxf(aab1[a], x1), 0.0f);
                    float inter = iw * ih;
                    float iou = inter / (aaa[a] + ar_ - inter + 1e-6f);
                    if (iou > iou_thr) alive = false;
                }
                unsigned long long mm = __ballot(alive);
                while (mm != 0ull && na < imtop) {
                    int s = __ffsll(mm) - 1;
                    float b0 = __shfl(x0, s), b1 = __shfl(x1, s);
                    float b2v = __shfl(x2, s), b3v = __shfl(x3, s);
                    float ba = __shfl(ar_, s);
                    if (lane == s) {
                        size_t oslot = (size_t)img * imtop + na;
                        ob[oslot * 4 + 0] = q0;
                        ob[oslot * 4 + 1] = q1;
                        ob[oslot * 4 + 2] = q2;
                        ob[oslot * 4 + 3] = q3;
                        osc[oslot] = sc;
                        ocl[oslot] = (float)(g % DCLS + 1);
                        aab0[na] = x0; aab1[na] = x1; aab2[na] = x2; aab3[na] = x3;
                        aaa[na] = ar_;
                        alive = false;
                    }
                    na++;
                    if (alive && lane > s) {
                        float iw = fmaxf(fminf(b2v, x2) - fmaxf(b0, x0), 0.0f);
                        float ih = fmaxf(fminf(b3v, x3) - fmaxf(b1, x1), 0.0f);
                        float inter = iw * ih;
                        float iou = inter / (ba + ar_ - inter + 1e-6f);
                        if (iou > iou_thr) alive = false;
                    }
                    mm = __ballot(alive);
                }
            }
            if (lane == 0) f_it = na;
        }
        __syncthreads();
        it = f_it;
    } else {
        // ---------------- fallback: global-memory argmax loop ----------------
        for (; it < imtop; ++it) {
            float best = -1e30f; int bg = 0x7fffffff; int bl = -1;
            for (int p = t; p < K; p += T) {
                float sv = cscore[base + p];
                int g = cidx[base + p];
                if (sv > best || (sv == best && g < bg)) { best = sv; bg = g; bl = p; }
            }
#pragma unroll
            for (int o = 32; o > 0; o >>= 1) {
                float os = __shfl_down(best, o);
                int   og = __shfl_down(bg, o);
                int   ol = __shfl_down(bl, o);
                if (os > best || (os == best && og < bg)) { best = os; bg = og; bl = ol; }
            }
            if (lane == 0) { ws_sc[wid] = best; ws_g[wid] = bg; ws_p[wid] = bl; }
            __syncthreads();
            if (wid == 0) {
                float b2 = (lane < NW) ? ws_sc[lane] : -1e30f;
                int   g2 = (lane < NW) ? ws_g[lane] : 0x7fffffff;
                int   l2 = (lane < NW) ? ws_p[lane] : -1;
#pragma unroll
                for (int o = NW / 2; o > 0; o >>= 1) {
                    float os = __shfl_down(b2, o);
                    int   og = __shfl_down(g2, o);
                    int   ol = __shfl_down(l2, o);
                    if (os > b2 || (os == b2 && og < g2)) { b2 = os; g2 = og; l2 = ol; }
                }
                if (lane == 0) {
                    f_sc = b2;
                    if (b2 > 0.0f) {
                        int lp = l2;
                        size_t oslot = (size_t)img * imtop + it;
                        ob[oslot * 4 + 0] = cbox[(size_t)(base + lp) * 4 + 0];
                        ob[oslot * 4 + 1] = cbox[(size_t)(base + lp) * 4 + 1];
                        ob[oslot * 4 + 2] = cbox[(size_t)(base + lp) * 4 + 2];
                        ob[oslot * 4 + 3] = cbox[(size_t)(base + lp) * 4 + 3];
                        osc[oslot] = b2;
                        ocl[oslot] = (float)(g2 % DCLS + 1);
                        f_o0 = cbo[(size_t)(base + lp) * 4 + 0];
                        f_o1 = cbo[(size_t)(base + lp) * 4 + 1];
                        f_o2 = cbo[(size_t)(base + lp) * 4 + 2];
                        f_o3 = cbo[(size_t)(base + lp) * 4 + 3];
                        f_ar = carea[base + lp];
                        cscore[base + lp] = -1.0f;
                    }
                }
            }
            __syncthreads();
            if (f_sc <= 0.0f) break;

            float b0 = f_o0, b1 = f_o1, b2_ = f_o2, b3 = f_o3, ai = f_ar;
            for (int p = t; p < K; p += T) {
                float c0 = cbo[(size_t)(base + p) * 4 + 0];
                float c1 = cbo[(size_t)(base + p) * 4 + 1];
                float c2 = cbo[(size_t)(base + p) * 4 + 2];
                float c3 = cbo[(size_t)(base + p) * 4 + 3];
                float iw = fmaxf(fminf(b2_, c2) - fmaxf(b0, c0), 0.0f);
                float ih = fmaxf(fminf(b3, c3) - fmaxf(b1, c1), 0.0f);
                float inter = iw * ih;
                float iou = inter / (ai + carea[base + p] - inter + 1e-6f);
                if (iou > iou_thr) cscore[base + p] = -1.0f;
            }
            __syncthreads();
        }
    }

    for (int q = it + t; q < imtop; q += T) {
        size_t oslot = (size_t)img * imtop + q;
        ob[oslot * 4 + 0] = 0.0f;
        ob[oslot * 4 + 1] = 0.0f;
        ob[oslot * 4 + 2] = 0.0f;
        ob[oslot * 4 + 3] = 0.0f;
        osc[oslot] = 0.0f;
        ocl[oslot] = -1.0f;
    }
}

// ---------------------------------------------------------------------------
extern "C" void kernel_launch(void* const* d_in, const int* in_sizes, int n_in,
                              void* d_out, int out_size, void* d_ws, size_t ws_size,
                              hipStream_t stream)
{
    const float* prop   = (const float*)d_in[0];
    const int*   imidx  = (const int*)d_in[1];
    const float* f0     = (const float*)d_in[2];
    const float* f1     = (const float*)d_in[3];
    const float* f2     = (const float*)d_in[4];
    const float* f3     = (const float*)d_in[5];
    const float* W0     = (const float*)d_in[6];
    const float* b0     = (const float*)d_in[7];
    const float* W1     = (const float*)d_in[8];
    const float* b1     = (const float*)d_in[9];
    const float* Wc     = (const float*)d_in[10];
    const float* bc     = (const float*)d_in[11];
    const float* Wr     = (const float*)d_in[12];
    const float* br     = (const float*)d_in[13];
    const float* imsz   = (const float*)d_in[14];
    const float* sthr   = (const float*)d_in[15];
    const float* ithr   = (const float*)d_in[16];
    const float* msz    = (const float*)d_in[18];

    int R = in_sizes[1];              // 1024
    int n = in_sizes[14] / 2;         // 2
    int imtop = out_size / (n * 6);   // 100
    int M = R * DCLS;                 // 81920
    int K0 = NPOOL * NPOOL * CCH;     // 12544
    int CL = in_sizes[7];             // 1024

    int h0 = (int)(sqrtf((float)(in_sizes[2] / (n * CCH))) + 0.5f);
    int h1 = (int)(sqrtf((float)(in_sizes[3] / (n * CCH))) + 0.5f);
    int h2 = (int)(sqrtf((float)(in_sizes[4] / (n * CCH))) + 0.5f);
    int h3 = (int)(sqrtf((float)(in_sizes[5] / (n * CCH))) + 0.5f);

    float* outf = (float*)d_out;

    // ---- MFMA-path workspace layout (bytes) ----
    size_t szPool  = (size_t)R * K0 * 2;
    size_t szX     = (size_t)R * CL * 4;
    size_t szHead  = (size_t)R * NHEAD * 4;
    size_t szWh    = (size_t)NHEAD * CL * 2;
    size_t szXh    = (size_t)R * CL * 2;
    size_t szW1t   = (size_t)CL * CL * 2;
    size_t szScr   = (size_t)R * DCLS * 4;

    size_t needed = 4 * szPool + 2 * szX + szHead + 2 * szWh
                  + 4 * szXh + 2 * szW1t + szScr;

    int splitK0 = 8;                  // Kc = K0/8 = 1568 = 49*32
    bool mfma_ok = (ws_size >= needed) && (R % 128 == 0) && (CL % 128 == 0)
                 && (K0 % (splitK0 * 32) == 0) && (CL % 32 == 0)
                 && ((R * 49) % 4 == 0) && (K0 % 64 == 0) && (CL % 64 == 0);

    if (mfma_ok) {
        uint8_t* w = (uint8_t*)d_ws;
        size_t o = 0;
        _Float16* poolH   = (_Float16*)(w + o); o += szPool;
        _Float16* poolL   = (_Float16*)(w + o); o += szPool;
        _Float16* W0tH    = (_Float16*)(w + o); o += szPool;
        _Float16* W0tL    = (_Float16*)(w + o); o += szPool;
        float*    x0acc   = (float*)(w + o);    o += szX;
        float*    unused  = (float*)(w + o);    o += szX;   // (kept for layout stability)
        float*    headacc = (float*)(w + o);    o += szHead;
        _Float16* WheadtH = (_Float16*)(w + o); o += szWh;
        _Float16* WheadtL = (_Float16*)(w + o); o += szWh;
        _Float16* x0H     = (_Float16*)(w + o); o += szXh;
        _Float16* x0L     = (_Float16*)(w + o); o += szXh;
        _Float16* x1H     = (_Float16*)(w + o); o += szXh;
        _Float16* x1L     = (_Float16*)(w + o); o += szXh;
        _Float16* W1tH    = (_Float16*)(w + o); o += szW1t;
        _Float16* W1tL    = (_Float16*)(w + o); o += szW1t;
        float*    scr     = (float*)(w + o);
        (void)unused;

        // NMS compaction arrays alias the pool region (dead after FC0)
        int*   cidx   = (int*)d_ws;
        float* cscore = (float*)(cidx + (size_t)n * M);
        float* cbo    = cscore + (size_t)n * M;
        float* cbox   = cbo + (size_t)n * M * 4;
        float* carea  = cbox + (size_t)n * M * 4;

        // 1. fused pre-stage: roi + all weight converts + x0acc zero
        {
            int NB_ROI = (R * 49) / 4;
            int NB_CW0 = (K0 / 64) * (CL / 64);
            int NB_CW1 = (CL / 64) * (CL / 64);
            int NB_CWc = (CL / 64) * ((NCLS + 63) / 64);
            int NB_CWr = (CL / 64) * ((NCLS * 4 + 63) / 64);
            int zc4    = (int)(szX / 16);
            int NB_Z   = (zc4 + 255) / 256;
            int NB = NB_ROI + NB_CW0 + NB_CW1 + NB_CWc + NB_CWr + NB_Z;
            pre_uber_k<<<dim3(NB), dim3(256), 0, stream>>>(
                prop, imidx, f0, f1, f2, f3, h0, h1, h2, h3,
                poolH, poolL,
                W0, W0tH, W0tL,
                W1, W1tH, W1tL,
                Wc, Wr, WheadtH, WheadtL,
                (float4*)x0acc, zc4,
                R, K0, CL);
        }
        // 2. FC0: x0acc = pooled @ W0  (split-K 8, XCD-pinned 1-D grid of 512)
        gemm_mfma_split_k<<<dim3(splitK0 * (R / 128) * (CL / 128)), dim3(256), 0, stream>>>(
            poolH, poolL, W0tH, W0tL, x0acc, R, CL, K0, K0 / splitK0, splitK0);
        // 3. x0 = relu(x0acc + b0) -> hi/lo
        act_split_k<<<dim3((R * CL / 4 + 255) / 256), dim3(256), 0, stream>>>(
            x0acc, b0, x0H, x0L, R * CL, CL);
        // 4. FC1 fused: x1 = relu(x0 @ W1 + b1) -> hi/lo directly (no atomics)
        gemm_mfma_fused64_k<<<dim3(CL / 64, R / 64), dim3(256), 0, stream>>>(
            x0H, x0L, W1tH, W1tL, b1, nullptr, x1H, x1L, R, CL, CL, 1);
        // 5. combined heads fused: headacc = x1 @ [Wc|Wr] raw fp32 (N=512)
        gemm_mfma_fused64_k<<<dim3(NHEAD / 64, R / 64), dim3(256), 0, stream>>>(
            x1H, x1L, WheadtH, WheadtL, nullptr, headacc, nullptr, nullptr, R, NHEAD, CL, 0);
        // 6. softmax (+bc)
        softmax_k<<<dim3(R), dim3(64), 0, stream>>>(headacc, NHEAD, bc, scr);
        // 7. NMS with fused decode (+br)
        nms_k<<<dim3(n), dim3(NMS_T), 0, stream>>>(
            scr, prop, imidx, headacc, NHEAD, NCLS, br, imsz, sthr, msz, ithr,
            cidx, cscore, cbo, cbox, carea, outf, M, n, imtop);
    } else {
        // -------- fallback: all-fp32 pipeline --------
        float* ws = (float*)d_ws;
        size_t off = 0;
        float* pooled  = ws + off; off += (size_t)R * K0;
        float* x0acc   = ws + off; off += (size_t)R * CL;
        float* x1acc   = ws + off; off += (size_t)R * CL;
        float* logits  = ws + off; off += (size_t)R * NCLS;
        off = (off + 3) & ~(size_t)3;
        float* reg     = ws + off; off += (size_t)R * NCLS * 4;
        float* scr     = ws + off; off += (size_t)R * DCLS;

        int*   cidx   = (int*)ws;
        float* cscore = (float*)(cidx + (size_t)n * M);
        float* cbo    = cscore + (size_t)n * M;
        float* cbox   = cbo + (size_t)n * M * 4;
        float* carea  = cbox + (size_t)n * M * 4;

        {
            size_t zcount = (size_t)(reg + (size_t)R * NCLS * 4 - x0acc);
            int c4 = (int)(zcount / 4);
            zero_k<<<dim3((c4 + 255) / 256), dim3(256), 0, stream>>>((float4*)x0acc, c4);
        }
        roi_align_k<<<dim3(R * 49), dim3(256), 0, stream>>>(
            prop, imidx, f0, f1, f2, f3, h0, h1, h2, h3, pooled);
        gemm_splitk_k<<<dim3(CL / 64, R / 64, 8), dim3(256), 0, stream>>>(
            pooled, W0, nullptr, x0acc, R, CL, K0, 1568);
        gemm_splitk_k<<<dim3(CL / 64, R / 64, 4), dim3(256), 0, stream>>>(
            x0acc, W1, b0, x1acc, R, CL, CL, 256);
        gemm_splitk_k<<<dim3((NCLS + 63) / 64, R / 64, 8), dim3(256), 0, stream>>>(
            x1acc, Wc, b1, logits, R, NCLS, CL, 128);
        gemm_splitk_k<<<dim3((NCLS * 4 + 63) / 64, R / 64, 4), dim3(256), 0, stream>>>(
            x1acc, Wr, b1, reg, R, NCLS * 4, CL, 256);
        softmax_k<<<dim3(R), dim3(64), 0, stream>>>(logits, NCLS, bc, scr);
        nms_k<<<dim3(n), dim3(NMS_T), 0, stream>>>(
            scr, prop, imidx, reg, NCLS * 4, 0, br, imsz, sthr, msz, ithr,
            cidx, cscore, cbo, cbox, carea, outf, M, n, imtop);
    }
}

// Round 5
// 385.183 us; speedup vs baseline: 1.1668x; 1.0435x over previous
//
#include <hip/hip_runtime.h>
#include <math.h>

#define CCH 256
#define NPOOL 7
#define NCLS 81
#define DCLS 80
#define NHEAD 512            /* padded head width: 81 logits + 324 reg + pad */
#define FLOG_MAX 4.1351666f  /* log(1000/16) */

typedef _Float16 half8 __attribute__((ext_vector_type(8)));
typedef _Float16 half4 __attribute__((ext_vector_type(4)));
typedef float floatx4 __attribute__((ext_vector_type(4)));

// ---------------------------------------------------------------------------
// zero a region (float4 stores)  (fallback path only)
// ---------------------------------------------------------------------------
__global__ void zero_k(float4* __restrict__ p, int count4)
{
    int i = blockIdx.x * blockDim.x + threadIdx.x;
    if (i < count4) p[i] = make_float4(0.f, 0.f, 0.f, 0.f);
}

// ---------------------------------------------------------------------------
// RoI-align box math (per-cell scalar part)
// ---------------------------------------------------------------------------
__device__ __forceinline__ void roi_setup(
    const float* __restrict__ prop, const int* __restrict__ imidx,
    const float* __restrict__ f0, const float* __restrict__ f1,
    const float* __restrict__ f2, const float* __restrict__ f3,
    int h0, int h1, int h2, int h3, int b,
    const float*& base, int& W, size_t& o00, size_t& o01, size_t& o10, size_t& o11,
    float& w00, float& w01, float& w10, float& w11)
{
    int roi = b / 49, p = b % 49;
    int py = p / 7, px = p % 7;

    const float* pr = prop + (size_t)roi * 4;
    float x1 = pr[0], y1 = pr[1], x2 = pr[2], y2 = pr[3];
    float pw = x2 - x1, ph = y2 - y1;

    float lv = floorf(4.0f + log2f(sqrtf(pw * ph) / 224.0f + 1e-6f));
    lv = fminf(fmaxf(lv, 2.0f), 5.0f);
    int lvl = (int)lv - 2;

    const float* fm; int H; float s;
    if (lvl == 0)      { fm = f0; H = h0; s = 0.25f;    }
    else if (lvl == 1) { fm = f1; H = h1; s = 0.125f;   }
    else if (lvl == 2) { fm = f2; H = h2; s = 0.0625f;  }
    else               { fm = f3; H = h3; s = 0.03125f; }
    W = H;

    float xs1 = x1 * s, ys1 = y1 * s, xs2 = x2 * s, ys2 = y2 * s;
    float gx = (px + 0.5f) / 7.0f, gy = (py + 0.5f) / 7.0f;
    float xx = xs1 + gx * (xs2 - xs1) - 0.5f;
    float yy = ys1 + gy * (ys2 - ys1) - 0.5f;
    float x0f = floorf(xx), y0f = floorf(yy);
    float wx = xx - x0f, wy = yy - y0f;
    int x0i = min(max((int)x0f, 0), W - 1);
    int x1i = min(max((int)x0f + 1, 0), W - 1);
    int y0i = min(max((int)y0f, 0), H - 1);
    int y1i = min(max((int)y0f + 1, 0), H - 1);

    int ii = imidx[roi];
    base = fm + (size_t)ii * H * W * CCH;
    o00 = ((size_t)y0i * W + x0i) * CCH;
    o01 = ((size_t)y0i * W + x1i) * CCH;
    o10 = ((size_t)y1i * W + x0i) * CCH;
    o11 = ((size_t)y1i * W + x1i) * CCH;
    w00 = (1.0f - wx) * (1.0f - wy);
    w01 = wx * (1.0f - wy);
    w10 = (1.0f - wx) * wy;
    w11 = wx * wy;
}

// fp32 fallback variant: grid R*49 x 256 threads
__global__ void roi_align_k(const float* __restrict__ prop,
                            const int* __restrict__ imidx,
                            const float* __restrict__ f0,
                            const float* __restrict__ f1,
                            const float* __restrict__ f2,
                            const float* __restrict__ f3,
                            int h0, int h1, int h2, int h3,
                            float* __restrict__ pooled)
{
    int b = blockIdx.x, c = threadIdx.x;
    const float* base; int W; size_t o00, o01, o10, o11;
    float w00, w01, w10, w11;
    roi_setup(prop, imidx, f0, f1, f2, f3, h0, h1, h2, h3, b,
              base, W, o00, o01, o10, o11, w00, w01, w10, w11);
    float v = base[o00 + c] * w00 + base[o01 + c] * w01
            + base[o10 + c] * w10 + base[o11 + c] * w11;
    pooled[(size_t)b * CCH + c] = v;
}

// ---------------------------------------------------------------------------
// Device bodies shared by the fused pre-stage über-kernel.
// ---------------------------------------------------------------------------
__device__ __forceinline__ void roi_f16v4_body(
    const float* __restrict__ prop, const int* __restrict__ imidx,
    const float* __restrict__ f0, const float* __restrict__ f1,
    const float* __restrict__ f2, const float* __restrict__ f3,
    int h0, int h1, int h2, int h3, int bb, int t,
    _Float16* __restrict__ poolH, _Float16* __restrict__ poolL)
{
    int b = bb * 4 + (t >> 6);
    int lane = t & 63;
    const float* base; int W; size_t o00, o01, o10, o11;
    float w00, w01, w10, w11;
    roi_setup(prop, imidx, f0, f1, f2, f3, h0, h1, h2, h3, b,
              base, W, o00, o01, o10, o11, w00, w01, w10, w11);

    int c4 = lane * 4;
    float4 v00 = *(const float4*)(base + o00 + c4);
    float4 v01 = *(const float4*)(base + o01 + c4);
    float4 v10 = *(const float4*)(base + o10 + c4);
    float4 v11 = *(const float4*)(base + o11 + c4);
    const float* p00 = (const float*)&v00;
    const float* p01 = (const float*)&v01;
    const float* p10 = (const float*)&v10;
    const float* p11 = (const float*)&v11;

    half4 h, l;
#pragma unroll
    for (int e = 0; e < 4; ++e) {
        float v = p00[e] * w00 + p01[e] * w01 + p10[e] * w10 + p11[e] * w11;
        _Float16 hh = (_Float16)v;
        h[e] = hh;
        l[e] = (_Float16)(v - (float)hh);
    }
    size_t idx = (size_t)b * CCH + c4;
    *(half4*)(poolH + idx) = h;
    *(half4*)(poolL + idx) = l;
}

__device__ __forceinline__ void conv_fast_body(
    const float* __restrict__ W, _Float16* __restrict__ WtH,
    _Float16* __restrict__ WtL, int K, int N, int k0, int n0, int t,
    float (*sh)[65])
{
#pragma unroll
    for (int p = 0; p < 4; ++p) {
        int idx = p * 256 + t;
        int kr = idx >> 4, nc = (idx & 15) * 4;
        float4 v = *(const float4*)(W + (size_t)(k0 + kr) * N + n0 + nc);
        sh[kr][nc + 0] = v.x; sh[kr][nc + 1] = v.y;
        sh[kr][nc + 2] = v.z; sh[kr][nc + 3] = v.w;
    }
    __syncthreads();
#pragma unroll
    for (int p = 0; p < 4; ++p) {
        int idx = p * 256 + t;
        int nr = idx >> 4, kc = (idx & 15) * 4;
        half4 h, l;
#pragma unroll
        for (int i = 0; i < 4; ++i) {
            float v = sh[kc + i][nr];
            _Float16 hh = (_Float16)v;
            h[i] = hh;
            l[i] = (_Float16)(v - (float)hh);
        }
        *(half4*)(WtH + (size_t)(n0 + nr) * K + k0 + kc) = h;
        *(half4*)(WtL + (size_t)(n0 + nr) * K + k0 + kc) = l;
    }
}

__device__ __forceinline__ void conv_guard_body(
    const float* __restrict__ W, _Float16* __restrict__ WtH,
    _Float16* __restrict__ WtL, int K, int N, int Kt, int rowofs,
    int k0, int n0, int t, float (*sh)[65])
{
#pragma unroll
    for (int p = 0; p < 4; ++p) {
        int idx = p * 256 + t;
        int kr = idx >> 4, nc = (idx & 15) * 4;
#pragma unroll
        for (int e = 0; e < 4; ++e) {
            int nn = n0 + nc + e;
            sh[kr][nc + e] = (nn < N) ? W[(size_t)(k0 + kr) * N + nn] : 0.0f;
        }
    }
    __syncthreads();
#pragma unroll
    for (int p = 0; p < 4; ++p) {
        int idx = p * 256 + t;
        int nr = idx >> 4, kc = (idx & 15) * 4;
        if (n0 + nr < N) {
            half4 h, l;
#pragma unroll
            for (int i = 0; i < 4; ++i) {
                float v = sh[kc + i][nr];
                _Float16 hh = (_Float16)v;
                h[i] = hh;
                l[i] = (_Float16)(v - (float)hh);
            }
            *(half4*)(WtH + (size_t)(rowofs + n0 + nr) * Kt + k0 + kc) = h;
            *(half4*)(WtL + (size_t)(rowofs + n0 + nr) * Kt + k0 + kc) = l;
        }
    }
}

// ---------------------------------------------------------------------------
// Fused pre-FC0 stage (verified round 4: -17.5 us): RoI + weight converts +
// accumulator zero + NMS-counter zero in ONE launch.
// ---------------------------------------------------------------------------
__global__ __launch_bounds__(256) void pre_uber_k(
    const float* __restrict__ prop, const int* __restrict__ imidx,
    const float* __restrict__ f0, const float* __restrict__ f1,
    const float* __restrict__ f2, const float* __restrict__ f3,
    int h0, int h1, int h2, int h3,
    _Float16* __restrict__ poolH, _Float16* __restrict__ poolL,
    const float* __restrict__ W0, _Float16* __restrict__ W0tH, _Float16* __restrict__ W0tL,
    const float* __restrict__ W1, _Float16* __restrict__ W1tH, _Float16* __restrict__ W1tL,
    const float* __restrict__ Wc, const float* __restrict__ Wr,
    _Float16* __restrict__ WheadtH, _Float16* __restrict__ WheadtL,
    float4* __restrict__ zp, int zc4,
    int* __restrict__ cntp, int ncnt,
    int R, int K0, int CL)
{
    __shared__ float sh[64][65];
    int b = blockIdx.x, t = threadIdx.x;

    if (blockIdx.x == 0 && t < ncnt) cntp[t] = 0;

    int NB_ROI = (R * 49) / 4;
    int KT0 = K0 / 64, NT0 = CL / 64;
    int NB_CW0 = KT0 * NT0;
    int KT1 = CL / 64;
    int NB_CW1 = KT1 * KT1;
    int NTc = (NCLS + 63) / 64;
    int NB_CWc = KT1 * NTc;
    int NTr = (NCLS * 4 + 63) / 64;
    int NB_CWr = KT1 * NTr;

    if (b < NB_ROI) {
        roi_f16v4_body(prop, imidx, f0, f1, f2, f3, h0, h1, h2, h3, b, t,
                       poolH, poolL);
        return;
    }
    b -= NB_ROI;
    if (b < NB_CW0) {
        int k0 = (b % KT0) * 64, n0 = (b / KT0) * 64;
        conv_fast_body(W0, W0tH, W0tL, K0, CL, k0, n0, t, sh);
        return;
    }
    b -= NB_CW0;
    if (b < NB_CW1) {
        int k0 = (b % KT1) * 64, n0 = (b / KT1) * 64;
        conv_fast_body(W1, W1tH, W1tL, CL, CL, k0, n0, t, sh);
        return;
    }
    b -= NB_CW1;
    if (b < NB_CWc) {
        int k0 = (b % KT1) * 64, n0 = (b / KT1) * 64;
        conv_guard_body(Wc, WheadtH, WheadtL, CL, NCLS, CL, 0, k0, n0, t, sh);
        return;
    }
    b -= NB_CWc;
    if (b < NB_CWr) {
        int k0 = (b % KT1) * 64, n0 = (b / KT1) * 64;
        conv_guard_body(Wr, WheadtH, WheadtL, CL, NCLS * 4, CL, NCLS, k0, n0, t, sh);
        return;
    }
    b -= NB_CWr;
    {
        int i = b * 256 + t;
        if (i < zc4) zp[i] = make_float4(0.f, 0.f, 0.f, 0.f);
    }
}

// ---------------------------------------------------------------------------
// act-split: out = relu(acc + bias) -> f16 hi/lo. 4 elems/thread.
// ---------------------------------------------------------------------------
__global__ void act_split_k(const float* __restrict__ acc,
                            const float* __restrict__ bias,
                            _Float16* __restrict__ outH,
                            _Float16* __restrict__ outL,
                            int total, int CL)
{
    int i = (blockIdx.x * blockDim.x + threadIdx.x) * 4;
    if (i >= total) return;
    int b = i % CL;
    float4 v = *(const float4*)(acc + i);
    float4 bb = *(const float4*)(bias + b);
    const float* pv = (const float*)&v;
    const float* pb = (const float*)&bb;
    half4 h, l;
#pragma unroll
    for (int e = 0; e < 4; ++e) {
        float f = fmaxf(pv[e] + pb[e], 0.0f);
        _Float16 hh = (_Float16)f;
        h[e] = hh;
        l[e] = (_Float16)(f - (float)hh);
    }
    *(half4*)(outH + i) = h;
    *(half4*)(outL + i) = l;
}

// ---------------------------------------------------------------------------
// global->LDS DMA, width 16 (wave-uniform LDS base + lane*16)
// ---------------------------------------------------------------------------
__device__ __forceinline__ void dma16(const _Float16* g, _Float16* l)
{
    __builtin_amdgcn_global_load_lds(
        (const __attribute__((address_space(1))) unsigned int*)g,
        (__attribute__((address_space(3))) unsigned int*)l, 16, 0, 0);
}

// ---------------------------------------------------------------------------
// LDS granule swizzle (verified round 3: SQ_LDS_BANK_CONFLICT 6.4M -> 0)
// ---------------------------------------------------------------------------
#define LDKE 32   /* halves per LDS row (64 B), unpadded for DMA */
#define DKQ_SWZ(lane)  ((((lane) & 3) ^ (((lane) >> 3) & 3)) << 3)
#define FK_SWZ(lane)   (((((lane) >> 4) ^ (((lane) >> 1) & 3))) << 3)

// ---------------------------------------------------------------------------
// Split-f16 MFMA GEMM, DMA staging, XCD-pinned 1-D grid.
// Tile 128x64 (was 128x128): grid = SP*(M/128)*(N/64) -> 4 blocks/CU for
// the FC0 shape, doubling resident blocks to overlap the per-K-step barrier
// drain. SP=8 keeps the XCD pinning property (bid%8 == z).
// 256 thr = 4 waves (2x2 grid of 64x32 wave tiles). LDS 24 KB.
// Requires M%128==0, N%64==0, Kc%32==0.
// ---------------------------------------------------------------------------
__global__ __launch_bounds__(256) void gemm_mfma_split_k(
    const _Float16* __restrict__ Ah, const _Float16* __restrict__ Al,
    const _Float16* __restrict__ Bh, const _Float16* __restrict__ Bl,
    float* __restrict__ Cacc, int M, int N, int K, int Kc, int SP)
{
    __shared__ _Float16 sAh[128 * LDKE], sAl[128 * LDKE];
    __shared__ _Float16 sBh[64 * LDKE],  sBl[64 * LDKE];

    int bid = blockIdx.x;
    int z = bid % SP;
    int q = bid / SP;
    int NT = N >> 6;
    int nn = q % NT;
    int m = q / NT;
    int m0 = m * 128, n0 = nn * 64;
    int kb = z * Kc;
    int ke = min(K, kb + Kc);

    int t = threadIdx.x;
    int lane = t & 63, w = t >> 6;
    int wr = w >> 1, wc = w & 1;          // 2x2 wave grid over 128x64
    int fr = lane & 15;                   // fragment row/col within 16
    int fk = FK_SWZ(lane);                // swizzled fragment granule offset

    // staging: wave w -> A chunks {2w,2w+1} (16 rows x 64 B each), B chunk w
    int drowA = w * 32 + (lane >> 2);
    int drowB = w * 16 + (lane >> 2);
    int dkq = DKQ_SWZ(lane);
    const _Float16* gAh = Ah + (size_t)(m0 + drowA) * K + dkq;
    const _Float16* gAl = Al + (size_t)(m0 + drowA) * K + dkq;
    const _Float16* gBh = Bh + (size_t)(n0 + drowB) * K + dkq;
    const _Float16* gBl = Bl + (size_t)(n0 + drowB) * K + dkq;
    size_t rowskip = (size_t)16 * K;

    _Float16* lAh0 = &sAh[(w * 2 + 0) * 512];
    _Float16* lAh1 = &sAh[(w * 2 + 1) * 512];
    _Float16* lAl0 = &sAl[(w * 2 + 0) * 512];
    _Float16* lAl1 = &sAl[(w * 2 + 1) * 512];
    _Float16* lBh  = &sBh[w * 512];
    _Float16* lBl  = &sBl[w * 512];

    floatx4 acc[4][2] = {};

    for (int k0 = kb; k0 < ke; k0 += 32) {
        dma16(gAh + k0, lAh0);
        dma16(gAh + rowskip + k0, lAh1);
        dma16(gAl + k0, lAl0);
        dma16(gAl + rowskip + k0, lAl1);
        dma16(gBh + k0, lBh);
        dma16(gBl + k0, lBl);
        __syncthreads();   // drains vmcnt -> DMA data visible

        half8 ah[4], al[4], bh[2], bl[2];
#pragma unroll
        for (int i = 0; i < 4; ++i) {
            int ar = wr * 64 + i * 16 + fr;
            ah[i] = *(const half8*)&sAh[ar * LDKE + fk];
            al[i] = *(const half8*)&sAl[ar * LDKE + fk];
        }
#pragma unroll
        for (int j = 0; j < 2; ++j) {
            int bcc = wc * 32 + j * 16 + fr;
            bh[j] = *(const half8*)&sBh[bcc * LDKE + fk];
            bl[j] = *(const half8*)&sBl[bcc * LDKE + fk];
        }
#pragma unroll
        for (int i = 0; i < 4; ++i)
#pragma unroll
            for (int j = 0; j < 2; ++j) {
                acc[i][j] = __builtin_amdgcn_mfma_f32_16x16x32_f16(ah[i], bh[j], acc[i][j], 0, 0, 0);
                acc[i][j] = __builtin_amdgcn_mfma_f32_16x16x32_f16(ah[i], bl[j], acc[i][j], 0, 0, 0);
                acc[i][j] = __builtin_amdgcn_mfma_f32_16x16x32_f16(al[i], bh[j], acc[i][j], 0, 0, 0);
            }
        __syncthreads();   // LDS reads complete before next DMA overwrite
    }

    // epilogue: C/D layout col=lane&15, row=(lane>>4)*4+reg
    int rbase = (lane >> 4) * 4;
#pragma unroll
    for (int i = 0; i < 4; ++i)
#pragma unroll
        for (int j = 0; j < 2; ++j) {
            int col = n0 + wc * 32 + j * 16 + fr;
#pragma unroll
            for (int r = 0; r < 4; ++r) {
                int row = m0 + wr * 64 + i * 16 + rbase + r;
                atomicAdd(&Cacc[(size_t)row * N + col], acc[i][j][r]);
            }
        }
}

// ---------------------------------------------------------------------------
// Non-split fused MFMA GEMM, 64x64 tile, double-buffered 2-phase prefetch.
// ---------------------------------------------------------------------------
__global__ __launch_bounds__(256) void gemm_mfma_fused64_k(
    const _Float16* __restrict__ Ah, const _Float16* __restrict__ Al,
    const _Float16* __restrict__ Bh, const _Float16* __restrict__ Bl,
    const float* __restrict__ bias,
    float* __restrict__ Cout,
    _Float16* __restrict__ outH, _Float16* __restrict__ outL,
    int M, int N, int K, int mode)
{
    __shared__ _Float16 sAh[2][64 * LDKE], sAl[2][64 * LDKE];
    __shared__ _Float16 sBh[2][64 * LDKE], sBl[2][64 * LDKE];

    int m0 = blockIdx.y * 64, n0 = blockIdx.x * 64;
    int t = threadIdx.x;
    int lane = t & 63, w = t >> 6;
    int wr = w >> 1, wc = w & 1;
    int fr = lane & 15;
    int fk = FK_SWZ(lane);

    int drow = w * 16 + (lane >> 2);
    int dkq = DKQ_SWZ(lane);
    const _Float16* gAh = Ah + (size_t)(m0 + drow) * K + dkq;
    const _Float16* gAl = Al + (size_t)(m0 + drow) * K + dkq;
    const _Float16* gBh = Bh + (size_t)(n0 + drow) * K + dkq;
    const _Float16* gBl = Bl + (size_t)(n0 + drow) * K + dkq;
    int lofs = w * 512;

    int nt = K >> 5;

    dma16(gAh + 0, &sAh[0][lofs]);
    dma16(gAl + 0, &sAl[0][lofs]);
    dma16(gBh + 0, &sBh[0][lofs]);
    dma16(gBl + 0, &sBl[0][lofs]);
    __syncthreads();

    floatx4 acc[2][2] = {};

    for (int tt = 0; tt < nt; ++tt) {
        int c = tt & 1, nb = c ^ 1;
        if (tt + 1 < nt) {
            int k1 = (tt + 1) << 5;
            dma16(gAh + k1, &sAh[nb][lofs]);
            dma16(gAl + k1, &sAl[nb][lofs]);
            dma16(gBh + k1, &sBh[nb][lofs]);
            dma16(gBl + k1, &sBl[nb][lofs]);
        }

        half8 ah[2], av[2], bh[2], bv[2];
#pragma unroll
        for (int i = 0; i < 2; ++i) {
            int ar = wr * 32 + i * 16 + fr;
            ah[i] = *(const half8*)&sAh[c][ar * LDKE + fk];
            av[i] = *(const half8*)&sAl[c][ar * LDKE + fk];
            int bc = wc * 32 + i * 16 + fr;
            bh[i] = *(const half8*)&sBh[c][bc * LDKE + fk];
            bv[i] = *(const half8*)&sBl[c][bc * LDKE + fk];
        }
#pragma unroll
        for (int i = 0; i < 2; ++i)
#pragma unroll
            for (int j = 0; j < 2; ++j) {
                acc[i][j] = __builtin_amdgcn_mfma_f32_16x16x32_f16(ah[i], bh[j], acc[i][j], 0, 0, 0);
                acc[i][j] = __builtin_amdgcn_mfma_f32_16x16x32_f16(ah[i], bv[j], acc[i][j], 0, 0, 0);
                acc[i][j] = __builtin_amdgcn_mfma_f32_16x16x32_f16(av[i], bh[j], acc[i][j], 0, 0, 0);
            }
        __syncthreads();
    }

    int rbase = (lane >> 4) * 4;
#pragma unroll
    for (int i = 0; i < 2; ++i)
#pragma unroll
        for (int j = 0; j < 2; ++j) {
            int col = n0 + wc * 32 + j * 16 + fr;
#pragma unroll
            for (int r = 0; r < 4; ++r) {
                int row = m0 + wr * 32 + i * 16 + rbase + r;
                float v = acc[i][j][r];
                if (mode == 0) {
                    Cout[(size_t)row * N + col] = v;
                } else {
                    float f = fmaxf(v + bias[col], 0.0f);
                    _Float16 hh = (_Float16)f;
                    outH[(size_t)row * N + col] = hh;
                    outL[(size_t)row * N + col] = (_Float16)(f - (float)hh);
                }
            }
        }
}

// ---------------------------------------------------------------------------
// fp32 split-K GEMM (fallback path only)
// ---------------------------------------------------------------------------
__global__ __launch_bounds__(256) void gemm_splitk_k(const float* __restrict__ A,
                                                     const float* __restrict__ B,
                                                     const float* __restrict__ abias,
                                                     float* __restrict__ Cacc,
                                                     int M, int N, int K, int Kc)
{
    __shared__ float Ast[16][68];
    __shared__ float Bs[16][68];

    int m0 = blockIdx.y * 64, n0 = blockIdx.x * 64;
    int kb = blockIdx.z * Kc;
    int ke = min(K, kb + Kc);
    int tid = threadIdx.x;
    int tx = tid & 15, ty = tid >> 4;
    int arow = tid >> 2, akq = (tid & 3) << 2;
    int bcol = tid & 63, bk = tid >> 6;

    const float* Arow = A + (size_t)(m0 + arow) * K;
    bool nfull = (n0 + 64 <= N);

    float acc[4][4] = {};

    for (int k0 = kb; k0 < ke; k0 += 16) {
        float4 av = *(const float4*)(Arow + k0 + akq);
        if (abias) {
            av.x = fmaxf(av.x + abias[k0 + akq + 0], 0.0f);
            av.y = fmaxf(av.y + abias[k0 + akq + 1], 0.0f);
            av.z = fmaxf(av.z + abias[k0 + akq + 2], 0.0f);
            av.w = fmaxf(av.w + abias[k0 + akq + 3], 0.0f);
        }
        float bv[4];
        if (nfull) {
#pragma unroll
            for (int e = 0; e < 4; ++e)
                bv[e] = B[(size_t)(k0 + bk * 4 + e) * N + n0 + bcol];
        } else {
            bool ok = (n0 + bcol) < N;
#pragma unroll
            for (int e = 0; e < 4; ++e)
                bv[e] = ok ? B[(size_t)(k0 + bk * 4 + e) * N + n0 + bcol] : 0.0f;
        }
        __syncthreads();
        Ast[akq + 0][arow] = av.x;
        Ast[akq + 1][arow] = av.y;
        Ast[akq + 2][arow] = av.z;
        Ast[akq + 3][arow] = av.w;
#pragma unroll
        for (int e = 0; e < 4; ++e) Bs[bk * 4 + e][bcol] = bv[e];
        __syncthreads();

#pragma unroll
        for (int kk = 0; kk < 16; ++kk) {
            float4 af = *(const float4*)&Ast[kk][ty * 4];
            float4 bf = *(const float4*)&Bs[kk][tx * 4];
            float a_[4] = {af.x, af.y, af.z, af.w};
            float b_[4] = {bf.x, bf.y, bf.z, bf.w};
#pragma unroll
            for (int i = 0; i < 4; ++i)
#pragma unroll
                for (int j = 0; j < 4; ++j)
                    acc[i][j] = fmaf(a_[i], b_[j], acc[i][j]);
        }
    }

#pragma unroll
    for (int i = 0; i < 4; ++i) {
        int row = m0 + ty * 4 + i;
#pragma unroll
        for (int j = 0; j < 4; ++j) {
            int col = n0 + tx * 4 + j;
            if (col < N) atomicAdd(&Cacc[(size_t)row * N + col], acc[i][j]);
        }
    }
}

// ---------------------------------------------------------------------------
// softmax over (logits + bc), classes 1..80. grid = R, block = 64.
// (fallback path only; MFMA path folds softmax into compact_k)
// ---------------------------------------------------------------------------
__global__ void softmax_k(const float* __restrict__ logits, int ldl,
                          const float* __restrict__ bc,
                          float* __restrict__ scr)
{
    int r = blockIdx.x;
    int t = threadIdx.x;
    const float* row = logits + (size_t)r * ldl;

    float v0 = row[t] + bc[t];
    float v1 = (t + 64 < NCLS) ? (row[t + 64] + bc[t + 64]) : -INFINITY;
    float m = fmaxf(v0, v1);
#pragma unroll
    for (int o = 32; o > 0; o >>= 1) m = fmaxf(m, __shfl_down(m, o));
    m = __shfl(m, 0);

    float e0 = expf(v0 - m);
    float e1 = (t + 64 < NCLS) ? expf(v1 - m) : 0.0f;
    float sum = e0 + e1;
#pragma unroll
    for (int o = 32; o > 0; o >>= 1) sum += __shfl_down(sum, o);
    sum = __shfl(sum, 0);
    float inv = 1.0f / sum;

    if (t >= 1)        scr[(size_t)r * DCLS + (t - 1)]  = e0 * inv;
    if (t + 64 < NCLS) scr[(size_t)r * DCLS + (t + 63)] = e1 * inv;
}

// ---------------------------------------------------------------------------
// Fused softmax + threshold + box-decode + compaction. One WAVE per roi
// (grid R/4 x 256 thr). The softmax reduction replicates softmax_k's wave
// shuffle trees verbatim -> bit-identical scores. Lanes then decode the 80
// classes in 2 lane-parallel passes; passers are compacted via atomicAdd
// into per-image arrays. Runs on 256 blocks instead of NMS's old grid-2
// serial compaction scan.
// ---------------------------------------------------------------------------
__global__ __launch_bounds__(256) void compact_k(
    const float* __restrict__ head, int ldh, int regofs,
    const float* __restrict__ bc,
    const float* __restrict__ br,
    const float* __restrict__ prop,
    const int* __restrict__ imidx,
    const float* __restrict__ imsz,
    const float* __restrict__ score_thr_p,
    const float* __restrict__ min_size_p,
    int* __restrict__ cntp,
    int* __restrict__ cidx,
    float* __restrict__ cscore,
    float* __restrict__ cbo,
    float* __restrict__ cbox,
    float* __restrict__ carea,
    int M, int n, int R)
{
    int wid = threadIdx.x >> 6, t = threadIdx.x & 63;
    int r = blockIdx.x * 4 + wid;
    if (r >= R) return;

    const float* row = head + (size_t)r * ldh;
    float v0 = row[t] + bc[t];
    float v1 = (t + 64 < NCLS) ? (row[t + 64] + bc[t + 64]) : -INFINITY;
    float m = fmaxf(v0, v1);
#pragma unroll
    for (int o = 32; o > 0; o >>= 1) m = fmaxf(m, __shfl_down(m, o));
    m = __shfl(m, 0);

    float e0 = expf(v0 - m);
    float e1 = (t + 64 < NCLS) ? expf(v1 - m) : 0.0f;
    float sum = e0 + e1;
#pragma unroll
    for (int o = 32; o > 0; o >>= 1) sum += __shfl_down(sum, o);
    sum = __shfl(sum, 0);
    float inv = 1.0f / sum;

    float score_thr = score_thr_p[0];
    float min_size  = min_size_p[0];
    float immax = imsz[0];
    for (int q = 1; q < 2 * n; ++q) immax = fmaxf(immax, imsz[q]);

    int img = imidx[r];
    int base = img * M;
    const float* pr = prop + (size_t)r * 4;
    float pw = pr[2] - pr[0], ph = pr[3] - pr[1];
    float cx = (pr[0] + pr[2]) * 0.5f, cy = (pr[1] + pr[3]) * 0.5f;
    float hbound = imsz[img * 2 + 0];
    float wbound = imsz[img * 2 + 1];

#pragma unroll
    for (int pass = 0; pass < 2; ++pass) {
        int cls; float s; bool active;
        if (pass == 0) { cls = t;      s = e0 * inv; active = (t >= 1); }
        else           { cls = t + 64; s = e1 * inv; active = (t + 64 < NCLS); }
        if (!active || s <= score_thr) continue;

        const float* rg_ = head + (size_t)r * ldh + regofs + cls * 4;
        const float* bb = br + cls * 4;
        float dx = (rg_[0] + bb[0]) * 0.1f;
        float dy = (rg_[1] + bb[1]) * 0.1f;
        float dw = fminf((rg_[2] + bb[2]) * 0.2f, FLOG_MAX);
        float dh = fminf((rg_[3] + bb[3]) * 0.2f, FLOG_MAX);
        float ncx = dx * pw + cx;
        float ncy = dy * ph + cy;
        float nw = expf(dw) * pw;
        float nh = expf(dh) * ph;
        float bx1 = fminf(fmaxf(ncx - nw * 0.5f, 0.0f), wbound);
        float bx2 = fminf(fmaxf(ncx + nw * 0.5f, 0.0f), wbound);
        float by1 = fminf(fmaxf(ncy - nh * 0.5f, 0.0f), hbound);
        float by2 = fminf(fmaxf(ncy + nh * 0.5f, 0.0f), hbound);
        if (bx2 - bx1 < min_size || by2 - by1 < min_size) continue;

        float off = (float)cls * (immax + 2.0f);
        int j = r * DCLS + cls - 1;
        int p = atomicAdd(&cntp[img], 1);
        cidx[base + p] = j;
        cscore[base + p] = s;
        cbox[(size_t)(base + p) * 4 + 0] = bx1;
        cbox[(size_t)(base + p) * 4 + 1] = by1;
        cbox[(size_t)(base + p) * 4 + 2] = bx2;
        cbox[(size_t)(base + p) * 4 + 3] = by2;
        cbo[(size_t)(base + p) * 4 + 0] = bx1 + off;
        cbo[(size_t)(base + p) * 4 + 1] = by1 + off;
        cbo[(size_t)(base + p) * 4 + 2] = bx2 + off;
        cbo[(size_t)(base + p) * 4 + 3] = by2 + off;
        carea[base + p] = (bx2 - bx1) * (by2 - by1);
    }
}

// ---------------------------------------------------------------------------
// NMS pick: sort-once + sequential-scan (verified round 3). grid = n,
// block = 1024. Compaction now done by compact_k; K read from cntp.
// ---------------------------------------------------------------------------
#define NMS_T 1024
#define NMS_SORTMAX 4096
#define NMS_AMAX 512
__global__ __launch_bounds__(NMS_T) void nms_pick_k(
    const float* __restrict__ iou_thr_p,
    const int* __restrict__ cntp,
    int* __restrict__ cidx,
    float* __restrict__ cscore,
    float* __restrict__ cbo,
    float* __restrict__ cbox,
    float* __restrict__ carea,
    float* __restrict__ out,
    int M, int n, int imtop)
{
    int img = blockIdx.x;
    int t = threadIdx.x;
    const int T = NMS_T;
    const int NW = NMS_T / 64;
    int lane = t & 63, wid = t >> 6;

    __shared__ unsigned long long skey[NMS_SORTMAX];
    __shared__ int sp_[NMS_SORTMAX];
    __shared__ float aab0[NMS_AMAX], aab1[NMS_AMAX], aab2[NMS_AMAX], aab3[NMS_AMAX], aaa[NMS_AMAX];
    __shared__ int f_it;
    __shared__ float ws_sc[NW];
    __shared__ int ws_g[NW], ws_p[NW];
    __shared__ float f_sc, f_o0, f_o1, f_o2, f_o3, f_ar;

    float iou_thr = iou_thr_p[0];
    int K = cntp[img];
    int base = img * M;

    float* ob  = out;
    float* osc = out + (size_t)n * imtop * 4;
    float* ocl = out + (size_t)n * imtop * 5;

    int it = 0;
    if (K <= NMS_SORTMAX && imtop <= NMS_AMAX) {
        int SN = 64; while (SN < K) SN <<= 1;
        for (int i = t; i < SN; i += T) {
            if (i < K) {
                unsigned int sb = __float_as_uint(cscore[base + i]);
                skey[i] = ((unsigned long long)sb << 32)
                        | (unsigned int)(~cidx[base + i]);
            } else {
                skey[i] = 0ull;
            }
            sp_[i] = i;
        }
        for (int k = 2; k <= SN; k <<= 1) {
            for (int j = k >> 1; j > 0; j >>= 1) {
                __syncthreads();
                for (int i = t; i < SN; i += T) {
                    int l = i ^ j;
                    if (l > i) {
                        unsigned long long ki = skey[i], kl = skey[l];
                        bool up = ((i & k) == 0);
                        bool sw = up ? (ki < kl) : (ki > kl);
                        if (sw) {
                            skey[i] = kl; skey[l] = ki;
                            int tp = sp_[i]; sp_[i] = sp_[l]; sp_[l] = tp;
                        }
                    }
                }
            }
        }
        __syncthreads();

        if (wid == 0) {
            int na = 0;
            for (int c0 = 0; c0 < K && na < imtop; c0 += 64) {
                int ci = c0 + lane;
                bool alive = ci < K;
                float x0 = 0.f, x1 = 0.f, x2 = 0.f, x3 = 0.f, ar_ = 0.f, sc = 0.f;
                float q0 = 0.f, q1 = 0.f, q2 = 0.f, q3 = 0.f;
                int g = 0;
                if (alive) {
                    unsigned long long key = skey[ci];
                    sc = __uint_as_float((unsigned int)(key >> 32));
                    int pp = sp_[ci];
                    g = cidx[base + pp];
                    x0 = cbo[(size_t)(base + pp) * 4 + 0];
                    x1 = cbo[(size_t)(base + pp) * 4 + 1];
                    x2 = cbo[(size_t)(base + pp) * 4 + 2];
                    x3 = cbo[(size_t)(base + pp) * 4 + 3];
                    ar_ = carea[base + pp];
                    q0 = cbox[(size_t)(base + pp) * 4 + 0];
                    q1 = cbox[(size_t)(base + pp) * 4 + 1];
                    q2 = cbox[(size_t)(base + pp) * 4 + 2];
                    q3 = cbox[(size_t)(base + pp) * 4 + 3];
                    if (sc <= 0.0f) alive = false;
                }
                for (int a = 0; a < na; ++a) {
                    float iw = fmaxf(fminf(aab2[a], x2) - fmaxf(aab0[a], x0), 0.0f);
                    float ih = fmaxf(fminf(aab3[a], x3) - fmaxf(aab1[a], x1), 0.0f);
                    float inter = iw * ih;
                    float iou = inter / (aaa[a] + ar_ - inter + 1e-6f);
                    if (iou > iou_thr) alive = false;
                }
                unsigned long long mm = __ballot(alive);
                while (mm != 0ull && na < imtop) {
                    int s = __ffsll(mm) - 1;
                    float b0 = __shfl(x0, s), b1 = __shfl(x1, s);
                    float b2v = __shfl(x2, s), b3v = __shfl(x3, s);
                    float ba = __shfl(ar_, s);
                    if (lane == s) {
                        size_t oslot = (size_t)img * imtop + na;
                        ob[oslot * 4 + 0] = q0;
                        ob[oslot * 4 + 1] = q1;
                        ob[oslot * 4 + 2] = q2;
                        ob[oslot * 4 + 3] = q3;
                        osc[oslot] = sc;
                        ocl[oslot] = (float)(g % DCLS + 1);
                        aab0[na] = x0; aab1[na] = x1; aab2[na] = x2; aab3[na] = x3;
                        aaa[na] = ar_;
                        alive = false;
                    }
                    na++;
                    if (alive && lane > s) {
                        float iw = fmaxf(fminf(b2v, x2) - fmaxf(b0, x0), 0.0f);
                        float ih = fmaxf(fminf(b3v, x3) - fmaxf(b1, x1), 0.0f);
                        float inter = iw * ih;
                        float iou = inter / (ba + ar_ - inter + 1e-6f);
                        if (iou > iou_thr) alive = false;
                    }
                    mm = __ballot(alive);
                }
            }
            if (lane == 0) f_it = na;
        }
        __syncthreads();
        it = f_it;
    } else {
        // fallback: global-memory argmax loop
        for (; it < imtop; ++it) {
            float best = -1e30f; int bg = 0x7fffffff; int bl = -1;
            for (int p = t; p < K; p += T) {
                float sv = cscore[base + p];
                int g = cidx[base + p];
                if (sv > best || (sv == best && g < bg)) { best = sv; bg = g; bl = p; }
            }
#pragma unroll
            for (int o = 32; o > 0; o >>= 1) {
                float os = __shfl_down(best, o);
                int   og = __shfl_down(bg, o);
                int   ol = __shfl_down(bl, o);
                if (os > best || (os == best && og < bg)) { best = os; bg = og; bl = ol; }
            }
            if (lane == 0) { ws_sc[wid] = best; ws_g[wid] = bg; ws_p[wid] = bl; }
            __syncthreads();
            if (wid == 0) {
                float b2 = (lane < NW) ? ws_sc[lane] : -1e30f;
                int   g2 = (lane < NW) ? ws_g[lane] : 0x7fffffff;
                int   l2 = (lane < NW) ? ws_p[lane] : -1;
#pragma unroll
                for (int o = NW / 2; o > 0; o >>= 1) {
                    float os = __shfl_down(b2, o);
                    int   og = __shfl_down(g2, o);
                    int   ol = __shfl_down(l2, o);
                    if (os > b2 || (os == b2 && og < g2)) { b2 = os; g2 = og; l2 = ol; }
                }
                if (lane == 0) {
                    f_sc = b2;
                    if (b2 > 0.0f) {
                        int lp = l2;
                        size_t oslot = (size_t)img * imtop + it;
                        ob[oslot * 4 + 0] = cbox[(size_t)(base + lp) * 4 + 0];
                        ob[oslot * 4 + 1] = cbox[(size_t)(base + lp) * 4 + 1];
                        ob[oslot * 4 + 2] = cbox[(size_t)(base + lp) * 4 + 2];
                        ob[oslot * 4 + 3] = cbox[(size_t)(base + lp) * 4 + 3];
                        osc[oslot] = b2;
                        ocl[oslot] = (float)(g2 % DCLS + 1);
                        f_o0 = cbo[(size_t)(base + lp) * 4 + 0];
                        f_o1 = cbo[(size_t)(base + lp) * 4 + 1];
                        f_o2 = cbo[(size_t)(base + lp) * 4 + 2];
                        f_o3 = cbo[(size_t)(base + lp) * 4 + 3];
                        f_ar = carea[base + lp];
                        cscore[base + lp] = -1.0f;
                    }
                }
            }
            __syncthreads();
            if (f_sc <= 0.0f) break;

            float b0 = f_o0, b1 = f_o1, b2_ = f_o2, b3 = f_o3, ai = f_ar;
            for (int p = t; p < K; p += T) {
                float c0 = cbo[(size_t)(base + p) * 4 + 0];
                float c1 = cbo[(size_t)(base + p) * 4 + 1];
                float c2 = cbo[(size_t)(base + p) * 4 + 2];
                float c3 = cbo[(size_t)(base + p) * 4 + 3];
                float iw = fmaxf(fminf(b2_, c2) - fmaxf(b0, c0), 0.0f);
                float ih = fmaxf(fminf(b3, c3) - fmaxf(b1, c1), 0.0f);
                float inter = iw * ih;
                float iou = inter / (ai + carea[base + p] - inter + 1e-6f);
                if (iou > iou_thr) cscore[base + p] = -1.0f;
            }
            __syncthreads();
        }
    }

    for (int q = it + t; q < imtop; q += T) {
        size_t oslot = (size_t)img * imtop + q;
        ob[oslot * 4 + 0] = 0.0f;
        ob[oslot * 4 + 1] = 0.0f;
        ob[oslot * 4 + 2] = 0.0f;
        ob[oslot * 4 + 3] = 0.0f;
        osc[oslot] = 0.0f;
        ocl[oslot] = -1.0f;
    }
}

// ---------------------------------------------------------------------------
// Legacy full NMS (compaction + decode + pick) — fallback path only.
// ---------------------------------------------------------------------------
__global__ __launch_bounds__(NMS_T) void nms_k(
    const float* __restrict__ scr,
    const float* __restrict__ prop,
    const int* __restrict__ imidx,
    const float* __restrict__ head, int ldh, int regofs,
    const float* __restrict__ br,
    const float* __restrict__ imsz,
    const float* __restrict__ score_thr_p,
    const float* __restrict__ min_size_p,
    const float* __restrict__ iou_thr_p,
    int* __restrict__ cidx,
    float* __restrict__ cscore,
    float* __restrict__ cbo,
    float* __restrict__ cbox,
    float* __restrict__ carea,
    float* __restrict__ out,
    int M, int n, int imtop)
{
    int img = blockIdx.x;
    int t = threadIdx.x;
    const int T = NMS_T;
    const int NW = NMS_T / 64;
    int lane = t & 63, wid = t >> 6;

    __shared__ int cnt;
    __shared__ float ws_sc[NW];
    __shared__ int ws_g[NW], ws_p[NW];
    __shared__ float f_sc, f_o0, f_o1, f_o2, f_o3, f_ar;

    if (t == 0) cnt = 0;
    __syncthreads();

    float score_thr = score_thr_p[0];
    float min_size  = min_size_p[0];
    float iou_thr   = iou_thr_p[0];
    float immax = imsz[0];
    for (int q = 1; q < 2 * n; ++q) immax = fmaxf(immax, imsz[q]);

    int base = img * M;
    for (int j = t; j < M; j += T) {
        int r = j / DCLS;
        if (imidx[r] != img) continue;
        float s = scr[j];
        if (s <= score_thr) continue;

        int cls = j - r * DCLS + 1;
        const float* pr = prop + (size_t)r * 4;
        float pw = pr[2] - pr[0], ph = pr[3] - pr[1];
        float cx = (pr[0] + pr[2]) * 0.5f, cy = (pr[1] + pr[3]) * 0.5f;
        const float* rg_ = head + (size_t)r * ldh + regofs + cls * 4;
        const float* bb = br + cls * 4;
        float dx = (rg_[0] + bb[0]) * 0.1f;
        float dy = (rg_[1] + bb[1]) * 0.1f;
        float dw = fminf((rg_[2] + bb[2]) * 0.2f, FLOG_MAX);
        float dh = fminf((rg_[3] + bb[3]) * 0.2f, FLOG_MAX);
        float ncx = dx * pw + cx;
        float ncy = dy * ph + cy;
        float nw = expf(dw) * pw;
        float nh = expf(dh) * ph;
        float hbound = imsz[img * 2 + 0];
        float wbound = imsz[img * 2 + 1];
        float bx1 = fminf(fmaxf(ncx - nw * 0.5f, 0.0f), wbound);
        float bx2 = fminf(fmaxf(ncx + nw * 0.5f, 0.0f), wbound);
        float by1 = fminf(fmaxf(ncy - nh * 0.5f, 0.0f), hbound);
        float by2 = fminf(fmaxf(ncy + nh * 0.5f, 0.0f), hbound);
        if (bx2 - bx1 < min_size || by2 - by1 < min_size) continue;

        float off = (float)cls * (immax + 2.0f);
        int p = atomicAdd(&cnt, 1);
        cidx[base + p] = j;
        cscore[base + p] = s;
        cbox[(size_t)(base + p) * 4 + 0] = bx1;
        cbox[(size_t)(base + p) * 4 + 1] = by1;
        cbox[(size_t)(base + p) * 4 + 2] = bx2;
        cbox[(size_t)(base + p) * 4 + 3] = by2;
        cbo[(size_t)(base + p) * 4 + 0] = bx1 + off;
        cbo[(size_t)(base + p) * 4 + 1] = by1 + off;
        cbo[(size_t)(base + p) * 4 + 2] = bx2 + off;
        cbo[(size_t)(base + p) * 4 + 3] = by2 + off;
        carea[base + p] = (bx2 - bx1) * (by2 - by1);
    }
    __syncthreads();
    int K = cnt;

    float* ob  = out;
    float* osc = out + (size_t)n * imtop * 4;
    float* ocl = out + (size_t)n * imtop * 5;

    int it = 0;
    for (; it < imtop; ++it) {
        float best = -1e30f; int bg = 0x7fffffff; int bl = -1;
        for (int p = t; p < K; p += T) {
            float sv = cscore[base + p];
            int g = cidx[base + p];
            if (sv > best || (sv == best && g < bg)) { best = sv; bg = g; bl = p; }
        }
#pragma unroll
        for (int o = 32; o > 0; o >>= 1) {
            float os = __shfl_down(best, o);
            int   og = __shfl_down(bg, o);
            int   ol = __shfl_down(bl, o);
            if (os > best || (os == best && og < bg)) { best = os; bg = og; bl = ol; }
        }
        if (lane == 0) { ws_sc[wid] = best; ws_g[wid] = bg; ws_p[wid] = bl; }
        __syncthreads();
        if (wid == 0) {
            float b2 = (lane < NW) ? ws_sc[lane] : -1e30f;
            int   g2 = (lane < NW) ? ws_g[lane] : 0x7fffffff;
            int   l2 = (lane < NW) ? ws_p[lane] : -1;
#pragma unroll
            for (int o = NW / 2; o > 0; o >>= 1) {
                float os = __shfl_down(b2, o);
                int   og = __shfl_down(g2, o);
                int   ol = __shfl_down(l2, o);
                if (os > b2 || (os == b2 && og < g2)) { b2 = os; g2 = og; l2 = ol; }
            }
            if (lane == 0) {
                f_sc = b2;
                if (b2 > 0.0f) {
                    int lp = l2;
                    size_t oslot = (size_t)img * imtop + it;
                    ob[oslot * 4 + 0] = cbox[(size_t)(base + lp) * 4 + 0];
                    ob[oslot * 4 + 1] = cbox[(size_t)(base + lp) * 4 + 1];
                    ob[oslot * 4 + 2] = cbox[(size_t)(base + lp) * 4 + 2];
                    ob[oslot * 4 + 3] = cbox[(size_t)(base + lp) * 4 + 3];
                    osc[oslot] = b2;
                    ocl[oslot] = (float)(g2 % DCLS + 1);
                    f_o0 = cbo[(size_t)(base + lp) * 4 + 0];
                    f_o1 = cbo[(size_t)(base + lp) * 4 + 1];
                    f_o2 = cbo[(size_t)(base + lp) * 4 + 2];
                    f_o3 = cbo[(size_t)(base + lp) * 4 + 3];
                    f_ar = carea[base + lp];
                    cscore[base + lp] = -1.0f;
                }
            }
        }
        __syncthreads();
        if (f_sc <= 0.0f) break;

        float b0 = f_o0, b1 = f_o1, b2_ = f_o2, b3 = f_o3, ai = f_ar;
        for (int p = t; p < K; p += T) {
            float c0 = cbo[(size_t)(base + p) * 4 + 0];
            float c1 = cbo[(size_t)(base + p) * 4 + 1];
            float c2 = cbo[(size_t)(base + p) * 4 + 2];
            float c3 = cbo[(size_t)(base + p) * 4 + 3];
            float iw = fmaxf(fminf(b2_, c2) - fmaxf(b0, c0), 0.0f);
            float ih = fmaxf(fminf(b3, c3) - fmaxf(b1, c1), 0.0f);
            float inter = iw * ih;
            float iou = inter / (ai + carea[base + p] - inter + 1e-6f);
            if (iou > iou_thr) cscore[base + p] = -1.0f;
        }
        __syncthreads();
    }

    for (int q = it + t; q < imtop; q += T) {
        size_t oslot = (size_t)img * imtop + q;
        ob[oslot * 4 + 0] = 0.0f;
        ob[oslot * 4 + 1] = 0.0f;
        ob[oslot * 4 + 2] = 0.0f;
        ob[oslot * 4 + 3] = 0.0f;
        osc[oslot] = 0.0f;
        ocl[oslot] = -1.0f;
    }
}

// ---------------------------------------------------------------------------
extern "C" void kernel_launch(void* const* d_in, const int* in_sizes, int n_in,
                              void* d_out, int out_size, void* d_ws, size_t ws_size,
                              hipStream_t stream)
{
    const float* prop   = (const float*)d_in[0];
    const int*   imidx  = (const int*)d_in[1];
    const float* f0     = (const float*)d_in[2];
    const float* f1     = (const float*)d_in[3];
    const float* f2     = (const float*)d_in[4];
    const float* f3     = (const float*)d_in[5];
    const float* W0     = (const float*)d_in[6];
    const float* b0     = (const float*)d_in[7];
    const float* W1     = (const float*)d_in[8];
    const float* b1     = (const float*)d_in[9];
    const float* Wc     = (const float*)d_in[10];
    const float* bc     = (const float*)d_in[11];
    const float* Wr     = (const float*)d_in[12];
    const float* br     = (const float*)d_in[13];
    const float* imsz   = (const float*)d_in[14];
    const float* sthr   = (const float*)d_in[15];
    const float* ithr   = (const float*)d_in[16];
    const float* msz    = (const float*)d_in[18];

    int R = in_sizes[1];              // 1024
    int n = in_sizes[14] / 2;         // 2
    int imtop = out_size / (n * 6);   // 100
    int M = R * DCLS;                 // 81920
    int K0 = NPOOL * NPOOL * CCH;     // 12544
    int CL = in_sizes[7];             // 1024

    int h0 = (int)(sqrtf((float)(in_sizes[2] / (n * CCH))) + 0.5f);
    int h1 = (int)(sqrtf((float)(in_sizes[3] / (n * CCH))) + 0.5f);
    int h2 = (int)(sqrtf((float)(in_sizes[4] / (n * CCH))) + 0.5f);
    int h3 = (int)(sqrtf((float)(in_sizes[5] / (n * CCH))) + 0.5f);

    float* outf = (float*)d_out;

    // ---- MFMA-path workspace layout (bytes) ----
    size_t szPool  = (size_t)R * K0 * 2;
    size_t szX     = (size_t)R * CL * 4;
    size_t szHead  = (size_t)R * NHEAD * 4;
    size_t szWh    = (size_t)NHEAD * CL * 2;
    size_t szXh    = (size_t)R * CL * 2;
    size_t szW1t   = (size_t)CL * CL * 2;
    size_t szScr   = (size_t)R * DCLS * 4;

    size_t needed = 4 * szPool + 2 * szX + szHead + 2 * szWh
                  + 4 * szXh + 2 * szW1t + szScr;

    int splitK0 = 8;                  // Kc = K0/8 = 1568 = 49*32
    bool mfma_ok = (ws_size >= needed) && (R % 128 == 0) && (CL % 128 == 0)
                 && (K0 % (splitK0 * 32) == 0) && (CL % 32 == 0)
                 && ((R * 49) % 4 == 0) && (K0 % 64 == 0) && (CL % 64 == 0)
                 && (R % 4 == 0);

    if (mfma_ok) {
        uint8_t* w = (uint8_t*)d_ws;
        size_t o = 0;
        _Float16* poolH   = (_Float16*)(w + o); o += szPool;
        _Float16* poolL   = (_Float16*)(w + o); o += szPool;
        _Float16* W0tH    = (_Float16*)(w + o); o += szPool;
        _Float16* W0tL    = (_Float16*)(w + o); o += szPool;
        float*    x0acc   = (float*)(w + o);    o += szX;
        float*    unused  = (float*)(w + o);    o += szX;   // (kept for layout stability)
        float*    headacc = (float*)(w + o);    o += szHead;
        _Float16* WheadtH = (_Float16*)(w + o); o += szWh;
        _Float16* WheadtL = (_Float16*)(w + o); o += szWh;
        _Float16* x0H     = (_Float16*)(w + o); o += szXh;
        _Float16* x0L     = (_Float16*)(w + o); o += szXh;
        _Float16* x1H     = (_Float16*)(w + o); o += szXh;
        _Float16* x1L     = (_Float16*)(w + o); o += szXh;
        _Float16* W1tH    = (_Float16*)(w + o); o += szW1t;
        _Float16* W1tL    = (_Float16*)(w + o); o += szW1t;
        float*    scr     = (float*)(w + o);    // region reused for NMS counters
        (void)unused;

        int* cnt = (int*)scr;

        // NMS compaction arrays alias the pool region (dead after FC0)
        int*   cidx   = (int*)d_ws;
        float* cscore = (float*)(cidx + (size_t)n * M);
        float* cbo    = cscore + (size_t)n * M;
        float* cbox   = cbo + (size_t)n * M * 4;
        float* carea  = cbox + (size_t)n * M * 4;

        // 1. fused pre-stage: roi + weight converts + x0acc zero + cnt zero
        {
            int NB_ROI = (R * 49) / 4;
            int NB_CW0 = (K0 / 64) * (CL / 64);
            int NB_CW1 = (CL / 64) * (CL / 64);
            int NB_CWc = (CL / 64) * ((NCLS + 63) / 64);
            int NB_CWr = (CL / 64) * ((NCLS * 4 + 63) / 64);
            int zc4    = (int)(szX / 16);
            int NB_Z   = (zc4 + 255) / 256;
            int NB = NB_ROI + NB_CW0 + NB_CW1 + NB_CWc + NB_CWr + NB_Z;
            pre_uber_k<<<dim3(NB), dim3(256), 0, stream>>>(
                prop, imidx, f0, f1, f2, f3, h0, h1, h2, h3,
                poolH, poolL,
                W0, W0tH, W0tL,
                W1, W1tH, W1tL,
                Wc, Wr, WheadtH, WheadtL,
                (float4*)x0acc, zc4,
                cnt, n,
                R, K0, CL);
        }
        // 2. FC0: x0acc = pooled @ W0  (split-K 8, 128x64 tiles, 1024 blocks)
        gemm_mfma_split_k<<<dim3(splitK0 * (R / 128) * (CL / 64)), dim3(256), 0, stream>>>(
            poolH, poolL, W0tH, W0tL, x0acc, R, CL, K0, K0 / splitK0, splitK0);
        // 3. x0 = relu(x0acc + b0) -> hi/lo
        act_split_k<<<dim3((R * CL / 4 + 255) / 256), dim3(256), 0, stream>>>(
            x0acc, b0, x0H, x0L, R * CL, CL);
        // 4. FC1 fused: x1 = relu(x0 @ W1 + b1) -> hi/lo directly (no atomics)
        gemm_mfma_fused64_k<<<dim3(CL / 64, R / 64), dim3(256), 0, stream>>>(
            x0H, x0L, W1tH, W1tL, b1, nullptr, x1H, x1L, R, CL, CL, 1);
        // 5. combined heads fused: headacc = x1 @ [Wc|Wr] raw fp32 (N=512)
        gemm_mfma_fused64_k<<<dim3(NHEAD / 64, R / 64), dim3(256), 0, stream>>>(
            x1H, x1L, WheadtH, WheadtL, nullptr, headacc, nullptr, nullptr, R, NHEAD, CL, 0);
        // 6. fused softmax + decode + compaction (one wave per roi)
        compact_k<<<dim3(R / 4), dim3(256), 0, stream>>>(
            headacc, NHEAD, NCLS, bc, br, prop, imidx, imsz, sthr, msz,
            cnt, cidx, cscore, cbo, cbox, carea, M, n, R);
        // 7. NMS pick (sort + scan)
        nms_pick_k<<<dim3(n), dim3(NMS_T), 0, stream>>>(
            ithr, cnt, cidx, cscore, cbo, cbox, carea, outf, M, n, imtop);
    } else {
        // -------- fallback: all-fp32 pipeline --------
        float* ws = (float*)d_ws;
        size_t off = 0;
        float* pooled  = ws + off; off += (size_t)R * K0;
        float* x0acc   = ws + off; off += (size_t)R * CL;
        float* x1acc   = ws + off; off += (size_t)R * CL;
        float* logits  = ws + off; off += (size_t)R * NCLS;
        off = (off + 3) & ~(size_t)3;
        float* reg     = ws + off; off += (size_t)R * NCLS * 4;
        float* scr     = ws + off; off += (size_t)R * DCLS;

        int*   cidx   = (int*)ws;
        float* cscore = (float*)(cidx + (size_t)n * M);
        float* cbo    = cscore + (size_t)n * M;
        float* cbox   = cbo + (size_t)n * M * 4;
        float* carea  = cbox + (size_t)n * M * 4;

        {
            size_t zcount = (size_t)(reg + (size_t)R * NCLS * 4 - x0acc);
            int c4 = (int)(zcount / 4);
            zero_k<<<dim3((c4 + 255) / 256), dim3(256), 0, stream>>>((float4*)x0acc, c4);
        }
        roi_align_k<<<dim3(R * 49), dim3(256), 0, stream>>>(
            prop, imidx, f0, f1, f2, f3, h0, h1, h2, h3, pooled);
        gemm_splitk_k<<<dim3(CL / 64, R / 64, 8), dim3(256), 0, stream>>>(
            pooled, W0, nullptr, x0acc, R, CL, K0, 1568);
        gemm_splitk_k<<<dim3(CL / 64, R / 64, 4), dim3(256), 0, stream>>>(
            x0acc, W1, b0, x1acc, R, CL, CL, 256);
        gemm_splitk_k<<<dim3((NCLS + 63) / 64, R / 64, 8), dim3(256), 0, stream>>>(
            x1acc, Wc, b1, logits, R, NCLS, CL, 128);
        gemm_splitk_k<<<dim3((NCLS * 4 + 63) / 64, R / 64, 4), dim3(256), 0, stream>>>(
            x1acc, Wr, b1, reg, R, NCLS * 4, CL, 256);
        softmax_k<<<dim3(R), dim3(64), 0, stream>>>(logits, NCLS, bc, scr);
        nms_k<<<dim3(n), dim3(NMS_T), 0, stream>>>(
            scr, prop, imidx, reg, NCLS * 4, 0, br, imsz, sthr, msz, ithr,
            cidx, cscore, cbo, cbox, carea, outf, M, n, imtop);
    }
}

// Round 6
// 378.114 us; speedup vs baseline: 1.1886x; 1.0187x over previous
//
#include <hip/hip_runtime.h>
#include <math.h>

#define CCH 256
#define NPOOL 7
#define NCLS 81
#define DCLS 80
#define NHEAD 512            /* padded head width: 81 logits + 324 reg + pad */
#define FLOG_MAX 4.1351666f  /* log(1000/16) */

typedef _Float16 half8 __attribute__((ext_vector_type(8)));
typedef _Float16 half4 __attribute__((ext_vector_type(4)));
typedef float floatx4 __attribute__((ext_vector_type(4)));

// ---------------------------------------------------------------------------
// zero a region (float4 stores)  (fallback path only)
// ---------------------------------------------------------------------------
__global__ void zero_k(float4* __restrict__ p, int count4)
{
    int i = blockIdx.x * blockDim.x + threadIdx.x;
    if (i < count4) p[i] = make_float4(0.f, 0.f, 0.f, 0.f);
}

// ---------------------------------------------------------------------------
// RoI-align box math (per-cell scalar part)
// ---------------------------------------------------------------------------
__device__ __forceinline__ void roi_setup(
    const float* __restrict__ prop, const int* __restrict__ imidx,
    const float* __restrict__ f0, const float* __restrict__ f1,
    const float* __restrict__ f2, const float* __restrict__ f3,
    int h0, int h1, int h2, int h3, int b,
    const float*& base, int& W, size_t& o00, size_t& o01, size_t& o10, size_t& o11,
    float& w00, float& w01, float& w10, float& w11)
{
    int roi = b / 49, p = b % 49;
    int py = p / 7, px = p % 7;

    const float* pr = prop + (size_t)roi * 4;
    float x1 = pr[0], y1 = pr[1], x2 = pr[2], y2 = pr[3];
    float pw = x2 - x1, ph = y2 - y1;

    float lv = floorf(4.0f + log2f(sqrtf(pw * ph) / 224.0f + 1e-6f));
    lv = fminf(fmaxf(lv, 2.0f), 5.0f);
    int lvl = (int)lv - 2;

    const float* fm; int H; float s;
    if (lvl == 0)      { fm = f0; H = h0; s = 0.25f;    }
    else if (lvl == 1) { fm = f1; H = h1; s = 0.125f;   }
    else if (lvl == 2) { fm = f2; H = h2; s = 0.0625f;  }
    else               { fm = f3; H = h3; s = 0.03125f; }
    W = H;

    float xs1 = x1 * s, ys1 = y1 * s, xs2 = x2 * s, ys2 = y2 * s;
    float gx = (px + 0.5f) / 7.0f, gy = (py + 0.5f) / 7.0f;
    float xx = xs1 + gx * (xs2 - xs1) - 0.5f;
    float yy = ys1 + gy * (ys2 - ys1) - 0.5f;
    float x0f = floorf(xx), y0f = floorf(yy);
    float wx = xx - x0f, wy = yy - y0f;
    int x0i = min(max((int)x0f, 0), W - 1);
    int x1i = min(max((int)x0f + 1, 0), W - 1);
    int y0i = min(max((int)y0f, 0), H - 1);
    int y1i = min(max((int)y0f + 1, 0), H - 1);

    int ii = imidx[roi];
    base = fm + (size_t)ii * H * W * CCH;
    o00 = ((size_t)y0i * W + x0i) * CCH;
    o01 = ((size_t)y0i * W + x1i) * CCH;
    o10 = ((size_t)y1i * W + x0i) * CCH;
    o11 = ((size_t)y1i * W + x1i) * CCH;
    w00 = (1.0f - wx) * (1.0f - wy);
    w01 = wx * (1.0f - wy);
    w10 = (1.0f - wx) * wy;
    w11 = wx * wy;
}

// fp32 fallback variant: grid R*49 x 256 threads
__global__ void roi_align_k(const float* __restrict__ prop,
                            const int* __restrict__ imidx,
                            const float* __restrict__ f0,
                            const float* __restrict__ f1,
                            const float* __restrict__ f2,
                            const float* __restrict__ f3,
                            int h0, int h1, int h2, int h3,
                            float* __restrict__ pooled)
{
    int b = blockIdx.x, c = threadIdx.x;
    const float* base; int W; size_t o00, o01, o10, o11;
    float w00, w01, w10, w11;
    roi_setup(prop, imidx, f0, f1, f2, f3, h0, h1, h2, h3, b,
              base, W, o00, o01, o10, o11, w00, w01, w10, w11);
    float v = base[o00 + c] * w00 + base[o01 + c] * w01
            + base[o10 + c] * w10 + base[o11 + c] * w11;
    pooled[(size_t)b * CCH + c] = v;
}

// ---------------------------------------------------------------------------
// Device bodies shared by the fused kernels.
// ---------------------------------------------------------------------------
__device__ __forceinline__ void roi_f16v4_body(
    const float* __restrict__ prop, const int* __restrict__ imidx,
    const float* __restrict__ f0, const float* __restrict__ f1,
    const float* __restrict__ f2, const float* __restrict__ f3,
    int h0, int h1, int h2, int h3, int bb, int t,
    _Float16* __restrict__ poolH, _Float16* __restrict__ poolL)
{
    int b = bb * 4 + (t >> 6);
    int lane = t & 63;
    const float* base; int W; size_t o00, o01, o10, o11;
    float w00, w01, w10, w11;
    roi_setup(prop, imidx, f0, f1, f2, f3, h0, h1, h2, h3, b,
              base, W, o00, o01, o10, o11, w00, w01, w10, w11);

    int c4 = lane * 4;
    float4 v00 = *(const float4*)(base + o00 + c4);
    float4 v01 = *(const float4*)(base + o01 + c4);
    float4 v10 = *(const float4*)(base + o10 + c4);
    float4 v11 = *(const float4*)(base + o11 + c4);
    const float* p00 = (const float*)&v00;
    const float* p01 = (const float*)&v01;
    const float* p10 = (const float*)&v10;
    const float* p11 = (const float*)&v11;

    half4 h, l;
#pragma unroll
    for (int e = 0; e < 4; ++e) {
        float v = p00[e] * w00 + p01[e] * w01 + p10[e] * w10 + p11[e] * w11;
        _Float16 hh = (_Float16)v;
        h[e] = hh;
        l[e] = (_Float16)(v - (float)hh);
    }
    size_t idx = (size_t)b * CCH + c4;
    *(half4*)(poolH + idx) = h;
    *(half4*)(poolL + idx) = l;
}

__device__ __forceinline__ void conv_fast_body(
    const float* __restrict__ W, _Float16* __restrict__ WtH,
    _Float16* __restrict__ WtL, int K, int N, int k0, int n0, int t,
    float (*sh)[65])
{
#pragma unroll
    for (int p = 0; p < 4; ++p) {
        int idx = p * 256 + t;
        int kr = idx >> 4, nc = (idx & 15) * 4;
        float4 v = *(const float4*)(W + (size_t)(k0 + kr) * N + n0 + nc);
        sh[kr][nc + 0] = v.x; sh[kr][nc + 1] = v.y;
        sh[kr][nc + 2] = v.z; sh[kr][nc + 3] = v.w;
    }
    __syncthreads();
#pragma unroll
    for (int p = 0; p < 4; ++p) {
        int idx = p * 256 + t;
        int nr = idx >> 4, kc = (idx & 15) * 4;
        half4 h, l;
#pragma unroll
        for (int i = 0; i < 4; ++i) {
            float v = sh[kc + i][nr];
            _Float16 hh = (_Float16)v;
            h[i] = hh;
            l[i] = (_Float16)(v - (float)hh);
        }
        *(half4*)(WtH + (size_t)(n0 + nr) * K + k0 + kc) = h;
        *(half4*)(WtL + (size_t)(n0 + nr) * K + k0 + kc) = l;
    }
}

__device__ __forceinline__ void conv_guard_body(
    const float* __restrict__ W, _Float16* __restrict__ WtH,
    _Float16* __restrict__ WtL, int K, int N, int Kt, int rowofs,
    int k0, int n0, int t, float (*sh)[65])
{
#pragma unroll
    for (int p = 0; p < 4; ++p) {
        int idx = p * 256 + t;
        int kr = idx >> 4, nc = (idx & 15) * 4;
#pragma unroll
        for (int e = 0; e < 4; ++e) {
            int nn = n0 + nc + e;
            sh[kr][nc + e] = (nn < N) ? W[(size_t)(k0 + kr) * N + nn] : 0.0f;
        }
    }
    __syncthreads();
#pragma unroll
    for (int p = 0; p < 4; ++p) {
        int idx = p * 256 + t;
        int nr = idx >> 4, kc = (idx & 15) * 4;
        if (n0 + nr < N) {
            half4 h, l;
#pragma unroll
            for (int i = 0; i < 4; ++i) {
                float v = sh[kc + i][nr];
                _Float16 hh = (_Float16)v;
                h[i] = hh;
                l[i] = (_Float16)(v - (float)hh);
            }
            *(half4*)(WtH + (size_t)(rowofs + n0 + nr) * Kt + k0 + kc) = h;
            *(half4*)(WtL + (size_t)(rowofs + n0 + nr) * Kt + k0 + kc) = l;
        }
    }
}

// ---------------------------------------------------------------------------
// Fused pre-FC0 stage: RoI + W0 convert + accumulator zero + cnt zero.
// (W1/Wc/Wr converts moved into the FC0 launch — they're independent of
// FC0's inputs and only consumed by FC1/heads, so they tail-fill FC0's CUs.)
// ---------------------------------------------------------------------------
__global__ __launch_bounds__(256) void pre_uber_k(
    const float* __restrict__ prop, const int* __restrict__ imidx,
    const float* __restrict__ f0, const float* __restrict__ f1,
    const float* __restrict__ f2, const float* __restrict__ f3,
    int h0, int h1, int h2, int h3,
    _Float16* __restrict__ poolH, _Float16* __restrict__ poolL,
    const float* __restrict__ W0, _Float16* __restrict__ W0tH, _Float16* __restrict__ W0tL,
    float4* __restrict__ zp, int zc4,
    int* __restrict__ cntp, int ncnt,
    int R, int K0, int CL)
{
    __shared__ float sh[64][65];
    int b = blockIdx.x, t = threadIdx.x;

    if (blockIdx.x == 0 && t < ncnt) cntp[t] = 0;

    int NB_ROI = (R * 49) / 4;
    int KT0 = K0 / 64, NT0 = CL / 64;
    int NB_CW0 = KT0 * NT0;

    if (b < NB_ROI) {
        roi_f16v4_body(prop, imidx, f0, f1, f2, f3, h0, h1, h2, h3, b, t,
                       poolH, poolL);
        return;
    }
    b -= NB_ROI;
    if (b < NB_CW0) {
        int k0 = (b % KT0) * 64, n0 = (b / KT0) * 64;
        conv_fast_body(W0, W0tH, W0tL, K0, CL, k0, n0, t, sh);
        return;
    }
    b -= NB_CW0;
    {
        int i = b * 256 + t;
        if (i < zc4) zp[i] = make_float4(0.f, 0.f, 0.f, 0.f);
    }
}

// ---------------------------------------------------------------------------
// act-split: out = relu(acc + bias) -> f16 hi/lo. 4 elems/thread.
// ---------------------------------------------------------------------------
__global__ void act_split_k(const float* __restrict__ acc,
                            const float* __restrict__ bias,
                            _Float16* __restrict__ outH,
                            _Float16* __restrict__ outL,
                            int total, int CL)
{
    int i = (blockIdx.x * blockDim.x + threadIdx.x) * 4;
    if (i >= total) return;
    int b = i % CL;
    float4 v = *(const float4*)(acc + i);
    float4 bb = *(const float4*)(bias + b);
    const float* pv = (const float*)&v;
    const float* pb = (const float*)&bb;
    half4 h, l;
#pragma unroll
    for (int e = 0; e < 4; ++e) {
        float f = fmaxf(pv[e] + pb[e], 0.0f);
        _Float16 hh = (_Float16)f;
        h[e] = hh;
        l[e] = (_Float16)(f - (float)hh);
    }
    *(half4*)(outH + i) = h;
    *(half4*)(outL + i) = l;
}

// ---------------------------------------------------------------------------
// global->LDS DMA, width 16 (wave-uniform LDS base + lane*16)
// ---------------------------------------------------------------------------
__device__ __forceinline__ void dma16(const _Float16* g, _Float16* l)
{
    __builtin_amdgcn_global_load_lds(
        (const __attribute__((address_space(1))) unsigned int*)g,
        (__attribute__((address_space(3))) unsigned int*)l, 16, 0, 0);
}

// ---------------------------------------------------------------------------
// LDS granule swizzle (verified round 3: SQ_LDS_BANK_CONFLICT 6.4M -> 0)
// ---------------------------------------------------------------------------
#define LDKE 32   /* halves per LDS row (64 B), unpadded for DMA */
#define DKQ_SWZ(lane)  ((((lane) & 3) ^ (((lane) >> 3) & 3)) << 3)
#define FK_SWZ(lane)   (((((lane) >> 4) ^ (((lane) >> 1) & 3))) << 3)

// ---------------------------------------------------------------------------
// FC0 GEMM + trailing weight-convert blocks (block-range fusion).
// GEMM: split-f16 MFMA, 128x128 tile (verified 103.5 us round 3/4), DMA
// staging, XCD-pinned (first nbg blocks, z = bid%SP). Convert blocks
// (bid >= nbg) transpose W1/Wc/Wr while GEMM blocks drain — they have no
// dependence on GEMM inputs and are consumed only by later kernels.
// LDS: 32 KB union (GEMM 4x8KB arrays | convert float[64][65]).
// ---------------------------------------------------------------------------
__global__ __launch_bounds__(256) void gemm_fc0_conv_k(
    const _Float16* __restrict__ Ah, const _Float16* __restrict__ Al,
    const _Float16* __restrict__ Bh, const _Float16* __restrict__ Bl,
    float* __restrict__ Cacc, int M, int N, int K, int Kc, int SP, int nbg,
    const float* __restrict__ W1, _Float16* __restrict__ W1tH, _Float16* __restrict__ W1tL,
    const float* __restrict__ Wc, const float* __restrict__ Wr,
    _Float16* __restrict__ WheadtH, _Float16* __restrict__ WheadtL, int CL)
{
    __shared__ __align__(16) char smem[4 * 128 * LDKE * 2];   // 32 KB

    int t = threadIdx.x;

    if (blockIdx.x >= nbg) {
        // ---------------- convert blocks ----------------
        float (*sh)[65] = (float(*)[65])smem;
        int b = blockIdx.x - nbg;
        int KT1 = CL / 64;
        int NB_CW1 = KT1 * KT1;
        int NB_CWc = KT1 * ((NCLS + 63) / 64);
        if (b < NB_CW1) {
            int k0 = (b % KT1) * 64, n0 = (b / KT1) * 64;
            conv_fast_body(W1, W1tH, W1tL, CL, CL, k0, n0, t, sh);
            return;
        }
        b -= NB_CW1;
        if (b < NB_CWc) {
            int k0 = (b % KT1) * 64, n0 = (b / KT1) * 64;
            conv_guard_body(Wc, WheadtH, WheadtL, CL, NCLS, CL, 0, k0, n0, t, sh);
            return;
        }
        b -= NB_CWc;
        {
            int k0 = (b % KT1) * 64, n0 = (b / KT1) * 64;
            conv_guard_body(Wr, WheadtH, WheadtL, CL, NCLS * 4, CL, NCLS, k0, n0, t, sh);
            return;
        }
    }

    // ---------------- GEMM blocks (verified round-3 body) ----------------
    _Float16* sAh = (_Float16*)smem;
    _Float16* sAl = sAh + 128 * LDKE;
    _Float16* sBh = sAl + 128 * LDKE;
    _Float16* sBl = sBh + 128 * LDKE;

    int bid = blockIdx.x;
    int z = bid % SP;
    int q = bid / SP;
    int NT = N >> 7;
    int nn = q % NT;
    int m = q / NT;
    int m0 = m * 128, n0 = nn * 128;
    int kb = z * Kc;
    int ke = min(K, kb + Kc);

    int lane = t & 63, w = t >> 6;
    int wr = w >> 1, wc = w & 1;          // 2x2 wave grid over 128x128
    int fr = lane & 15;                   // fragment row/col within 16
    int fk = FK_SWZ(lane);                // swizzled fragment granule offset

    int drow = w * 32 + (lane >> 2);
    int dkq = DKQ_SWZ(lane);
    const _Float16* gAh = Ah + (size_t)(m0 + drow) * K + dkq;
    const _Float16* gAl = Al + (size_t)(m0 + drow) * K + dkq;
    const _Float16* gBh = Bh + (size_t)(n0 + drow) * K + dkq;
    const _Float16* gBl = Bl + (size_t)(n0 + drow) * K + dkq;
    size_t rowskip = (size_t)16 * K;

    _Float16* lAh0 = &sAh[(w * 2 + 0) * 512];
    _Float16* lAh1 = &sAh[(w * 2 + 1) * 512];
    _Float16* lAl0 = &sAl[(w * 2 + 0) * 512];
    _Float16* lAl1 = &sAl[(w * 2 + 1) * 512];
    _Float16* lBh0 = &sBh[(w * 2 + 0) * 512];
    _Float16* lBh1 = &sBh[(w * 2 + 1) * 512];
    _Float16* lBl0 = &sBl[(w * 2 + 0) * 512];
    _Float16* lBl1 = &sBl[(w * 2 + 1) * 512];

    floatx4 acc[4][4] = {};

    for (int k0 = kb; k0 < ke; k0 += 32) {
        dma16(gAh + k0, lAh0);
        dma16(gAh + rowskip + k0, lAh1);
        dma16(gAl + k0, lAl0);
        dma16(gAl + rowskip + k0, lAl1);
        dma16(gBh + k0, lBh0);
        dma16(gBh + rowskip + k0, lBh1);
        dma16(gBl + k0, lBl0);
        dma16(gBl + rowskip + k0, lBl1);
        __syncthreads();   // drains vmcnt -> DMA data visible

        half8 ah[4], al[4], bh[4], bl[4];
#pragma unroll
        for (int i = 0; i < 4; ++i) {
            int ar = wr * 64 + i * 16 + fr;
            ah[i] = *(const half8*)&sAh[ar * LDKE + fk];
            al[i] = *(const half8*)&sAl[ar * LDKE + fk];
            int bc = wc * 64 + i * 16 + fr;
            bh[i] = *(const half8*)&sBh[bc * LDKE + fk];
            bl[i] = *(const half8*)&sBl[bc * LDKE + fk];
        }
#pragma unroll
        for (int i = 0; i < 4; ++i)
#pragma unroll
            for (int j = 0; j < 4; ++j) {
                acc[i][j] = __builtin_amdgcn_mfma_f32_16x16x32_f16(ah[i], bh[j], acc[i][j], 0, 0, 0);
                acc[i][j] = __builtin_amdgcn_mfma_f32_16x16x32_f16(ah[i], bl[j], acc[i][j], 0, 0, 0);
                acc[i][j] = __builtin_amdgcn_mfma_f32_16x16x32_f16(al[i], bh[j], acc[i][j], 0, 0, 0);
            }
        __syncthreads();   // LDS reads complete before next DMA overwrite
    }

    // epilogue: C/D layout col=lane&15, row=(lane>>4)*4+reg
    int rbase = (lane >> 4) * 4;
#pragma unroll
    for (int i = 0; i < 4; ++i)
#pragma unroll
        for (int j = 0; j < 4; ++j) {
            int col = n0 + wc * 64 + j * 16 + fr;
#pragma unroll
            for (int r = 0; r < 4; ++r) {
                int row = m0 + wr * 64 + i * 16 + rbase + r;
                atomicAdd(&Cacc[(size_t)row * N + col], acc[i][j][r]);
            }
        }
}

// ---------------------------------------------------------------------------
// Non-split fused MFMA GEMM, 64x64 tile, double-buffered 2-phase prefetch.
// ---------------------------------------------------------------------------
__global__ __launch_bounds__(256) void gemm_mfma_fused64_k(
    const _Float16* __restrict__ Ah, const _Float16* __restrict__ Al,
    const _Float16* __restrict__ Bh, const _Float16* __restrict__ Bl,
    const float* __restrict__ bias,
    float* __restrict__ Cout,
    _Float16* __restrict__ outH, _Float16* __restrict__ outL,
    int M, int N, int K, int mode)
{
    __shared__ _Float16 sAh[2][64 * LDKE], sAl[2][64 * LDKE];
    __shared__ _Float16 sBh[2][64 * LDKE], sBl[2][64 * LDKE];

    int m0 = blockIdx.y * 64, n0 = blockIdx.x * 64;
    int t = threadIdx.x;
    int lane = t & 63, w = t >> 6;
    int wr = w >> 1, wc = w & 1;
    int fr = lane & 15;
    int fk = FK_SWZ(lane);

    int drow = w * 16 + (lane >> 2);
    int dkq = DKQ_SWZ(lane);
    const _Float16* gAh = Ah + (size_t)(m0 + drow) * K + dkq;
    const _Float16* gAl = Al + (size_t)(m0 + drow) * K + dkq;
    const _Float16* gBh = Bh + (size_t)(n0 + drow) * K + dkq;
    const _Float16* gBl = Bl + (size_t)(n0 + drow) * K + dkq;
    int lofs = w * 512;

    int nt = K >> 5;

    dma16(gAh + 0, &sAh[0][lofs]);
    dma16(gAl + 0, &sAl[0][lofs]);
    dma16(gBh + 0, &sBh[0][lofs]);
    dma16(gBl + 0, &sBl[0][lofs]);
    __syncthreads();

    floatx4 acc[2][2] = {};

    for (int tt = 0; tt < nt; ++tt) {
        int c = tt & 1, nb = c ^ 1;
        if (tt + 1 < nt) {
            int k1 = (tt + 1) << 5;
            dma16(gAh + k1, &sAh[nb][lofs]);
            dma16(gAl + k1, &sAl[nb][lofs]);
            dma16(gBh + k1, &sBh[nb][lofs]);
            dma16(gBl + k1, &sBl[nb][lofs]);
        }

        half8 ah[2], av[2], bh[2], bv[2];
#pragma unroll
        for (int i = 0; i < 2; ++i) {
            int ar = wr * 32 + i * 16 + fr;
            ah[i] = *(const half8*)&sAh[c][ar * LDKE + fk];
            av[i] = *(const half8*)&sAl[c][ar * LDKE + fk];
            int bc = wc * 32 + i * 16 + fr;
            bh[i] = *(const half8*)&sBh[c][bc * LDKE + fk];
            bv[i] = *(const half8*)&sBl[c][bc * LDKE + fk];
        }
#pragma unroll
        for (int i = 0; i < 2; ++i)
#pragma unroll
            for (int j = 0; j < 2; ++j) {
                acc[i][j] = __builtin_amdgcn_mfma_f32_16x16x32_f16(ah[i], bh[j], acc[i][j], 0, 0, 0);
                acc[i][j] = __builtin_amdgcn_mfma_f32_16x16x32_f16(ah[i], bv[j], acc[i][j], 0, 0, 0);
                acc[i][j] = __builtin_amdgcn_mfma_f32_16x16x32_f16(av[i], bh[j], acc[i][j], 0, 0, 0);
            }
        __syncthreads();
    }

    int rbase = (lane >> 4) * 4;
#pragma unroll
    for (int i = 0; i < 2; ++i)
#pragma unroll
        for (int j = 0; j < 2; ++j) {
            int col = n0 + wc * 32 + j * 16 + fr;
#pragma unroll
            for (int r = 0; r < 4; ++r) {
                int row = m0 + wr * 32 + i * 16 + rbase + r;
                float v = acc[i][j][r];
                if (mode == 0) {
                    Cout[(size_t)row * N + col] = v;
                } else {
                    float f = fmaxf(v + bias[col], 0.0f);
                    _Float16 hh = (_Float16)f;
                    outH[(size_t)row * N + col] = hh;
                    outL[(size_t)row * N + col] = (_Float16)(f - (float)hh);
                }
            }
        }
}

// ---------------------------------------------------------------------------
// fp32 split-K GEMM (fallback path only)
// ---------------------------------------------------------------------------
__global__ __launch_bounds__(256) void gemm_splitk_k(const float* __restrict__ A,
                                                     const float* __restrict__ B,
                                                     const float* __restrict__ abias,
                                                     float* __restrict__ Cacc,
                                                     int M, int N, int K, int Kc)
{
    __shared__ float Ast[16][68];
    __shared__ float Bs[16][68];

    int m0 = blockIdx.y * 64, n0 = blockIdx.x * 64;
    int kb = blockIdx.z * Kc;
    int ke = min(K, kb + Kc);
    int tid = threadIdx.x;
    int tx = tid & 15, ty = tid >> 4;
    int arow = tid >> 2, akq = (tid & 3) << 2;
    int bcol = tid & 63, bk = tid >> 6;

    const float* Arow = A + (size_t)(m0 + arow) * K;
    bool nfull = (n0 + 64 <= N);

    float acc[4][4] = {};

    for (int k0 = kb; k0 < ke; k0 += 16) {
        float4 av = *(const float4*)(Arow + k0 + akq);
        if (abias) {
            av.x = fmaxf(av.x + abias[k0 + akq + 0], 0.0f);
            av.y = fmaxf(av.y + abias[k0 + akq + 1], 0.0f);
            av.z = fmaxf(av.z + abias[k0 + akq + 2], 0.0f);
            av.w = fmaxf(av.w + abias[k0 + akq + 3], 0.0f);
        }
        float bv[4];
        if (nfull) {
#pragma unroll
            for (int e = 0; e < 4; ++e)
                bv[e] = B[(size_t)(k0 + bk * 4 + e) * N + n0 + bcol];
        } else {
            bool ok = (n0 + bcol) < N;
#pragma unroll
            for (int e = 0; e < 4; ++e)
                bv[e] = ok ? B[(size_t)(k0 + bk * 4 + e) * N + n0 + bcol] : 0.0f;
        }
        __syncthreads();
        Ast[akq + 0][arow] = av.x;
        Ast[akq + 1][arow] = av.y;
        Ast[akq + 2][arow] = av.z;
        Ast[akq + 3][arow] = av.w;
#pragma unroll
        for (int e = 0; e < 4; ++e) Bs[bk * 4 + e][bcol] = bv[e];
        __syncthreads();

#pragma unroll
        for (int kk = 0; kk < 16; ++kk) {
            float4 af = *(const float4*)&Ast[kk][ty * 4];
            float4 bf = *(const float4*)&Bs[kk][tx * 4];
            float a_[4] = {af.x, af.y, af.z, af.w};
            float b_[4] = {bf.x, bf.y, bf.z, bf.w};
#pragma unroll
            for (int i = 0; i < 4; ++i)
#pragma unroll
                for (int j = 0; j < 4; ++j)
                    acc[i][j] = fmaf(a_[i], b_[j], acc[i][j]);
        }
    }

#pragma unroll
    for (int i = 0; i < 4; ++i) {
        int row = m0 + ty * 4 + i;
#pragma unroll
        for (int j = 0; j < 4; ++j) {
            int col = n0 + tx * 4 + j;
            if (col < N) atomicAdd(&Cacc[(size_t)row * N + col], acc[i][j]);
        }
    }
}

// ---------------------------------------------------------------------------
// softmax over (logits + bc), classes 1..80. grid = R, block = 64.
// (fallback path only; MFMA path folds softmax into compact_k)
// ---------------------------------------------------------------------------
__global__ void softmax_k(const float* __restrict__ logits, int ldl,
                          const float* __restrict__ bc,
                          float* __restrict__ scr)
{
    int r = blockIdx.x;
    int t = threadIdx.x;
    const float* row = logits + (size_t)r * ldl;

    float v0 = row[t] + bc[t];
    float v1 = (t + 64 < NCLS) ? (row[t + 64] + bc[t + 64]) : -INFINITY;
    float m = fmaxf(v0, v1);
#pragma unroll
    for (int o = 32; o > 0; o >>= 1) m = fmaxf(m, __shfl_down(m, o));
    m = __shfl(m, 0);

    float e0 = expf(v0 - m);
    float e1 = (t + 64 < NCLS) ? expf(v1 - m) : 0.0f;
    float sum = e0 + e1;
#pragma unroll
    for (int o = 32; o > 0; o >>= 1) sum += __shfl_down(sum, o);
    sum = __shfl(sum, 0);
    float inv = 1.0f / sum;

    if (t >= 1)        scr[(size_t)r * DCLS + (t - 1)]  = e0 * inv;
    if (t + 64 < NCLS) scr[(size_t)r * DCLS + (t + 63)] = e1 * inv;
}

// ---------------------------------------------------------------------------
// Fused softmax + threshold + box-decode + compaction (verified round 5).
// One WAVE per roi (grid R/4 x 256 thr).
// ---------------------------------------------------------------------------
__global__ __launch_bounds__(256) void compact_k(
    const float* __restrict__ head, int ldh, int regofs,
    const float* __restrict__ bc,
    const float* __restrict__ br,
    const float* __restrict__ prop,
    const int* __restrict__ imidx,
    const float* __restrict__ imsz,
    const float* __restrict__ score_thr_p,
    const float* __restrict__ min_size_p,
    int* __restrict__ cntp,
    int* __restrict__ cidx,
    float* __restrict__ cscore,
    float* __restrict__ cbo,
    float* __restrict__ cbox,
    float* __restrict__ carea,
    int M, int n, int R)
{
    int wid = threadIdx.x >> 6, t = threadIdx.x & 63;
    int r = blockIdx.x * 4 + wid;
    if (r >= R) return;

    const float* row = head + (size_t)r * ldh;
    float v0 = row[t] + bc[t];
    float v1 = (t + 64 < NCLS) ? (row[t + 64] + bc[t + 64]) : -INFINITY;
    float m = fmaxf(v0, v1);
#pragma unroll
    for (int o = 32; o > 0; o >>= 1) m = fmaxf(m, __shfl_down(m, o));
    m = __shfl(m, 0);

    float e0 = expf(v0 - m);
    float e1 = (t + 64 < NCLS) ? expf(v1 - m) : 0.0f;
    float sum = e0 + e1;
#pragma unroll
    for (int o = 32; o > 0; o >>= 1) sum += __shfl_down(sum, o);
    sum = __shfl(sum, 0);
    float inv = 1.0f / sum;

    float score_thr = score_thr_p[0];
    float min_size  = min_size_p[0];
    float immax = imsz[0];
    for (int q = 1; q < 2 * n; ++q) immax = fmaxf(immax, imsz[q]);

    int img = imidx[r];
    int base = img * M;
    const float* pr = prop + (size_t)r * 4;
    float pw = pr[2] - pr[0], ph = pr[3] - pr[1];
    float cx = (pr[0] + pr[2]) * 0.5f, cy = (pr[1] + pr[3]) * 0.5f;
    float hbound = imsz[img * 2 + 0];
    float wbound = imsz[img * 2 + 1];

#pragma unroll
    for (int pass = 0; pass < 2; ++pass) {
        int cls; float s; bool active;
        if (pass == 0) { cls = t;      s = e0 * inv; active = (t >= 1); }
        else           { cls = t + 64; s = e1 * inv; active = (t + 64 < NCLS); }
        if (!active || s <= score_thr) continue;

        const float* rg_ = head + (size_t)r * ldh + regofs + cls * 4;
        const float* bb = br + cls * 4;
        float dx = (rg_[0] + bb[0]) * 0.1f;
        float dy = (rg_[1] + bb[1]) * 0.1f;
        float dw = fminf((rg_[2] + bb[2]) * 0.2f, FLOG_MAX);
        float dh = fminf((rg_[3] + bb[3]) * 0.2f, FLOG_MAX);
        float ncx = dx * pw + cx;
        float ncy = dy * ph + cy;
        float nw = expf(dw) * pw;
        float nh = expf(dh) * ph;
        float bx1 = fminf(fmaxf(ncx - nw * 0.5f, 0.0f), wbound);
        float bx2 = fminf(fmaxf(ncx + nw * 0.5f, 0.0f), wbound);
        float by1 = fminf(fmaxf(ncy - nh * 0.5f, 0.0f), hbound);
        float by2 = fminf(fmaxf(ncy + nh * 0.5f, 0.0f), hbound);
        if (bx2 - bx1 < min_size || by2 - by1 < min_size) continue;

        float off = (float)cls * (immax + 2.0f);
        int j = r * DCLS + cls - 1;
        int p = atomicAdd(&cntp[img], 1);
        cidx[base + p] = j;
        cscore[base + p] = s;
        cbox[(size_t)(base + p) * 4 + 0] = bx1;
        cbox[(size_t)(base + p) * 4 + 1] = by1;
        cbox[(size_t)(base + p) * 4 + 2] = bx2;
        cbox[(size_t)(base + p) * 4 + 3] = by2;
        cbo[(size_t)(base + p) * 4 + 0] = bx1 + off;
        cbo[(size_t)(base + p) * 4 + 1] = by1 + off;
        cbo[(size_t)(base + p) * 4 + 2] = bx2 + off;
        cbo[(size_t)(base + p) * 4 + 3] = by2 + off;
        carea[base + p] = (bx2 - bx1) * (by2 - by1);
    }
}

// ---------------------------------------------------------------------------
// NMS pick: sort-once + sequential-scan (verified round 3/5). grid = n,
// block = 1024. Compaction done by compact_k; K read from cntp.
// ---------------------------------------------------------------------------
#define NMS_T 1024
#define NMS_SORTMAX 4096
#define NMS_AMAX 512
__global__ __launch_bounds__(NMS_T) void nms_pick_k(
    const float* __restrict__ iou_thr_p,
    const int* __restrict__ cntp,
    int* __restrict__ cidx,
    float* __restrict__ cscore,
    float* __restrict__ cbo,
    float* __restrict__ cbox,
    float* __restrict__ carea,
    float* __restrict__ out,
    int M, int n, int imtop)
{
    int img = blockIdx.x;
    int t = threadIdx.x;
    const int T = NMS_T;
    const int NW = NMS_T / 64;
    int lane = t & 63, wid = t >> 6;

    __shared__ unsigned long long skey[NMS_SORTMAX];
    __shared__ int sp_[NMS_SORTMAX];
    __shared__ float aab0[NMS_AMAX], aab1[NMS_AMAX], aab2[NMS_AMAX], aab3[NMS_AMAX], aaa[NMS_AMAX];
    __shared__ int f_it;
    __shared__ float ws_sc[NW];
    __shared__ int ws_g[NW], ws_p[NW];
    __shared__ float f_sc, f_o0, f_o1, f_o2, f_o3, f_ar;

    float iou_thr = iou_thr_p[0];
    int K = cntp[img];
    int base = img * M;

    float* ob  = out;
    float* osc = out + (size_t)n * imtop * 4;
    float* ocl = out + (size_t)n * imtop * 5;

    int it = 0;
    if (K <= NMS_SORTMAX && imtop <= NMS_AMAX) {
        int SN = 64; while (SN < K) SN <<= 1;
        for (int i = t; i < SN; i += T) {
            if (i < K) {
                unsigned int sb = __float_as_uint(cscore[base + i]);
                skey[i] = ((unsigned long long)sb << 32)
                        | (unsigned int)(~cidx[base + i]);
            } else {
                skey[i] = 0ull;
            }
            sp_[i] = i;
        }
        for (int k = 2; k <= SN; k <<= 1) {
            for (int j = k >> 1; j > 0; j >>= 1) {
                __syncthreads();
                for (int i = t; i < SN; i += T) {
                    int l = i ^ j;
                    if (l > i) {
                        unsigned long long ki = skey[i], kl = skey[l];
                        bool up = ((i & k) == 0);
                        bool sw = up ? (ki < kl) : (ki > kl);
                        if (sw) {
                            skey[i] = kl; skey[l] = ki;
                            int tp = sp_[i]; sp_[i] = sp_[l]; sp_[l] = tp;
                        }
                    }
                }
            }
        }
        __syncthreads();

        if (wid == 0) {
            int na = 0;
            for (int c0 = 0; c0 < K && na < imtop; c0 += 64) {
                int ci = c0 + lane;
                bool alive = ci < K;
                float x0 = 0.f, x1 = 0.f, x2 = 0.f, x3 = 0.f, ar_ = 0.f, sc = 0.f;
                float q0 = 0.f, q1 = 0.f, q2 = 0.f, q3 = 0.f;
                int g = 0;
                if (alive) {
                    unsigned long long key = skey[ci];
                    sc = __uint_as_float((unsigned int)(key >> 32));
                    int pp = sp_[ci];
                    g = cidx[base + pp];
                    x0 = cbo[(size_t)(base + pp) * 4 + 0];
                    x1 = cbo[(size_t)(base + pp) * 4 + 1];
                    x2 = cbo[(size_t)(base + pp) * 4 + 2];
                    x3 = cbo[(size_t)(base + pp) * 4 + 3];
                    ar_ = carea[base + pp];
                    q0 = cbox[(size_t)(base + pp) * 4 + 0];
                    q1 = cbox[(size_t)(base + pp) * 4 + 1];
                    q2 = cbox[(size_t)(base + pp) * 4 + 2];
                    q3 = cbox[(size_t)(base + pp) * 4 + 3];
                    if (sc <= 0.0f) alive = false;
                }
                for (int a = 0; a < na; ++a) {
                    float iw = fmaxf(fminf(aab2[a], x2) - fmaxf(aab0[a], x0), 0.0f);
                    float ih = fmaxf(fminf(aab3[a], x3) - fmaxf(aab1[a], x1), 0.0f);
                    float inter = iw * ih;
                    float iou = inter / (aaa[a] + ar_ - inter + 1e-6f);
                    if (iou > iou_thr) alive = false;
                }
                unsigned long long mm = __ballot(alive);
                while (mm != 0ull && na < imtop) {
                    int s = __ffsll(mm) - 1;
                    float b0 = __shfl(x0, s), b1 = __shfl(x1, s);
                    float b2v = __shfl(x2, s), b3v = __shfl(x3, s);
                    float ba = __shfl(ar_, s);
                    if (lane == s) {
                        size_t oslot = (size_t)img * imtop + na;
                        ob[oslot * 4 + 0] = q0;
                        ob[oslot * 4 + 1] = q1;
                        ob[oslot * 4 + 2] = q2;
                        ob[oslot * 4 + 3] = q3;
                        osc[oslot] = sc;
                        ocl[oslot] = (float)(g % DCLS + 1);
                        aab0[na] = x0; aab1[na] = x1; aab2[na] = x2; aab3[na] = x3;
                        aaa[na] = ar_;
                        alive = false;
                    }
                    na++;
                    if (alive && lane > s) {
                        float iw = fmaxf(fminf(b2v, x2) - fmaxf(b0, x0), 0.0f);
                        float ih = fmaxf(fminf(b3v, x3) - fmaxf(b1, x1), 0.0f);
                        float inter = iw * ih;
                        float iou = inter / (ba + ar_ - inter + 1e-6f);
                        if (iou > iou_thr) alive = false;
                    }
                    mm = __ballot(alive);
                }
            }
            if (lane == 0) f_it = na;
        }
        __syncthreads();
        it = f_it;
    } else {
        // fallback: global-memory argmax loop
        for (; it < imtop; ++it) {
            float best = -1e30f; int bg = 0x7fffffff; int bl = -1;
            for (int p = t; p < K; p += T) {
                float sv = cscore[base + p];
                int g = cidx[base + p];
                if (sv > best || (sv == best && g < bg)) { best = sv; bg = g; bl = p; }
            }
#pragma unroll
            for (int o = 32; o > 0; o >>= 1) {
                float os = __shfl_down(best, o);
                int   og = __shfl_down(bg, o);
                int   ol = __shfl_down(bl, o);
                if (os > best || (os == best && og < bg)) { best = os; bg = og; bl = ol; }
            }
            if (lane == 0) { ws_sc[wid] = best; ws_g[wid] = bg; ws_p[wid] = bl; }
            __syncthreads();
            if (wid == 0) {
                float b2 = (lane < NW) ? ws_sc[lane] : -1e30f;
                int   g2 = (lane < NW) ? ws_g[lane] : 0x7fffffff;
                int   l2 = (lane < NW) ? ws_p[lane] : -1;
#pragma unroll
                for (int o = NW / 2; o > 0; o >>= 1) {
                    float os = __shfl_down(b2, o);
                    int   og = __shfl_down(g2, o);
                    int   ol = __shfl_down(l2, o);
                    if (os > b2 || (os == b2 && og < g2)) { b2 = os; g2 = og; l2 = ol; }
                }
                if (lane == 0) {
                    f_sc = b2;
                    if (b2 > 0.0f) {
                        int lp = l2;
                        size_t oslot = (size_t)img * imtop + it;
                        ob[oslot * 4 + 0] = cbox[(size_t)(base + lp) * 4 + 0];
                        ob[oslot * 4 + 1] = cbox[(size_t)(base + lp) * 4 + 1];
                        ob[oslot * 4 + 2] = cbox[(size_t)(base + lp) * 4 + 2];
                        ob[oslot * 4 + 3] = cbox[(size_t)(base + lp) * 4 + 3];
                        osc[oslot] = b2;
                        ocl[oslot] = (float)(g2 % DCLS + 1);
                        f_o0 = cbo[(size_t)(base + lp) * 4 + 0];
                        f_o1 = cbo[(size_t)(base + lp) * 4 + 1];
                        f_o2 = cbo[(size_t)(base + lp) * 4 + 2];
                        f_o3 = cbo[(size_t)(base + lp) * 4 + 3];
                        f_ar = carea[base + lp];
                        cscore[base + lp] = -1.0f;
                    }
                }
            }
            __syncthreads();
            if (f_sc <= 0.0f) break;

            float b0 = f_o0, b1 = f_o1, b2_ = f_o2, b3 = f_o3, ai = f_ar;
            for (int p = t; p < K; p += T) {
                float c0 = cbo[(size_t)(base + p) * 4 + 0];
                float c1 = cbo[(size_t)(base + p) * 4 + 1];
                float c2 = cbo[(size_t)(base + p) * 4 + 2];
                float c3 = cbo[(size_t)(base + p) * 4 + 3];
                float iw = fmaxf(fminf(b2_, c2) - fmaxf(b0, c0), 0.0f);
                float ih = fmaxf(fminf(b3, c3) - fmaxf(b1, c1), 0.0f);
                float inter = iw * ih;
                float iou = inter / (ai + carea[base + p] - inter + 1e-6f);
                if (iou > iou_thr) cscore[base + p] = -1.0f;
            }
            __syncthreads();
        }
    }

    for (int q = it + t; q < imtop; q += T) {
        size_t oslot = (size_t)img * imtop + q;
        ob[oslot * 4 + 0] = 0.0f;
        ob[oslot * 4 + 1] = 0.0f;
        ob[oslot * 4 + 2] = 0.0f;
        ob[oslot * 4 + 3] = 0.0f;
        osc[oslot] = 0.0f;
        ocl[oslot] = -1.0f;
    }
}

// ---------------------------------------------------------------------------
// Legacy full NMS (compaction + decode + pick) — fallback path only.
// ---------------------------------------------------------------------------
__global__ __launch_bounds__(NMS_T) void nms_k(
    const float* __restrict__ scr,
    const float* __restrict__ prop,
    const int* __restrict__ imidx,
    const float* __restrict__ head, int ldh, int regofs,
    const float* __restrict__ br,
    const float* __restrict__ imsz,
    const float* __restrict__ score_thr_p,
    const float* __restrict__ min_size_p,
    const float* __restrict__ iou_thr_p,
    int* __restrict__ cidx,
    float* __restrict__ cscore,
    float* __restrict__ cbo,
    float* __restrict__ cbox,
    float* __restrict__ carea,
    float* __restrict__ out,
    int M, int n, int imtop)
{
    int img = blockIdx.x;
    int t = threadIdx.x;
    const int T = NMS_T;
    const int NW = NMS_T / 64;
    int lane = t & 63, wid = t >> 6;

    __shared__ int cnt;
    __shared__ float ws_sc[NW];
    __shared__ int ws_g[NW], ws_p[NW];
    __shared__ float f_sc, f_o0, f_o1, f_o2, f_o3, f_ar;

    if (t == 0) cnt = 0;
    __syncthreads();

    float score_thr = score_thr_p[0];
    float min_size  = min_size_p[0];
    float iou_thr   = iou_thr_p[0];
    float immax = imsz[0];
    for (int q = 1; q < 2 * n; ++q) immax = fmaxf(immax, imsz[q]);

    int base = img * M;
    for (int j = t; j < M; j += T) {
        int r = j / DCLS;
        if (imidx[r] != img) continue;
        float s = scr[j];
        if (s <= score_thr) continue;

        int cls = j - r * DCLS + 1;
        const float* pr = prop + (size_t)r * 4;
        float pw = pr[2] - pr[0], ph = pr[3] - pr[1];
        float cx = (pr[0] + pr[2]) * 0.5f, cy = (pr[1] + pr[3]) * 0.5f;
        const float* rg_ = head + (size_t)r * ldh + regofs + cls * 4;
        const float* bb = br + cls * 4;
        float dx = (rg_[0] + bb[0]) * 0.1f;
        float dy = (rg_[1] + bb[1]) * 0.1f;
        float dw = fminf((rg_[2] + bb[2]) * 0.2f, FLOG_MAX);
        float dh = fminf((rg_[3] + bb[3]) * 0.2f, FLOG_MAX);
        float ncx = dx * pw + cx;
        float ncy = dy * ph + cy;
        float nw = expf(dw) * pw;
        float nh = expf(dh) * ph;
        float hbound = imsz[img * 2 + 0];
        float wbound = imsz[img * 2 + 1];
        float bx1 = fminf(fmaxf(ncx - nw * 0.5f, 0.0f), wbound);
        float bx2 = fminf(fmaxf(ncx + nw * 0.5f, 0.0f), wbound);
        float by1 = fminf(fmaxf(ncy - nh * 0.5f, 0.0f), hbound);
        float by2 = fminf(fmaxf(ncy + nh * 0.5f, 0.0f), hbound);
        if (bx2 - bx1 < min_size || by2 - by1 < min_size) continue;

        float off = (float)cls * (immax + 2.0f);
        int p = atomicAdd(&cnt, 1);
        cidx[base + p] = j;
        cscore[base + p] = s;
        cbox[(size_t)(base + p) * 4 + 0] = bx1;
        cbox[(size_t)(base + p) * 4 + 1] = by1;
        cbox[(size_t)(base + p) * 4 + 2] = bx2;
        cbox[(size_t)(base + p) * 4 + 3] = by2;
        cbo[(size_t)(base + p) * 4 + 0] = bx1 + off;
        cbo[(size_t)(base + p) * 4 + 1] = by1 + off;
        cbo[(size_t)(base + p) * 4 + 2] = bx2 + off;
        cbo[(size_t)(base + p) * 4 + 3] = by2 + off;
        carea[base + p] = (bx2 - bx1) * (by2 - by1);
    }
    __syncthreads();
    int K = cnt;

    float* ob  = out;
    float* osc = out + (size_t)n * imtop * 4;
    float* ocl = out + (size_t)n * imtop * 5;

    int it = 0;
    for (; it < imtop; ++it) {
        float best = -1e30f; int bg = 0x7fffffff; int bl = -1;
        for (int p = t; p < K; p += T) {
            float sv = cscore[base + p];
            int g = cidx[base + p];
            if (sv > best || (sv == best && g < bg)) { best = sv; bg = g; bl = p; }
        }
#pragma unroll
        for (int o = 32; o > 0; o >>= 1) {
            float os = __shfl_down(best, o);
            int   og = __shfl_down(bg, o);
            int   ol = __shfl_down(bl, o);
            if (os > best || (os == best && og < bg)) { best = os; bg = og; bl = ol; }
        }
        if (lane == 0) { ws_sc[wid] = best; ws_g[wid] = bg; ws_p[wid] = bl; }
        __syncthreads();
        if (wid == 0) {
            float b2 = (lane < NW) ? ws_sc[lane] : -1e30f;
            int   g2 = (lane < NW) ? ws_g[lane] : 0x7fffffff;
            int   l2 = (lane < NW) ? ws_p[lane] : -1;
#pragma unroll
            for (int o = NW / 2; o > 0; o >>= 1) {
                float os = __shfl_down(b2, o);
                int   og = __shfl_down(g2, o);
                int   ol = __shfl_down(l2, o);
                if (os > b2 || (os == b2 && og < g2)) { b2 = os; g2 = og; l2 = ol; }
            }
            if (lane == 0) {
                f_sc = b2;
                if (b2 > 0.0f) {
                    int lp = l2;
                    size_t oslot = (size_t)img * imtop + it;
                    ob[oslot * 4 + 0] = cbox[(size_t)(base + lp) * 4 + 0];
                    ob[oslot * 4 + 1] = cbox[(size_t)(base + lp) * 4 + 1];
                    ob[oslot * 4 + 2] = cbox[(size_t)(base + lp) * 4 + 2];
                    ob[oslot * 4 + 3] = cbox[(size_t)(base + lp) * 4 + 3];
                    osc[oslot] = b2;
                    ocl[oslot] = (float)(g2 % DCLS + 1);
                    f_o0 = cbo[(size_t)(base + lp) * 4 + 0];
                    f_o1 = cbo[(size_t)(base + lp) * 4 + 1];
                    f_o2 = cbo[(size_t)(base + lp) * 4 + 2];
                    f_o3 = cbo[(size_t)(base + lp) * 4 + 3];
                    f_ar = carea[base + lp];
                    cscore[base + lp] = -1.0f;
                }
            }
        }
        __syncthreads();
        if (f_sc <= 0.0f) break;

        float b0 = f_o0, b1 = f_o1, b2_ = f_o2, b3 = f_o3, ai = f_ar;
        for (int p = t; p < K; p += T) {
            float c0 = cbo[(size_t)(base + p) * 4 + 0];
            float c1 = cbo[(size_t)(base + p) * 4 + 1];
            float c2 = cbo[(size_t)(base + p) * 4 + 2];
            float c3 = cbo[(size_t)(base + p) * 4 + 3];
            float iw = fmaxf(fminf(b2_, c2) - fmaxf(b0, c0), 0.0f);
            float ih = fmaxf(fminf(b3, c3) - fmaxf(b1, c1), 0.0f);
            float inter = iw * ih;
            float iou = inter / (ai + carea[base + p] - inter + 1e-6f);
            if (iou > iou_thr) cscore[base + p] = -1.0f;
        }
        __syncthreads();
    }

    for (int q = it + t; q < imtop; q += T) {
        size_t oslot = (size_t)img * imtop + q;
        ob[oslot * 4 + 0] = 0.0f;
        ob[oslot * 4 + 1] = 0.0f;
        ob[oslot * 4 + 2] = 0.0f;
        ob[oslot * 4 + 3] = 0.0f;
        osc[oslot] = 0.0f;
        ocl[oslot] = -1.0f;
    }
}

// ---------------------------------------------------------------------------
extern "C" void kernel_launch(void* const* d_in, const int* in_sizes, int n_in,
                              void* d_out, int out_size, void* d_ws, size_t ws_size,
                              hipStream_t stream)
{
    const float* prop   = (const float*)d_in[0];
    const int*   imidx  = (const int*)d_in[1];
    const float* f0     = (const float*)d_in[2];
    const float* f1     = (const float*)d_in[3];
    const float* f2     = (const float*)d_in[4];
    const float* f3     = (const float*)d_in[5];
    const float* W0     = (const float*)d_in[6];
    const float* b0     = (const float*)d_in[7];
    const float* W1     = (const float*)d_in[8];
    const float* b1     = (const float*)d_in[9];
    const float* Wc     = (const float*)d_in[10];
    const float* bc     = (const float*)d_in[11];
    const float* Wr     = (const float*)d_in[12];
    const float* br     = (const float*)d_in[13];
    const float* imsz   = (const float*)d_in[14];
    const float* sthr   = (const float*)d_in[15];
    const float* ithr   = (const float*)d_in[16];
    const float* msz    = (const float*)d_in[18];

    int R = in_sizes[1];              // 1024
    int n = in_sizes[14] / 2;         // 2
    int imtop = out_size / (n * 6);   // 100
    int M = R * DCLS;                 // 81920
    int K0 = NPOOL * NPOOL * CCH;     // 12544
    int CL = in_sizes[7];             // 1024

    int h0 = (int)(sqrtf((float)(in_sizes[2] / (n * CCH))) + 0.5f);
    int h1 = (int)(sqrtf((float)(in_sizes[3] / (n * CCH))) + 0.5f);
    int h2 = (int)(sqrtf((float)(in_sizes[4] / (n * CCH))) + 0.5f);
    int h3 = (int)(sqrtf((float)(in_sizes[5] / (n * CCH))) + 0.5f);

    float* outf = (float*)d_out;

    // ---- MFMA-path workspace layout (bytes) ----
    size_t szPool  = (size_t)R * K0 * 2;
    size_t szX     = (size_t)R * CL * 4;
    size_t szHead  = (size_t)R * NHEAD * 4;
    size_t szWh    = (size_t)NHEAD * CL * 2;
    size_t szXh    = (size_t)R * CL * 2;
    size_t szW1t   = (size_t)CL * CL * 2;
    size_t szScr   = (size_t)R * DCLS * 4;

    size_t needed = 4 * szPool + 2 * szX + szHead + 2 * szWh
                  + 4 * szXh + 2 * szW1t + szScr;

    int splitK0 = 8;                  // Kc = K0/8 = 1568 = 49*32
    bool mfma_ok = (ws_size >= needed) && (R % 128 == 0) && (CL % 128 == 0)
                 && (K0 % (splitK0 * 32) == 0) && (CL % 32 == 0)
                 && ((R * 49) % 4 == 0) && (K0 % 64 == 0) && (CL % 64 == 0)
                 && (R % 4 == 0);

    if (mfma_ok) {
        uint8_t* w = (uint8_t*)d_ws;
        size_t o = 0;
        _Float16* poolH   = (_Float16*)(w + o); o += szPool;
        _Float16* poolL   = (_Float16*)(w + o); o += szPool;
        _Float16* W0tH    = (_Float16*)(w + o); o += szPool;
        _Float16* W0tL    = (_Float16*)(w + o); o += szPool;
        float*    x0acc   = (float*)(w + o);    o += szX;
        float*    unused  = (float*)(w + o);    o += szX;   // (kept for layout stability)
        float*    headacc = (float*)(w + o);    o += szHead;
        _Float16* WheadtH = (_Float16*)(w + o); o += szWh;
        _Float16* WheadtL = (_Float16*)(w + o); o += szWh;
        _Float16* x0H     = (_Float16*)(w + o); o += szXh;
        _Float16* x0L     = (_Float16*)(w + o); o += szXh;
        _Float16* x1H     = (_Float16*)(w + o); o += szXh;
        _Float16* x1L     = (_Float16*)(w + o); o += szXh;
        _Float16* W1tH    = (_Float16*)(w + o); o += szW1t;
        _Float16* W1tL    = (_Float16*)(w + o); o += szW1t;
        float*    scr     = (float*)(w + o);    // region reused for NMS counters
        (void)unused;

        int* cnt = (int*)scr;

        // NMS compaction arrays alias the pool region (dead after FC0)
        int*   cidx   = (int*)d_ws;
        float* cscore = (float*)(cidx + (size_t)n * M);
        float* cbo    = cscore + (size_t)n * M;
        float* cbox   = cbo + (size_t)n * M * 4;
        float* carea  = cbox + (size_t)n * M * 4;

        // 1. fused pre-stage: roi + W0 convert + x0acc zero + cnt zero
        {
            int NB_ROI = (R * 49) / 4;
            int NB_CW0 = (K0 / 64) * (CL / 64);
            int zc4    = (int)(szX / 16);
            int NB_Z   = (zc4 + 255) / 256;
            int NB = NB_ROI + NB_CW0 + NB_Z;
            pre_uber_k<<<dim3(NB), dim3(256), 0, stream>>>(
                prop, imidx, f0, f1, f2, f3, h0, h1, h2, h3,
                poolH, poolL,
                W0, W0tH, W0tL,
                (float4*)x0acc, zc4,
                cnt, n,
                R, K0, CL);
        }
        // 2. FC0 (128x128 verified tile) + trailing W1/Wc/Wr convert blocks
        {
            int nbg = splitK0 * (R / 128) * (CL / 128);          // 512
            int KT1 = CL / 64;
            int NB_CW1 = KT1 * KT1;
            int NB_CWc = KT1 * ((NCLS + 63) / 64);
            int NB_CWr = KT1 * ((NCLS * 4 + 63) / 64);
            gemm_fc0_conv_k<<<dim3(nbg + NB_CW1 + NB_CWc + NB_CWr), dim3(256), 0, stream>>>(
                poolH, poolL, W0tH, W0tL, x0acc, R, CL, K0, K0 / splitK0, splitK0, nbg,
                W1, W1tH, W1tL, Wc, Wr, WheadtH, WheadtL, CL);
        }
        // 3. x0 = relu(x0acc + b0) -> hi/lo
        act_split_k<<<dim3((R * CL / 4 + 255) / 256), dim3(256), 0, stream>>>(
            x0acc, b0, x0H, x0L, R * CL, CL);
        // 4. FC1 fused: x1 = relu(x0 @ W1 + b1) -> hi/lo directly (no atomics)
        gemm_mfma_fused64_k<<<dim3(CL / 64, R / 64), dim3(256), 0, stream>>>(
            x0H, x0L, W1tH, W1tL, b1, nullptr, x1H, x1L, R, CL, CL, 1);
        // 5. combined heads fused: headacc = x1 @ [Wc|Wr] raw fp32 (N=512)
        gemm_mfma_fused64_k<<<dim3(NHEAD / 64, R / 64), dim3(256), 0, stream>>>(
            x1H, x1L, WheadtH, WheadtL, nullptr, headacc, nullptr, nullptr, R, NHEAD, CL, 0);
        // 6. fused softmax + decode + compaction (one wave per roi)
        compact_k<<<dim3(R / 4), dim3(256), 0, stream>>>(
            headacc, NHEAD, NCLS, bc, br, prop, imidx, imsz, sthr, msz,
            cnt, cidx, cscore, cbo, cbox, carea, M, n, R);
        // 7. NMS pick (sort + scan)
        nms_pick_k<<<dim3(n), dim3(NMS_T), 0, stream>>>(
            ithr, cnt, cidx, cscore, cbo, cbox, carea, outf, M, n, imtop);
    } else {
        // -------- fallback: all-fp32 pipeline --------
        float* ws = (float*)d_ws;
        size_t off = 0;
        float* pooled  = ws + off; off += (size_t)R * K0;
        float* x0acc   = ws + off; off += (size_t)R * CL;
        float* x1acc   = ws + off; off += (size_t)R * CL;
        float* logits  = ws + off; off += (size_t)R * NCLS;
        off = (off + 3) & ~(size_t)3;
        float* reg     = ws + off; off += (size_t)R * NCLS * 4;
        float* scr     = ws + off; off += (size_t)R * DCLS;

        int*   cidx   = (int*)ws;
        float* cscore = (float*)(cidx + (size_t)n * M);
        float* cbo    = cscore + (size_t)n * M;
        float* cbox   = cbo + (size_t)n * M * 4;
        float* carea  = cbox + (size_t)n * M * 4;

        {
            size_t zcount = (size_t)(reg + (size_t)R * NCLS * 4 - x0acc);
            int c4 = (int)(zcount / 4);
            zero_k<<<dim3((c4 + 255) / 256), dim3(256), 0, stream>>>((float4*)x0acc, c4);
        }
        roi_align_k<<<dim3(R * 49), dim3(256), 0, stream>>>(
            prop, imidx, f0, f1, f2, f3, h0, h1, h2, h3, pooled);
        gemm_splitk_k<<<dim3(CL / 64, R / 64, 8), dim3(256), 0, stream>>>(
            pooled, W0, nullptr, x0acc, R, CL, K0, 1568);
        gemm_splitk_k<<<dim3(CL / 64, R / 64, 4), dim3(256), 0, stream>>>(
            x0acc, W1, b0, x1acc, R, CL, CL, 256);
        gemm_splitk_k<<<dim3((NCLS + 63) / 64, R / 64, 8), dim3(256), 0, stream>>>(
            x1acc, Wc, b1, logits, R, NCLS, CL, 128);
        gemm_splitk_k<<<dim3((NCLS * 4 + 63) / 64, R / 64, 4), dim3(256), 0, stream>>>(
            x1acc, Wr, b1, reg, R, NCLS * 4, CL, 256);
        softmax_k<<<dim3(R), dim3(64), 0, stream>>>(logits, NCLS, bc, scr);
        nms_k<<<dim3(n), dim3(NMS_T), 0, stream>>>(
            scr, prop, imidx, reg, NCLS * 4, 0, br, imsz, sthr, msz, ithr,
            cidx, cscore, cbo, cbox, carea, outf, M, n, imtop);
    }
}